// Round 15
// baseline (1254.119 us; speedup 1.0000x reference)
//
#include <hip/hip_runtime.h>
#include <hip/hip_bf16.h>
#include <cstdint>

// Problem dims
// L=6, E=1024, H=16, F=4096, V=32000, B=4, S=512, ML=512, DH=64, tokens=2048

typedef float f32x4 __attribute__((ext_vector_type(4)));
typedef short s16x8 __attribute__((ext_vector_type(8)));
typedef __bf16 b16x8 __attribute__((ext_vector_type(8)));

struct Frag8 {
    s16x8 v;
    __device__ operator s16x8() const { return v; }
    __device__ operator b16x8() const { return __builtin_bit_cast(b16x8, v); }
};

__device__ __forceinline__ f32x4 mfma16(Frag8 a, Frag8 b, f32x4 c) {
    return __builtin_amdgcn_mfma_f32_16x16x32_bf16(a, b, c, 0, 0, 0);
}

__device__ __forceinline__ void gload_lds16(const void* g, void* l) {
    __builtin_amdgcn_global_load_lds(
        (__attribute__((address_space(1))) void*)g,
        (__attribute__((address_space(3))) void*)l, 16, 0, 0);
}

__device__ __forceinline__ unsigned short bf16bits(float x) {
    return __builtin_bit_cast(unsigned short, __float2bfloat16(x));
}

// ---------------- fused fp32 -> bf16 conversion (5 segments, 8 elems/thread) ----------------
__global__ __launch_bounds__(256) void k_conv5(const float* __restrict__ s0, const float* __restrict__ s1,
                                               const float* __restrict__ s2, const float* __restrict__ s3,
                                               const float* __restrict__ s4,
                                               __hip_bfloat16* __restrict__ d0, __hip_bfloat16* __restrict__ d1,
                                               __hip_bfloat16* __restrict__ d2, __hip_bfloat16* __restrict__ d3,
                                               __hip_bfloat16* __restrict__ d4,
                                               int b0, int b1, int b2, int b3) {
    const int blk = blockIdx.x;
    const float* src;
    __hip_bfloat16* dst;
    long base;
    if (blk < b0)      { src = s0; dst = d0; base = (long)blk * 2048; }
    else if (blk < b1) { src = s1; dst = d1; base = (long)(blk - b0) * 2048; }
    else if (blk < b2) { src = s2; dst = d2; base = (long)(blk - b1) * 2048; }
    else if (blk < b3) { src = s3; dst = d3; base = (long)(blk - b2) * 2048; }
    else               { src = s4; dst = d4; base = (long)(blk - b3) * 2048; }
    const long i = base + (long)threadIdx.x * 8;
    const float4 v0 = *(const float4*)(src + i);
    const float4 v1 = *(const float4*)(src + i + 4);
    s16x8 u;
    u[0] = (short)bf16bits(v0.x); u[1] = (short)bf16bits(v0.y);
    u[2] = (short)bf16bits(v0.z); u[3] = (short)bf16bits(v0.w);
    u[4] = (short)bf16bits(v1.x); u[5] = (short)bf16bits(v1.y);
    u[6] = (short)bf16bits(v1.z); u[7] = (short)bf16bits(v1.w);
    *(s16x8*)((unsigned short*)dst + i) = u;
}

// ---------------- bias pre-extraction: dist_emb[(i,h)] -> biasT[h][i] ----------------
__global__ __launch_bounds__(256) void k_bias_prep(const float* __restrict__ dist_emb,
                                                   float* __restrict__ biasT) {
    const int h = blockIdx.x;
    for (int i = threadIdx.x; i < 513; i += 256) biasT[h * 513 + i] = dist_emb[i * 16 + h];
}

// ---------------- embedding gather ----------------
__global__ __launch_bounds__(256) void k_embed(const int* __restrict__ seq,
                                               const float* __restrict__ tok,
                                               float* __restrict__ x,
                                               __hip_bfloat16* __restrict__ xb) {
    const int t = blockIdx.x;
    const int tokid = seq[t];
    const float4 v = *(const float4*)(tok + (size_t)tokid * 1024 + threadIdx.x * 4);
    float4 o;
    o.x = v.x * 32.0f; o.y = v.y * 32.0f; o.z = v.z * 32.0f; o.w = v.w * 32.0f;
    *(float4*)(x + (size_t)t * 1024 + threadIdx.x * 4) = o;
    ushort4 u;
    u.x = bf16bits(o.x); u.y = bf16bits(o.y); u.z = bf16bits(o.z); u.w = bf16bits(o.w);
    *(ushort4*)((unsigned short*)xb + (size_t)t * 1024 + threadIdx.x * 4) = u;
}

// ---------------- V transpose: qkv V-part -> vT[b,h,d,s] (LDS-tiled, coalesced) ----------------
__global__ __launch_bounds__(256) void k_vtrans(const __hip_bfloat16* __restrict__ qkv,
                                                __hip_bfloat16* __restrict__ vT) {
    const int st = blockIdx.x;
    const int bh = blockIdx.y;
    const int b = bh >> 4, h = bh & 15;
    __shared__ __align__(16) short T[64][72];
    const int tid = threadIdx.x;
#pragma unroll
    for (int i = 0; i < 2; ++i) {
        const int c = i * 256 + tid;
        const int s = c >> 3, d0 = (c & 7) * 8;
        const s16x8 v = *(const s16x8*)(qkv + (size_t)(b * 512 + st * 64 + s) * 3072 + 2048 + h * 64 + d0);
#pragma unroll
        for (int j = 0; j < 8; ++j) T[d0 + j][s] = v[j];
    }
    __syncthreads();
#pragma unroll
    for (int i = 0; i < 2; ++i) {
        const int c = i * 256 + tid;
        const int d = c >> 3, s0 = (c & 7) * 8;
        const s16x8 v = *(const s16x8*)&T[d][s0];
        *(s16x8*)(vT + ((size_t)bh * 64 + d) * 512 + st * 64 + s0) = v;
    }
}

// ============ 256x256-tile 8-wave phase-interleaved GEMM (vocab) ============
// Round-4 schedule with the pre-MFMA barrier removed (4 barriers/K-tile).
template <int TAG>
__global__ __launch_bounds__(512, 2) void k_gemm256(const __hip_bfloat16* __restrict__ A,
                                                    const __hip_bfloat16* __restrict__ B,
                                                    const float* __restrict__ bias,
                                                    float* __restrict__ Cf,
                                                    __hip_bfloat16* __restrict__ Cb,
                                                    const int M, const int N, const int K,
                                                    const int mtiles, const int act) {
    __shared__ __align__(16) char lds[131072];  // [buf][A 32KB | B 32KB] x2

    const int nwg = gridDim.x, bid = blockIdx.x;
    const int qq = nwg >> 3, rr = nwg & 7;
    const int xcd = bid & 7, local = bid >> 3;
    const int wgid = (xcd < rr ? xcd * (qq + 1) : rr * (qq + 1) + (xcd - rr) * qq) + local;
    const int m0 = (wgid % mtiles) * 256;
    const int n0 = (wgid / mtiles) * 256;

    const int tid = threadIdx.x;
    const int lane = tid & 63;
    const int wid = tid >> 6;
    const int wr = wid >> 2, wc = wid & 3;
    const int l16 = lane & 15, lq = lane >> 4;
    const int sw = l16 & 7;

    const int srow = tid >> 3;
    const int scol = ((tid & 7) ^ (srow & 7)) << 3;
    const __hip_bfloat16* aS = A + (size_t)(m0 + srow) * K + scol;
    const __hip_bfloat16* bS = B + (size_t)(n0 + srow) * K + scol;
    const size_t rstep = (size_t)64 * K;

    const int NT = K >> 6;
    const int arow = wr * 128 + l16;
    const int brow = wc * 64 + l16;

    auto stage = [&](int d, int isB, int blk, int kk) {
        const __hip_bfloat16* src = (isB ? bS : aS) + (size_t)blk * rstep + kk;
        char* dst = lds + d * 65536 + isB * 32768 + blk * 8192 + tid * 16;
        gload_lds16(src, dst);
    };

    stage(0, 1, 0, 0); stage(0, 1, 1, 0);
    stage(0, 1, 2, 0); stage(0, 1, 3, 0);
    stage(0, 0, 0, 0); stage(0, 0, 2, 0);
    stage(0, 0, 1, 0); stage(0, 0, 3, 0);
    asm volatile("s_waitcnt vmcnt(2)" ::: "memory");
    __builtin_amdgcn_sched_barrier(0);
    __builtin_amdgcn_s_barrier();
    __builtin_amdgcn_sched_barrier(0);

    f32x4 acc[8][4] = {};
    Frag8 bfr[2][4];

    for (int t = 0; t < NT; ++t) {
        const int d = t & 1;
        const char* Ab = lds + d * 65536;
        const char* Bb = Ab + 32768;
        const bool st = (t + 1 < NT);
        const int k1 = (t + 1) << 6;

#pragma unroll
        for (int q = 0; q < 4; ++q) {
            if (q == 0) {
#pragma unroll
                for (int ks = 0; ks < 2; ++ks)
#pragma unroll
                    for (int ni = 0; ni < 4; ++ni)
                        bfr[ks][ni].v = *(const s16x8*)(
                            Bb + (brow + ni * 16) * 128 + (((ks * 4 + lq) ^ sw) << 4));
            }
            Frag8 af[2][2];
#pragma unroll
            for (int m2 = 0; m2 < 2; ++m2)
#pragma unroll
                for (int ks = 0; ks < 2; ++ks)
                    af[m2][ks].v = *(const s16x8*)(
                        Ab + (arow + (q * 2 + m2) * 16) * 128 + (((ks * 4 + lq) ^ sw) << 4));

            if (st) {
                if (q == 0)      { stage(d ^ 1, 1, 0, k1); stage(d ^ 1, 1, 1, k1); }
                else if (q == 1) { stage(d ^ 1, 1, 2, k1); stage(d ^ 1, 1, 3, k1); }
                else if (q == 2) { stage(d ^ 1, 0, 0, k1); stage(d ^ 1, 0, 2, k1); }
                else             { stage(d ^ 1, 0, 1, k1); stage(d ^ 1, 0, 3, k1); }
            }

            // no pre-MFMA barrier: compiler inserts lgkmcnt for the ds_read deps
            __builtin_amdgcn_sched_barrier(0);
            __builtin_amdgcn_s_setprio(1);
#pragma unroll
            for (int ks = 0; ks < 2; ++ks)
#pragma unroll
                for (int m2 = 0; m2 < 2; ++m2)
#pragma unroll
                    for (int ni = 0; ni < 4; ++ni)
                        acc[q * 2 + m2][ni] = mfma16(af[m2][ks], bfr[ks][ni], acc[q * 2 + m2][ni]);
            __builtin_amdgcn_s_setprio(0);
            __builtin_amdgcn_sched_barrier(0);
            if (q == 1) {
                if (st) asm volatile("s_waitcnt vmcnt(4)" ::: "memory");
                else    asm volatile("s_waitcnt vmcnt(0)" ::: "memory");
            } else if (q == 3) {
                if (st) asm volatile("s_waitcnt vmcnt(2)" ::: "memory");
                else    asm volatile("s_waitcnt vmcnt(0)" ::: "memory");
            }
            __builtin_amdgcn_s_barrier();
            __builtin_amdgcn_sched_barrier(0);
        }
    }

#pragma unroll
    for (int mi = 0; mi < 8; ++mi) {
        const int rowb = m0 + wr * 128 + mi * 16 + lq * 4;
#pragma unroll
        for (int ni = 0; ni < 4; ++ni) {
            const int col = n0 + wc * 64 + ni * 16 + l16;
            const float bv = bias[col];
#pragma unroll
            for (int r = 0; r < 4; ++r) {
                float v2 = acc[mi][ni][r] + bv;
                if (act == 1) v2 = 0.5f * v2 * (1.0f + erff(v2 * 0.70710678118654752f));
                const size_t idx = (size_t)(rowb + r) * N + col;
                if (Cf) Cf[idx] = v2;
                if (Cb) Cb[idx] = __float2bfloat16(v2);
            }
        }
    }
}

// ============ 256x128-tile 8-wave barrier-free GEMM (QKV / FFN1 / FFN2 split-K) ============
// BK=64, 2 LDS buffers x 48KB (A 4x8KB blocks | B 2x8KB blocks). 8 waves as 2x4:
// wave = 128 rows x 32 cols, acc[8][2]. 4 phases/K-tile, 8 MFMA each. 6-load
// ledger: A-blocks 1,3 staged last; waits vmcnt(4) @q1-end, vmcnt(2) @q3-end.
// grid.y = split-K slice (f32 partials via Cf; bias only in slice 0).
template <int TAG>
__global__ __launch_bounds__(512, 2) void k_gemm256n(const __hip_bfloat16* __restrict__ A,
                                                     const __hip_bfloat16* __restrict__ B,
                                                     const float* __restrict__ bias,
                                                     float* __restrict__ Cf,
                                                     __hip_bfloat16* __restrict__ Cb,
                                                     const int M, const int N, const int K,
                                                     const int Ksub, const int mtiles,
                                                     const int act) {
    __shared__ __align__(16) char lds[98304];  // 2 bufs x (A 32KB | B 16KB)

    const int nwg = gridDim.x, bid = blockIdx.x;
    const int qq = nwg >> 3, rr = nwg & 7;
    const int xcd = bid & 7, local = bid >> 3;
    const int wgid = (xcd < rr ? xcd * (qq + 1) : rr * (qq + 1) + (xcd - rr) * qq) + local;
    const int m0 = (wgid % mtiles) * 256;
    const int n0 = (wgid / mtiles) * 128;

    const int tid = threadIdx.x;
    const int lane = tid & 63;
    const int wid = tid >> 6;
    const int wr = wid >> 2, wc = wid & 3;     // 2 row-waves x 4 col-waves
    const int l16 = lane & 15, lq = lane >> 4;
    const int sw = l16 & 7;

    const int kb = blockIdx.y * Ksub;
    const int srow = tid >> 3;
    const int scol = ((tid & 7) ^ (srow & 7)) << 3;
    const __hip_bfloat16* aS = A + (size_t)(m0 + srow) * K + scol + kb;
    const __hip_bfloat16* bS = B + (size_t)(n0 + srow) * K + scol + kb;
    const size_t rstep = (size_t)64 * K;

    const int NT = Ksub >> 6;
    const int arow = wr * 128 + l16;
    const int brow = wc * 32 + l16;

    auto stage = [&](int d, int isB, int blk, int kk) {
        const __hip_bfloat16* src = (isB ? bS : aS) + (size_t)blk * rstep + kk;
        char* dst = lds + d * 49152 + isB * 32768 + blk * 8192 + tid * 16;
        gload_lds16(src, dst);
    };

    // prologue: stage K-tile 0, order = [B0,B1, A0,A2, A1,A3]
    stage(0, 1, 0, 0); stage(0, 1, 1, 0);
    stage(0, 0, 0, 0); stage(0, 0, 2, 0);
    stage(0, 0, 1, 0); stage(0, 0, 3, 0);
    asm volatile("s_waitcnt vmcnt(2)" ::: "memory");  // B + A0,A2 landed; A1,A3 in flight
    __builtin_amdgcn_sched_barrier(0);
    __builtin_amdgcn_s_barrier();
    __builtin_amdgcn_sched_barrier(0);

    f32x4 acc[8][2] = {};
    Frag8 bfr[2][2];

    for (int t = 0; t < NT; ++t) {
        const int d = t & 1;
        const char* Ab = lds + d * 49152;
        const char* Bb = Ab + 32768;
        const bool st = (t + 1 < NT);
        const int k1 = (t + 1) << 6;

#pragma unroll
        for (int q = 0; q < 4; ++q) {
            if (q == 0) {
#pragma unroll
                for (int ks = 0; ks < 2; ++ks)
#pragma unroll
                    for (int ni = 0; ni < 2; ++ni)
                        bfr[ks][ni].v = *(const s16x8*)(
                            Bb + (brow + ni * 16) * 128 + (((ks * 4 + lq) ^ sw) << 4));
            }
            Frag8 af[2][2];
#pragma unroll
            for (int m2 = 0; m2 < 2; ++m2)
#pragma unroll
                for (int ks = 0; ks < 2; ++ks)
                    af[m2][ks].v = *(const s16x8*)(
                        Ab + (arow + (q * 2 + m2) * 16) * 128 + (((ks * 4 + lq) ^ sw) << 4));

            if (st) {
                if (q == 0)      { stage(d ^ 1, 1, 0, k1); stage(d ^ 1, 1, 1, k1); }
                else if (q == 1) { stage(d ^ 1, 0, 0, k1); stage(d ^ 1, 0, 2, k1); }
                else if (q == 2) { stage(d ^ 1, 0, 1, k1); stage(d ^ 1, 0, 3, k1); }
            }

            __builtin_amdgcn_sched_barrier(0);
            __builtin_amdgcn_s_setprio(1);
#pragma unroll
            for (int ks = 0; ks < 2; ++ks)
#pragma unroll
                for (int m2 = 0; m2 < 2; ++m2)
#pragma unroll
                    for (int ni = 0; ni < 2; ++ni)
                        acc[q * 2 + m2][ni] = mfma16(af[m2][ks], bfr[ks][ni], acc[q * 2 + m2][ni]);
            __builtin_amdgcn_s_setprio(0);
            __builtin_amdgcn_sched_barrier(0);
            if (q == 1) {
                if (st) asm volatile("s_waitcnt vmcnt(4)" ::: "memory");
                else    asm volatile("s_waitcnt vmcnt(0)" ::: "memory");
            } else if (q == 3) {
                if (st) asm volatile("s_waitcnt vmcnt(2)" ::: "memory");
                else    asm volatile("s_waitcnt vmcnt(0)" ::: "memory");
            }
            __builtin_amdgcn_s_barrier();
            __builtin_amdgcn_sched_barrier(0);
        }
    }

    float* Cfp = Cf ? Cf + (size_t)blockIdx.y * M * N : nullptr;
    const bool addb = (blockIdx.y == 0);

    // epilogue: C/D layout col=lane&15, row=(lane>>4)*4+r
#pragma unroll
    for (int mi = 0; mi < 8; ++mi) {
        const int rowb = m0 + wr * 128 + mi * 16 + lq * 4;
#pragma unroll
        for (int ni = 0; ni < 2; ++ni) {
            const int col = n0 + wc * 32 + ni * 16 + l16;
            const float bv = addb ? bias[col] : 0.0f;
#pragma unroll
            for (int r = 0; r < 4; ++r) {
                float v2 = acc[mi][ni][r] + bv;
                if (act == 1) v2 = 0.5f * v2 * (1.0f + erff(v2 * 0.70710678118654752f));
                const size_t idx = (size_t)(rowb + r) * N + col;
                if (Cfp) Cfp[idx] = v2;
                if (Cb) Cb[idx] = __float2bfloat16(v2);
            }
        }
    }
}

// ============ 128x128-tile pipelined GEMM (small shapes: Wo, fallback) ============
__device__ __forceinline__ const s16x8* fragp(const char* base, int row, int lq) {
    const int line = row >> 1;
    const int u = ((row & 1) << 2) | lq;
    return (const s16x8*)(base + line * 128 + ((u ^ (line & 7)) << 4));
}

template <int TAG>
__global__ __launch_bounds__(256, 2) void k_gemm(const __hip_bfloat16* __restrict__ A,
                                                 const __hip_bfloat16* __restrict__ B,
                                                 const float* __restrict__ bias,
                                                 float* __restrict__ Cf,
                                                 __hip_bfloat16* __restrict__ Cb,
                                                 const int M, const int N, const int K,
                                                 const int Ksub, const int mtiles,
                                                 const int act) {
    __shared__ __align__(16) char lds[3 * 16384];

    const int nwg = gridDim.x;
    const int bid = blockIdx.x;
    const int q = nwg >> 3, r = nwg & 7;
    const int xcd = bid & 7, local = bid >> 3;
    const int wgid = (xcd < r ? xcd * (q + 1) : r * (q + 1) + (xcd - r) * q) + local;
    const int m0 = (wgid % mtiles) * 128;
    const int n0 = (wgid / mtiles) * 128;

    const int tid = threadIdx.x;
    const int lane = tid & 63, w = tid >> 6;
    const int wr = w >> 1, wc = w & 1;
    const int l16 = lane & 15, lq = lane >> 4;

    const int kb = blockIdx.y * Ksub;
    const int NT = Ksub >> 5;

    int arow0, acol0, arow1, acol1;
    {
        const int c0 = tid, line0 = c0 >> 3, u0 = (c0 & 7) ^ (line0 & 7);
        arow0 = (line0 << 1) | (u0 >> 2); acol0 = (u0 & 3) * 8;
        const int c1 = tid + 256, line1 = c1 >> 3, u1 = (c1 & 7) ^ (line1 & 7);
        arow1 = (line1 << 1) | (u1 >> 2); acol1 = (u1 & 3) * 8;
    }
    const size_t abase0 = (size_t)(m0 + arow0) * K + acol0 + kb;
    const size_t abase1 = (size_t)(m0 + arow1) * K + acol1 + kb;
    const size_t bbase0 = (size_t)(n0 + arow0) * K + acol0 + kb;
    const size_t bbase1 = (size_t)(n0 + arow1) * K + acol1 + kb;

    auto stageA = [&](int tt, int buf) {
        char* dst = lds + buf * 16384;
        gload_lds16(A + abase0 + tt * 32, dst + tid * 16);
        gload_lds16(A + abase1 + tt * 32, dst + (tid + 256) * 16);
    };
    auto stageB = [&](int tt, int buf) {
        char* dst = lds + buf * 16384 + 8192;
        gload_lds16(B + bbase0 + tt * 32, dst + tid * 16);
        gload_lds16(B + bbase1 + tt * 32, dst + (tid + 256) * 16);
    };

    f32x4 acc[4][4] = {};

    stageA(0, 0); stageB(0, 0);
    stageA(1, 1); stageB(1, 1);
    asm volatile("s_waitcnt vmcnt(4)" ::: "memory");
    __builtin_amdgcn_sched_barrier(0);
    __builtin_amdgcn_s_barrier();
    __builtin_amdgcn_sched_barrier(0);

    int cur = 0;
    for (int t = 0; t < NT; ++t) {
        const int stb = (cur == 0) ? 2 : cur - 1;
        const char* Ab = lds + cur * 16384;
        const char* Bb = Ab + 8192;
        const bool doStage = (t + 2 < NT);

        if (doStage) stageA(t + 2, stb);

        Frag8 a0, a1, b0, b1, b2, b3;
        a0.v = *fragp(Ab, wr * 64 + l16, lq);
        a1.v = *fragp(Ab, wr * 64 + 16 + l16, lq);
        b0.v = *fragp(Bb, wc * 64 + l16, lq);
        b1.v = *fragp(Bb, wc * 64 + 16 + l16, lq);
        b2.v = *fragp(Bb, wc * 64 + 32 + l16, lq);
        b3.v = *fragp(Bb, wc * 64 + 48 + l16, lq);

        __builtin_amdgcn_s_setprio(1);
        acc[0][0] = mfma16(a0, b0, acc[0][0]);
        acc[0][1] = mfma16(a0, b1, acc[0][1]);
        acc[0][2] = mfma16(a0, b2, acc[0][2]);
        acc[0][3] = mfma16(a0, b3, acc[0][3]);
        acc[1][0] = mfma16(a1, b0, acc[1][0]);
        acc[1][1] = mfma16(a1, b1, acc[1][1]);
        acc[1][2] = mfma16(a1, b2, acc[1][2]);
        acc[1][3] = mfma16(a1, b3, acc[1][3]);
        __builtin_amdgcn_s_setprio(0);

        if (doStage) stageB(t + 2, stb);

        Frag8 a2, a3;
        a2.v = *fragp(Ab, wr * 64 + 32 + l16, lq);
        a3.v = *fragp(Ab, wr * 64 + 48 + l16, lq);

        __builtin_amdgcn_s_setprio(1);
        acc[2][0] = mfma16(a2, b0, acc[2][0]);
        acc[2][1] = mfma16(a2, b1, acc[2][1]);
        acc[2][2] = mfma16(a2, b2, acc[2][2]);
        acc[2][3] = mfma16(a2, b3, acc[2][3]);
        acc[3][0] = mfma16(a3, b0, acc[3][0]);
        acc[3][1] = mfma16(a3, b1, acc[3][1]);
        acc[3][2] = mfma16(a3, b2, acc[3][2]);
        acc[3][3] = mfma16(a3, b3, acc[3][3]);
        __builtin_amdgcn_s_setprio(0);

        if (t + 3 < NT) {
            asm volatile("s_waitcnt vmcnt(4)" ::: "memory");
        } else {
            asm volatile("s_waitcnt vmcnt(0)" ::: "memory");
        }
        __builtin_amdgcn_sched_barrier(0);
        __builtin_amdgcn_s_barrier();
        __builtin_amdgcn_sched_barrier(0);

        cur = (cur == 2) ? 0 : cur + 1;
    }

    float* Cfp = Cf ? Cf + (size_t)blockIdx.y * M * N : nullptr;
    const bool addb = (blockIdx.y == 0);

#pragma unroll
    for (int mi = 0; mi < 4; ++mi) {
        const int rowb = m0 + wr * 64 + mi * 16 + lq * 4;
#pragma unroll
        for (int ni = 0; ni < 4; ++ni) {
            const int col = n0 + wc * 64 + ni * 16 + l16;
            const float bv = addb ? bias[col] : 0.0f;
#pragma unroll
            for (int rr = 0; rr < 4; ++rr) {
                float v2 = acc[mi][ni][rr] + bv;
                if (act == 1) v2 = 0.5f * v2 * (1.0f + erff(v2 * 0.70710678118654752f));
                const size_t idx = (size_t)(rowb + rr) * N + col;
                if (Cfp) Cfp[idx] = v2;
                if (Cb) Cb[idx] = __float2bfloat16(v2);
            }
        }
    }
}

// ---------------- flash attention (round-11 compute, CU-load-balanced remap) ----------------
__global__ __launch_bounds__(256) void k_attn(const __hip_bfloat16* __restrict__ qkv,
                                              const __hip_bfloat16* __restrict__ vT,
                                              const int* __restrict__ seq,
                                              const float* __restrict__ biasT,
                                              __hip_bfloat16* __restrict__ out) {
    const int f = blockIdx.x;
    const int half = f >> 8;
    const int qb = half ? (7 - (f & 7)) : (f & 7);
    const int hb = ((f & 255) >> 3) + (half << 5);
    const int h = hb & 15, b = hb >> 4;
    const int q0 = qb * 64;
    const int tid = threadIdx.x, lane = tid & 63, w = tid >> 6;
    const int l16 = lane & 15, lq = lane >> 4;

    __shared__ __align__(16) char Ks[2 * 8192];
    __shared__ __align__(16) char Vs[2 * 8192];
    __shared__ __align__(16) char Ps[4 * 2048];
    __shared__ float bias_l[513];
    __shared__ float pad_l[512];

    for (int i = tid; i < 513; i += 256) bias_l[i] = biasT[h * 513 + i];
    for (int i = tid; i < 512; i += 256) pad_l[i] = (seq[b * 512 + i] == 0) ? -1e9f : 0.0f;

    const int qrowA = q0 + w * 16 + l16;
    const __hip_bfloat16* qptr = qkv + (size_t)(b * 512 + qrowA) * 3072 + h * 64;
    Frag8 qf[2];
    qf[0].v = *(const s16x8*)(qptr + lq * 8);
    qf[1].v = *(const s16x8*)(qptr + 32 + lq * 8);

    const int kr0 = tid >> 3, sl = tid & 7;
    const int kr1 = kr0 + 32;
    char* kdst0 = Ks + kr0 * 128 + ((sl ^ (kr0 & 7)) * 16);
    char* kdst1 = Ks + kr1 * 128 + ((sl ^ (kr1 & 7)) * 16);
    char* vdst0 = Vs + kr0 * 128 + ((sl ^ (kr0 & 7)) * 16);
    char* vdst1 = Vs + kr1 * 128 + ((sl ^ (kr1 & 7)) * 16);
    const __hip_bfloat16* vbase = vT + (size_t)(b * 16 + h) * 64 * 512;

    s16x8 kreg0, kreg1, vreg0, vreg1;
    auto load_regs = [&](int kt) {
        const size_t kb_ = (size_t)(b * 512 + kt * 64) * 3072 + h * 64 + 1024;
        kreg0 = *(const s16x8*)(qkv + kb_ + (size_t)kr0 * 3072 + sl * 8);
        kreg1 = *(const s16x8*)(qkv + kb_ + (size_t)kr1 * 3072 + sl * 8);
        vreg0 = *(const s16x8*)(vbase + (size_t)kr0 * 512 + kt * 64 + sl * 8);
        vreg1 = *(const s16x8*)(vbase + (size_t)kr1 * 512 + kt * 64 + sl * 8);
    };

    f32x4 oacc[4] = {};
    float mrow[4] = {-1e30f, -1e30f, -1e30f, -1e30f};
    float lrow[4] = {0.f, 0.f, 0.f, 0.f};
    char* PsW = Ps + w * 2048;

    load_regs(0);
    for (int kt = 0; kt <= qb; ++kt) {
        const int bo = (kt & 1) * 8192;
        *(s16x8*)(kdst0 + bo) = kreg0;
        *(s16x8*)(kdst1 + bo) = kreg1;
        *(s16x8*)(vdst0 + bo) = vreg0;
        *(s16x8*)(vdst1 + bo) = vreg1;
        __syncthreads();
        if (kt < qb) load_regs(kt + 1);

        const char* Kb = Ks + bo;
        const char* Vb = Vs + bo;

        f32x4 sacc[4] = {};
#pragma unroll
        for (int ks = 0; ks < 2; ++ks) {
#pragma unroll
            for (int nf = 0; nf < 4; ++nf) {
                const int key = nf * 16 + l16;
                Frag8 kf;
                kf.v = *(const s16x8*)(Kb + key * 128 + (((ks * 4 + lq) ^ (key & 7)) * 16));
                sacc[nf] = mfma16(qf[ks], kf, sacc[nf]);
            }
        }

        float pvv[4][4];
#pragma unroll
        for (int nf = 0; nf < 4; ++nf) {
            const int keyg = kt * 64 + nf * 16 + l16;
            const float padv = pad_l[keyg];
#pragma unroll
            for (int rr = 0; rr < 4; ++rr) {
                const int qg = q0 + w * 16 + lq * 4 + rr;
                pvv[nf][rr] = (keyg > qg) ? -1e9f
                            : sacc[nf][rr] * 0.125f + bias_l[qg - keyg] + padv;
            }
        }

#pragma unroll
        for (int rr = 0; rr < 4; ++rr) {
            float tm = fmaxf(fmaxf(pvv[0][rr], pvv[1][rr]), fmaxf(pvv[2][rr], pvv[3][rr]));
#pragma unroll
            for (int off = 1; off < 16; off <<= 1) tm = fmaxf(tm, __shfl_xor(tm, off, 64));
            const float mnew = fmaxf(mrow[rr], tm);
            const float sf = __expf(mrow[rr] - mnew);
            mrow[rr] = mnew;
            float ts = 0.f;
#pragma unroll
            for (int nf = 0; nf < 4; ++nf) {
                const float pe = __expf(pvv[nf][rr] - mnew);
                pvv[nf][rr] = pe;
                ts += pe;
            }
#pragma unroll
            for (int off = 1; off < 16; off <<= 1) ts += __shfl_xor(ts, off, 64);
            lrow[rr] = lrow[rr] * sf + ts;
            oacc[0][rr] *= sf; oacc[1][rr] *= sf; oacc[2][rr] *= sf; oacc[3][rr] *= sf;
        }

#pragma unroll
        for (int nf = 0; nf < 4; ++nf) {
            const int cc = nf * 16 + l16;
            const int slot = cc >> 3, rem = cc & 7;
#pragma unroll
            for (int rr = 0; rr < 4; ++rr) {
                const int row = lq * 4 + rr;
                *(short*)(PsW + row * 128 + ((slot ^ (row & 7)) * 16) + rem * 2) =
                    (short)bf16bits(pvv[nf][rr]);
            }
        }

#pragma unroll
        for (int ks = 0; ks < 2; ++ks) {
            Frag8 pf;
            pf.v = *(const s16x8*)(PsW + l16 * 128 + (((ks * 4 + lq) ^ (l16 & 7)) * 16));
#pragma unroll
            for (int nf = 0; nf < 4; ++nf) {
                const int d = nf * 16 + l16;
                Frag8 vf;
                vf.v = *(const s16x8*)(Vb + d * 128 + (((ks * 4 + lq) ^ (d & 7)) * 16));
                oacc[nf] = mfma16(pf, vf, oacc[nf]);
            }
        }
    }

#pragma unroll
    for (int nf = 0; nf < 4; ++nf) {
        const int d = nf * 16 + l16;
#pragma unroll
        for (int rr = 0; rr < 4; ++rr) {
            const int qg = q0 + w * 16 + lq * 4 + rr;
            out[(size_t)(b * 512 + qg) * 1024 + h * 64 + d] = __float2bfloat16(oacc[nf][rr] / lrow[rr]);
        }
    }
}

// ---------------- fused residual add (up to 4 partials) + LayerNorm ----------------
__global__ __launch_bounds__(256) void k_add_ln(const float* __restrict__ x,
                                                const float* __restrict__ res0,
                                                const float* __restrict__ res1,
                                                const float* __restrict__ res2,
                                                const float* __restrict__ res3,
                                                const float* __restrict__ gamma,
                                                const float* __restrict__ beta,
                                                float* __restrict__ xout,
                                                __hip_bfloat16* __restrict__ bout) {
    const int t = blockIdx.x;
    const int tid = threadIdx.x;
    float4 y = *(const float4*)(x + (size_t)t * 1024 + tid * 4);
    const float* rs[4] = {res0, res1, res2, res3};
#pragma unroll
    for (int k = 0; k < 4; ++k) {
        if (rs[k]) {
            const float4 rv = *(const float4*)(rs[k] + (size_t)t * 1024 + tid * 4);
            y.x += rv.x; y.y += rv.y; y.z += rv.z; y.w += rv.w;
        }
    }
    float s = y.x + y.y + y.z + y.w;
    float s2 = y.x * y.x + y.y * y.y + y.z * y.z + y.w * y.w;
#pragma unroll
    for (int off = 32; off >= 1; off >>= 1) {
        s += __shfl_xor(s, off, 64);
        s2 += __shfl_xor(s2, off, 64);
    }
    __shared__ float red[8];
    const int w = tid >> 6, lane = tid & 63;
    if (lane == 0) { red[w] = s; red[4 + w] = s2; }
    __syncthreads();
    const float tot = red[0] + red[1] + red[2] + red[3];
    const float tot2 = red[4] + red[5] + red[6] + red[7];
    const float mean = tot * (1.0f / 1024.0f);
    const float var = tot2 * (1.0f / 1024.0f) - mean * mean;
    const float inv = rsqrtf(var + 1e-5f);
    const float4 g = *(const float4*)(gamma + tid * 4);
    const float4 bb = *(const float4*)(beta + tid * 4);
    float4 o;
    o.x = (y.x - mean) * inv * g.x + bb.x;
    o.y = (y.y - mean) * inv * g.y + bb.y;
    o.z = (y.z - mean) * inv * g.z + bb.z;
    o.w = (y.w - mean) * inv * g.w + bb.w;
    *(float4*)(xout + (size_t)t * 1024 + tid * 4) = o;
    ushort4 u;
    u.x = bf16bits(o.x); u.y = bf16bits(o.y); u.z = bf16bits(o.z); u.w = bf16bits(o.w);
    *(ushort4*)((unsigned short*)bout + (size_t)t * 1024 + tid * 4) = u;
}

// ---------------- host ----------------
extern "C" void kernel_launch(void* const* d_in, const int* in_sizes, int n_in,
                              void* d_out, int out_size, void* d_ws, size_t ws_size,
                              hipStream_t stream) {
    const int* seq = (const int*)d_in[0];
    const float* tok = (const float*)d_in[1];
    const float* dist = (const float*)d_in[2];
    const float* Wqkv = (const float*)d_in[3];
    const float* bqkv = (const float*)d_in[4];
    const float* Wo = (const float*)d_in[5];
    const float* bo = (const float*)d_in[6];
    const float* W1 = (const float*)d_in[7];
    const float* b1 = (const float*)d_in[8];
    const float* W2 = (const float*)d_in[9];
    const float* b2 = (const float*)d_in[10];
    const float* ln1s = (const float*)d_in[11];
    const float* ln1b = (const float*)d_in[12];
    const float* ln2s = (const float*)d_in[13];
    const float* ln2b = (const float*)d_in[14];
    const float* lnfs = (const float*)d_in[15];
    const float* lnfb = (const float*)d_in[16];
    const float* Wg = (const float*)d_in[17];
    const float* bg = (const float*)d_in[18];
    float* out = (float*)d_out;

    const size_t base_need = (size_t)300 * 1024 * 1024;
    const int ffn2_splits = (ws_size >= base_need) ? 4 : 2;

    char* p = (char*)d_ws;
    auto take = [&](size_t bytes) {
        char* r = p;
        p += (bytes + 255) & ~(size_t)255;
        return r;
    };
    __hip_bfloat16* wqkv_b = (__hip_bfloat16*)take((size_t)6 * 3072 * 1024 * 2);
    __hip_bfloat16* wo_b = (__hip_bfloat16*)take((size_t)6 * 1024 * 1024 * 2);
    __hip_bfloat16* w1_b = (__hip_bfloat16*)take((size_t)6 * 4096 * 1024 * 2);
    __hip_bfloat16* w2_b = (__hip_bfloat16*)take((size_t)6 * 1024 * 4096 * 2);
    __hip_bfloat16* wg_b = (__hip_bfloat16*)take((size_t)32000 * 1024 * 2);
    float* xf = (float*)take((size_t)2048 * 1024 * 4);
    __hip_bfloat16* xb = (__hip_bfloat16*)take((size_t)2048 * 1024 * 2);
    __hip_bfloat16* qkvb = (__hip_bfloat16*)take((size_t)2048 * 3072 * 2);
    __hip_bfloat16* hb = (__hip_bfloat16*)take((size_t)2048 * 4096 * 2);
    __hip_bfloat16* ab = (__hip_bfloat16*)take((size_t)2048 * 1024 * 2);
    __hip_bfloat16* vTb = (__hip_bfloat16*)take((size_t)64 * 64 * 512 * 2);
    float* biasT = (float*)take((size_t)16 * 513 * 4);
    float* tmpf = (float*)take((size_t)ffn2_splits * 2048 * 1024 * 4);
    float* tmpf1 = tmpf + (size_t)2048 * 1024;
    float* tmpf2 = (ffn2_splits == 4) ? tmpf + (size_t)2 * 2048 * 1024 : nullptr;
    float* tmpf3 = (ffn2_splits == 4) ? tmpf + (size_t)3 * 2048 * 1024 : nullptr;

    k_conv5<<<dim3(52864), dim3(256), 0, stream>>>(
        Wqkv, Wo, W1, W2, Wg, wqkv_b, wo_b, w1_b, w2_b, wg_b,
        9216, 9216 + 3072, 9216 + 3072 + 12288, 9216 + 3072 + 12288 + 12288);
    k_bias_prep<<<dim3(16), dim3(256), 0, stream>>>(dist, biasT);
    k_embed<<<dim3(2048), dim3(256), 0, stream>>>(seq, tok, xf, xb);

    for (int l = 0; l < 6; ++l) {
        // QKV: 2048 x 3072 x 1024 (256x128 tiles: 8 x 24 = 192 wgs), bf16 out
        k_gemm256n<0><<<dim3(192), dim3(512), 0, stream>>>(
            xb, wqkv_b + (size_t)l * 3072 * 1024, bqkv + l * 3072, nullptr, qkvb,
            2048, 3072, 1024, 1024, 8, 0);
        k_vtrans<<<dim3(8, 64), dim3(256), 0, stream>>>(qkvb, vTb);
        k_attn<<<dim3(512), dim3(256), 0, stream>>>(qkvb, vTb, seq, biasT, ab);
        // Wo: 2048 x 1024 x 1024, 128^2 split-K=2 -> f32 partials
        k_gemm<1><<<dim3(16 * 8, 2), dim3(256), 0, stream>>>(
            ab, wo_b + (size_t)l * 1024 * 1024, bo + l * 1024, tmpf, nullptr,
            2048, 1024, 1024, 512, 16, 0);
        k_add_ln<<<dim3(2048), dim3(256), 0, stream>>>(xf, tmpf, tmpf1, nullptr, nullptr,
                                                       ln1s + l * 1024, ln1b + l * 1024, xf, xb);
        // FFN1: 2048 x 4096 x 1024 (256x128 tiles: 8 x 32 = 256 wgs, full coverage), GELU
        k_gemm256n<2><<<dim3(256), dim3(512), 0, stream>>>(
            xb, w1_b + (size_t)l * 4096 * 1024, b1 + l * 4096, nullptr, hb,
            2048, 4096, 1024, 1024, 8, 1);
        // FFN2: 2048 x 1024 x 4096
        if (ffn2_splits == 4) {
            // 256x128 tiles split-K=4: 64 x 4 = 256 wgs full coverage, NT=16
            k_gemm256n<3><<<dim3(64, 4), dim3(512), 0, stream>>>(
                hb, w2_b + (size_t)l * 1024 * 4096, b2 + l * 1024, tmpf, nullptr,
                2048, 1024, 4096, 1024, 8, 0);
        } else {
            k_gemm<3><<<dim3(16 * 8, 2), dim3(256), 0, stream>>>(
                hb, w2_b + (size_t)l * 1024 * 4096, b2 + l * 1024, tmpf, nullptr,
                2048, 1024, 4096, 2048, 16, 0);
        }
        k_add_ln<<<dim3(2048), dim3(256), 0, stream>>>(xf, tmpf, tmpf1, tmpf2, tmpf3,
                                                       ln2s + l * 1024, ln2b + l * 1024, xf, xb);
    }
    k_add_ln<<<dim3(2048), dim3(256), 0, stream>>>(xf, nullptr, nullptr, nullptr, nullptr,
                                                   lnfs, lnfb, xf, xb);
    // vocab: 2048 x 32000 x 1024 (256^2 tiles: 8 x 125 = 1000 wgs), f32 out
    k_gemm256<4><<<dim3(1000), dim3(512), 0, stream>>>(xb, wg_b, bg, out, nullptr,
                                                       2048, 32000, 1024, 8, 0);
}

// Round 16
// 1253.325 us; speedup vs baseline: 1.0006x; 1.0006x over previous
//
#include <hip/hip_runtime.h>
#include <hip/hip_bf16.h>
#include <cstdint>

// Problem dims
// L=6, E=1024, H=16, F=4096, V=32000, B=4, S=512, ML=512, DH=64, tokens=2048

typedef float f32x4 __attribute__((ext_vector_type(4)));
typedef short s16x8 __attribute__((ext_vector_type(8)));
typedef __bf16 b16x8 __attribute__((ext_vector_type(8)));

struct Frag8 {
    s16x8 v;
    __device__ operator s16x8() const { return v; }
    __device__ operator b16x8() const { return __builtin_bit_cast(b16x8, v); }
};

__device__ __forceinline__ f32x4 mfma16(Frag8 a, Frag8 b, f32x4 c) {
    return __builtin_amdgcn_mfma_f32_16x16x32_bf16(a, b, c, 0, 0, 0);
}

__device__ __forceinline__ void gload_lds16(const void* g, void* l) {
    __builtin_amdgcn_global_load_lds(
        (__attribute__((address_space(1))) void*)g,
        (__attribute__((address_space(3))) void*)l, 16, 0, 0);
}

__device__ __forceinline__ unsigned short bf16bits(float x) {
    return __builtin_bit_cast(unsigned short, __float2bfloat16(x));
}

// ---------------- fused fp32 -> bf16 conversion (5 segments, 8 elems/thread) ----------------
__global__ __launch_bounds__(256) void k_conv5(const float* __restrict__ s0, const float* __restrict__ s1,
                                               const float* __restrict__ s2, const float* __restrict__ s3,
                                               const float* __restrict__ s4,
                                               __hip_bfloat16* __restrict__ d0, __hip_bfloat16* __restrict__ d1,
                                               __hip_bfloat16* __restrict__ d2, __hip_bfloat16* __restrict__ d3,
                                               __hip_bfloat16* __restrict__ d4,
                                               int b0, int b1, int b2, int b3) {
    const int blk = blockIdx.x;
    const float* src;
    __hip_bfloat16* dst;
    long base;
    if (blk < b0)      { src = s0; dst = d0; base = (long)blk * 2048; }
    else if (blk < b1) { src = s1; dst = d1; base = (long)(blk - b0) * 2048; }
    else if (blk < b2) { src = s2; dst = d2; base = (long)(blk - b1) * 2048; }
    else if (blk < b3) { src = s3; dst = d3; base = (long)(blk - b2) * 2048; }
    else               { src = s4; dst = d4; base = (long)(blk - b3) * 2048; }
    const long i = base + (long)threadIdx.x * 8;
    const float4 v0 = *(const float4*)(src + i);
    const float4 v1 = *(const float4*)(src + i + 4);
    s16x8 u;
    u[0] = (short)bf16bits(v0.x); u[1] = (short)bf16bits(v0.y);
    u[2] = (short)bf16bits(v0.z); u[3] = (short)bf16bits(v0.w);
    u[4] = (short)bf16bits(v1.x); u[5] = (short)bf16bits(v1.y);
    u[6] = (short)bf16bits(v1.z); u[7] = (short)bf16bits(v1.w);
    *(s16x8*)((unsigned short*)dst + i) = u;
}

// ---------------- bias pre-extraction: dist_emb[(i,h)] -> biasT[h][i] ----------------
__global__ __launch_bounds__(256) void k_bias_prep(const float* __restrict__ dist_emb,
                                                   float* __restrict__ biasT) {
    const int h = blockIdx.x;
    for (int i = threadIdx.x; i < 513; i += 256) biasT[h * 513 + i] = dist_emb[i * 16 + h];
}

// ---------------- embedding gather ----------------
__global__ __launch_bounds__(256) void k_embed(const int* __restrict__ seq,
                                               const float* __restrict__ tok,
                                               float* __restrict__ x,
                                               __hip_bfloat16* __restrict__ xb) {
    const int t = blockIdx.x;
    const int tokid = seq[t];
    const float4 v = *(const float4*)(tok + (size_t)tokid * 1024 + threadIdx.x * 4);
    float4 o;
    o.x = v.x * 32.0f; o.y = v.y * 32.0f; o.z = v.z * 32.0f; o.w = v.w * 32.0f;
    *(float4*)(x + (size_t)t * 1024 + threadIdx.x * 4) = o;
    ushort4 u;
    u.x = bf16bits(o.x); u.y = bf16bits(o.y); u.z = bf16bits(o.z); u.w = bf16bits(o.w);
    *(ushort4*)((unsigned short*)xb + (size_t)t * 1024 + threadIdx.x * 4) = u;
}

// ---------------- V transpose: qkv V-part -> vT[b,h,d,s] (LDS-tiled, coalesced) ----------------
__global__ __launch_bounds__(256) void k_vtrans(const __hip_bfloat16* __restrict__ qkv,
                                                __hip_bfloat16* __restrict__ vT) {
    const int st = blockIdx.x;
    const int bh = blockIdx.y;
    const int b = bh >> 4, h = bh & 15;
    __shared__ __align__(16) short T[64][72];
    const int tid = threadIdx.x;
#pragma unroll
    for (int i = 0; i < 2; ++i) {
        const int c = i * 256 + tid;
        const int s = c >> 3, d0 = (c & 7) * 8;
        const s16x8 v = *(const s16x8*)(qkv + (size_t)(b * 512 + st * 64 + s) * 3072 + 2048 + h * 64 + d0);
#pragma unroll
        for (int j = 0; j < 8; ++j) T[d0 + j][s] = v[j];
    }
    __syncthreads();
#pragma unroll
    for (int i = 0; i < 2; ++i) {
        const int c = i * 256 + tid;
        const int d = c >> 3, s0 = (c & 7) * 8;
        const s16x8 v = *(const s16x8*)&T[d][s0];
        *(s16x8*)(vT + ((size_t)bh * 64 + d) * 512 + st * 64 + s0) = v;
    }
}

// ============ 256x256-tile 8-wave phase-interleaved GEMM (vocab) ============
// Round-4 schedule with the pre-MFMA barrier removed (4 barriers/K-tile).
template <int TAG>
__global__ __launch_bounds__(512, 2) void k_gemm256(const __hip_bfloat16* __restrict__ A,
                                                    const __hip_bfloat16* __restrict__ B,
                                                    const float* __restrict__ bias,
                                                    float* __restrict__ Cf,
                                                    __hip_bfloat16* __restrict__ Cb,
                                                    const int M, const int N, const int K,
                                                    const int mtiles, const int act) {
    __shared__ __align__(16) char lds[131072];  // [buf][A 32KB | B 32KB] x2

    const int nwg = gridDim.x, bid = blockIdx.x;
    const int qq = nwg >> 3, rr = nwg & 7;
    const int xcd = bid & 7, local = bid >> 3;
    const int wgid = (xcd < rr ? xcd * (qq + 1) : rr * (qq + 1) + (xcd - rr) * qq) + local;
    const int m0 = (wgid % mtiles) * 256;
    const int n0 = (wgid / mtiles) * 256;

    const int tid = threadIdx.x;
    const int lane = tid & 63;
    const int wid = tid >> 6;
    const int wr = wid >> 2, wc = wid & 3;
    const int l16 = lane & 15, lq = lane >> 4;
    const int sw = l16 & 7;

    const int srow = tid >> 3;
    const int scol = ((tid & 7) ^ (srow & 7)) << 3;
    const __hip_bfloat16* aS = A + (size_t)(m0 + srow) * K + scol;
    const __hip_bfloat16* bS = B + (size_t)(n0 + srow) * K + scol;
    const size_t rstep = (size_t)64 * K;

    const int NT = K >> 6;
    const int arow = wr * 128 + l16;
    const int brow = wc * 64 + l16;

    auto stage = [&](int d, int isB, int blk, int kk) {
        const __hip_bfloat16* src = (isB ? bS : aS) + (size_t)blk * rstep + kk;
        char* dst = lds + d * 65536 + isB * 32768 + blk * 8192 + tid * 16;
        gload_lds16(src, dst);
    };

    stage(0, 1, 0, 0); stage(0, 1, 1, 0);
    stage(0, 1, 2, 0); stage(0, 1, 3, 0);
    stage(0, 0, 0, 0); stage(0, 0, 2, 0);
    stage(0, 0, 1, 0); stage(0, 0, 3, 0);
    asm volatile("s_waitcnt vmcnt(2)" ::: "memory");
    __builtin_amdgcn_sched_barrier(0);
    __builtin_amdgcn_s_barrier();
    __builtin_amdgcn_sched_barrier(0);

    f32x4 acc[8][4] = {};
    Frag8 bfr[2][4];

    for (int t = 0; t < NT; ++t) {
        const int d = t & 1;
        const char* Ab = lds + d * 65536;
        const char* Bb = Ab + 32768;
        const bool st = (t + 1 < NT);
        const int k1 = (t + 1) << 6;

#pragma unroll
        for (int q = 0; q < 4; ++q) {
            if (q == 0) {
#pragma unroll
                for (int ks = 0; ks < 2; ++ks)
#pragma unroll
                    for (int ni = 0; ni < 4; ++ni)
                        bfr[ks][ni].v = *(const s16x8*)(
                            Bb + (brow + ni * 16) * 128 + (((ks * 4 + lq) ^ sw) << 4));
            }
            Frag8 af[2][2];
#pragma unroll
            for (int m2 = 0; m2 < 2; ++m2)
#pragma unroll
                for (int ks = 0; ks < 2; ++ks)
                    af[m2][ks].v = *(const s16x8*)(
                        Ab + (arow + (q * 2 + m2) * 16) * 128 + (((ks * 4 + lq) ^ sw) << 4));

            if (st) {
                if (q == 0)      { stage(d ^ 1, 1, 0, k1); stage(d ^ 1, 1, 1, k1); }
                else if (q == 1) { stage(d ^ 1, 1, 2, k1); stage(d ^ 1, 1, 3, k1); }
                else if (q == 2) { stage(d ^ 1, 0, 0, k1); stage(d ^ 1, 0, 2, k1); }
                else             { stage(d ^ 1, 0, 1, k1); stage(d ^ 1, 0, 3, k1); }
            }

            // no pre-MFMA barrier: compiler inserts lgkmcnt for the ds_read deps
            __builtin_amdgcn_sched_barrier(0);
            __builtin_amdgcn_s_setprio(1);
#pragma unroll
            for (int ks = 0; ks < 2; ++ks)
#pragma unroll
                for (int m2 = 0; m2 < 2; ++m2)
#pragma unroll
                    for (int ni = 0; ni < 4; ++ni)
                        acc[q * 2 + m2][ni] = mfma16(af[m2][ks], bfr[ks][ni], acc[q * 2 + m2][ni]);
            __builtin_amdgcn_s_setprio(0);
            __builtin_amdgcn_sched_barrier(0);
            if (q == 1) {
                if (st) asm volatile("s_waitcnt vmcnt(4)" ::: "memory");
                else    asm volatile("s_waitcnt vmcnt(0)" ::: "memory");
            } else if (q == 3) {
                if (st) asm volatile("s_waitcnt vmcnt(2)" ::: "memory");
                else    asm volatile("s_waitcnt vmcnt(0)" ::: "memory");
            }
            __builtin_amdgcn_s_barrier();
            __builtin_amdgcn_sched_barrier(0);
        }
    }

#pragma unroll
    for (int mi = 0; mi < 8; ++mi) {
        const int rowb = m0 + wr * 128 + mi * 16 + lq * 4;
#pragma unroll
        for (int ni = 0; ni < 4; ++ni) {
            const int col = n0 + wc * 64 + ni * 16 + l16;
            const float bv = bias[col];
#pragma unroll
            for (int r = 0; r < 4; ++r) {
                float v2 = acc[mi][ni][r] + bv;
                if (act == 1) v2 = 0.5f * v2 * (1.0f + erff(v2 * 0.70710678118654752f));
                const size_t idx = (size_t)(rowb + r) * N + col;
                if (Cf) Cf[idx] = v2;
                if (Cb) Cb[idx] = __float2bfloat16(v2);
            }
        }
    }
}

// ============ 256x128-tile 8-wave barrier-free GEMM (FFN1 / FFN2 split-K) ============
// BK=64, 2 LDS buffers x 48KB (A 4x8KB blocks | B 2x8KB blocks). 8 waves as 2x4:
// wave = 128 rows x 32 cols, acc[8][2]. 4 phases/K-tile, 8 MFMA each. 6-load
// ledger: A-blocks 1,3 staged last; waits vmcnt(4) @q1-end, vmcnt(2) @q3-end.
// grid.y = split-K slice (f32 partials via Cf; bias only in slice 0).
template <int TAG>
__global__ __launch_bounds__(512, 2) void k_gemm256n(const __hip_bfloat16* __restrict__ A,
                                                     const __hip_bfloat16* __restrict__ B,
                                                     const float* __restrict__ bias,
                                                     float* __restrict__ Cf,
                                                     __hip_bfloat16* __restrict__ Cb,
                                                     const int M, const int N, const int K,
                                                     const int Ksub, const int mtiles,
                                                     const int act) {
    __shared__ __align__(16) char lds[98304];  // 2 bufs x (A 32KB | B 16KB)

    const int nwg = gridDim.x, bid = blockIdx.x;
    const int qq = nwg >> 3, rr = nwg & 7;
    const int xcd = bid & 7, local = bid >> 3;
    const int wgid = (xcd < rr ? xcd * (qq + 1) : rr * (qq + 1) + (xcd - rr) * qq) + local;
    const int m0 = (wgid % mtiles) * 256;
    const int n0 = (wgid / mtiles) * 128;

    const int tid = threadIdx.x;
    const int lane = tid & 63;
    const int wid = tid >> 6;
    const int wr = wid >> 2, wc = wid & 3;     // 2 row-waves x 4 col-waves
    const int l16 = lane & 15, lq = lane >> 4;
    const int sw = l16 & 7;

    const int kb = blockIdx.y * Ksub;
    const int srow = tid >> 3;
    const int scol = ((tid & 7) ^ (srow & 7)) << 3;
    const __hip_bfloat16* aS = A + (size_t)(m0 + srow) * K + scol + kb;
    const __hip_bfloat16* bS = B + (size_t)(n0 + srow) * K + scol + kb;
    const size_t rstep = (size_t)64 * K;

    const int NT = Ksub >> 6;
    const int arow = wr * 128 + l16;
    const int brow = wc * 32 + l16;

    auto stage = [&](int d, int isB, int blk, int kk) {
        const __hip_bfloat16* src = (isB ? bS : aS) + (size_t)blk * rstep + kk;
        char* dst = lds + d * 49152 + isB * 32768 + blk * 8192 + tid * 16;
        gload_lds16(src, dst);
    };

    // prologue: stage K-tile 0, order = [B0,B1, A0,A2, A1,A3]
    stage(0, 1, 0, 0); stage(0, 1, 1, 0);
    stage(0, 0, 0, 0); stage(0, 0, 2, 0);
    stage(0, 0, 1, 0); stage(0, 0, 3, 0);
    asm volatile("s_waitcnt vmcnt(2)" ::: "memory");  // B + A0,A2 landed; A1,A3 in flight
    __builtin_amdgcn_sched_barrier(0);
    __builtin_amdgcn_s_barrier();
    __builtin_amdgcn_sched_barrier(0);

    f32x4 acc[8][2] = {};
    Frag8 bfr[2][2];

    for (int t = 0; t < NT; ++t) {
        const int d = t & 1;
        const char* Ab = lds + d * 49152;
        const char* Bb = Ab + 32768;
        const bool st = (t + 1 < NT);
        const int k1 = (t + 1) << 6;

#pragma unroll
        for (int q = 0; q < 4; ++q) {
            if (q == 0) {
#pragma unroll
                for (int ks = 0; ks < 2; ++ks)
#pragma unroll
                    for (int ni = 0; ni < 2; ++ni)
                        bfr[ks][ni].v = *(const s16x8*)(
                            Bb + (brow + ni * 16) * 128 + (((ks * 4 + lq) ^ sw) << 4));
            }
            Frag8 af[2][2];
#pragma unroll
            for (int m2 = 0; m2 < 2; ++m2)
#pragma unroll
                for (int ks = 0; ks < 2; ++ks)
                    af[m2][ks].v = *(const s16x8*)(
                        Ab + (arow + (q * 2 + m2) * 16) * 128 + (((ks * 4 + lq) ^ sw) << 4));

            if (st) {
                if (q == 0)      { stage(d ^ 1, 1, 0, k1); stage(d ^ 1, 1, 1, k1); }
                else if (q == 1) { stage(d ^ 1, 0, 0, k1); stage(d ^ 1, 0, 2, k1); }
                else if (q == 2) { stage(d ^ 1, 0, 1, k1); stage(d ^ 1, 0, 3, k1); }
            }

            __builtin_amdgcn_sched_barrier(0);
            __builtin_amdgcn_s_setprio(1);
#pragma unroll
            for (int ks = 0; ks < 2; ++ks)
#pragma unroll
                for (int m2 = 0; m2 < 2; ++m2)
#pragma unroll
                    for (int ni = 0; ni < 2; ++ni)
                        acc[q * 2 + m2][ni] = mfma16(af[m2][ks], bfr[ks][ni], acc[q * 2 + m2][ni]);
            __builtin_amdgcn_s_setprio(0);
            __builtin_amdgcn_sched_barrier(0);
            if (q == 1) {
                if (st) asm volatile("s_waitcnt vmcnt(4)" ::: "memory");
                else    asm volatile("s_waitcnt vmcnt(0)" ::: "memory");
            } else if (q == 3) {
                if (st) asm volatile("s_waitcnt vmcnt(2)" ::: "memory");
                else    asm volatile("s_waitcnt vmcnt(0)" ::: "memory");
            }
            __builtin_amdgcn_s_barrier();
            __builtin_amdgcn_sched_barrier(0);
        }
    }

    float* Cfp = Cf ? Cf + (size_t)blockIdx.y * M * N : nullptr;
    const bool addb = (blockIdx.y == 0);

    // epilogue: C/D layout col=lane&15, row=(lane>>4)*4+r
#pragma unroll
    for (int mi = 0; mi < 8; ++mi) {
        const int rowb = m0 + wr * 128 + mi * 16 + lq * 4;
#pragma unroll
        for (int ni = 0; ni < 2; ++ni) {
            const int col = n0 + wc * 32 + ni * 16 + l16;
            const float bv = addb ? bias[col] : 0.0f;
#pragma unroll
            for (int r = 0; r < 4; ++r) {
                float v2 = acc[mi][ni][r] + bv;
                if (act == 1) v2 = 0.5f * v2 * (1.0f + erff(v2 * 0.70710678118654752f));
                const size_t idx = (size_t)(rowb + r) * N + col;
                if (Cfp) Cfp[idx] = v2;
                if (Cb) Cb[idx] = __float2bfloat16(v2);
            }
        }
    }
}

// ============ 128x128-tile pipelined GEMM (QKV, Wo, fallback) ============
__device__ __forceinline__ const s16x8* fragp(const char* base, int row, int lq) {
    const int line = row >> 1;
    const int u = ((row & 1) << 2) | lq;
    return (const s16x8*)(base + line * 128 + ((u ^ (line & 7)) << 4));
}

template <int TAG>
__global__ __launch_bounds__(256, 2) void k_gemm(const __hip_bfloat16* __restrict__ A,
                                                 const __hip_bfloat16* __restrict__ B,
                                                 const float* __restrict__ bias,
                                                 float* __restrict__ Cf,
                                                 __hip_bfloat16* __restrict__ Cb,
                                                 const int M, const int N, const int K,
                                                 const int Ksub, const int mtiles,
                                                 const int act) {
    __shared__ __align__(16) char lds[3 * 16384];

    const int nwg = gridDim.x;
    const int bid = blockIdx.x;
    const int q = nwg >> 3, r = nwg & 7;
    const int xcd = bid & 7, local = bid >> 3;
    const int wgid = (xcd < r ? xcd * (q + 1) : r * (q + 1) + (xcd - r) * q) + local;
    const int m0 = (wgid % mtiles) * 128;
    const int n0 = (wgid / mtiles) * 128;

    const int tid = threadIdx.x;
    const int lane = tid & 63, w = tid >> 6;
    const int wr = w >> 1, wc = w & 1;
    const int l16 = lane & 15, lq = lane >> 4;

    const int kb = blockIdx.y * Ksub;
    const int NT = Ksub >> 5;

    int arow0, acol0, arow1, acol1;
    {
        const int c0 = tid, line0 = c0 >> 3, u0 = (c0 & 7) ^ (line0 & 7);
        arow0 = (line0 << 1) | (u0 >> 2); acol0 = (u0 & 3) * 8;
        const int c1 = tid + 256, line1 = c1 >> 3, u1 = (c1 & 7) ^ (line1 & 7);
        arow1 = (line1 << 1) | (u1 >> 2); acol1 = (u1 & 3) * 8;
    }
    const size_t abase0 = (size_t)(m0 + arow0) * K + acol0 + kb;
    const size_t abase1 = (size_t)(m0 + arow1) * K + acol1 + kb;
    const size_t bbase0 = (size_t)(n0 + arow0) * K + acol0 + kb;
    const size_t bbase1 = (size_t)(n0 + arow1) * K + acol1 + kb;

    auto stageA = [&](int tt, int buf) {
        char* dst = lds + buf * 16384;
        gload_lds16(A + abase0 + tt * 32, dst + tid * 16);
        gload_lds16(A + abase1 + tt * 32, dst + (tid + 256) * 16);
    };
    auto stageB = [&](int tt, int buf) {
        char* dst = lds + buf * 16384 + 8192;
        gload_lds16(B + bbase0 + tt * 32, dst + tid * 16);
        gload_lds16(B + bbase1 + tt * 32, dst + (tid + 256) * 16);
    };

    f32x4 acc[4][4] = {};

    stageA(0, 0); stageB(0, 0);
    stageA(1, 1); stageB(1, 1);
    asm volatile("s_waitcnt vmcnt(4)" ::: "memory");
    __builtin_amdgcn_sched_barrier(0);
    __builtin_amdgcn_s_barrier();
    __builtin_amdgcn_sched_barrier(0);

    int cur = 0;
    for (int t = 0; t < NT; ++t) {
        const int stb = (cur == 0) ? 2 : cur - 1;
        const char* Ab = lds + cur * 16384;
        const char* Bb = Ab + 8192;
        const bool doStage = (t + 2 < NT);

        if (doStage) stageA(t + 2, stb);

        Frag8 a0, a1, b0, b1, b2, b3;
        a0.v = *fragp(Ab, wr * 64 + l16, lq);
        a1.v = *fragp(Ab, wr * 64 + 16 + l16, lq);
        b0.v = *fragp(Bb, wc * 64 + l16, lq);
        b1.v = *fragp(Bb, wc * 64 + 16 + l16, lq);
        b2.v = *fragp(Bb, wc * 64 + 32 + l16, lq);
        b3.v = *fragp(Bb, wc * 64 + 48 + l16, lq);

        __builtin_amdgcn_s_setprio(1);
        acc[0][0] = mfma16(a0, b0, acc[0][0]);
        acc[0][1] = mfma16(a0, b1, acc[0][1]);
        acc[0][2] = mfma16(a0, b2, acc[0][2]);
        acc[0][3] = mfma16(a0, b3, acc[0][3]);
        acc[1][0] = mfma16(a1, b0, acc[1][0]);
        acc[1][1] = mfma16(a1, b1, acc[1][1]);
        acc[1][2] = mfma16(a1, b2, acc[1][2]);
        acc[1][3] = mfma16(a1, b3, acc[1][3]);
        __builtin_amdgcn_s_setprio(0);

        if (doStage) stageB(t + 2, stb);

        Frag8 a2, a3;
        a2.v = *fragp(Ab, wr * 64 + 32 + l16, lq);
        a3.v = *fragp(Ab, wr * 64 + 48 + l16, lq);

        __builtin_amdgcn_s_setprio(1);
        acc[2][0] = mfma16(a2, b0, acc[2][0]);
        acc[2][1] = mfma16(a2, b1, acc[2][1]);
        acc[2][2] = mfma16(a2, b2, acc[2][2]);
        acc[2][3] = mfma16(a2, b3, acc[2][3]);
        acc[3][0] = mfma16(a3, b0, acc[3][0]);
        acc[3][1] = mfma16(a3, b1, acc[3][1]);
        acc[3][2] = mfma16(a3, b2, acc[3][2]);
        acc[3][3] = mfma16(a3, b3, acc[3][3]);
        __builtin_amdgcn_s_setprio(0);

        if (t + 3 < NT) {
            asm volatile("s_waitcnt vmcnt(4)" ::: "memory");
        } else {
            asm volatile("s_waitcnt vmcnt(0)" ::: "memory");
        }
        __builtin_amdgcn_sched_barrier(0);
        __builtin_amdgcn_s_barrier();
        __builtin_amdgcn_sched_barrier(0);

        cur = (cur == 2) ? 0 : cur + 1;
    }

    float* Cfp = Cf ? Cf + (size_t)blockIdx.y * M * N : nullptr;
    const bool addb = (blockIdx.y == 0);

#pragma unroll
    for (int mi = 0; mi < 4; ++mi) {
        const int rowb = m0 + wr * 64 + mi * 16 + lq * 4;
#pragma unroll
        for (int ni = 0; ni < 4; ++ni) {
            const int col = n0 + wc * 64 + ni * 16 + l16;
            const float bv = addb ? bias[col] : 0.0f;
#pragma unroll
            for (int rr = 0; rr < 4; ++rr) {
                float v2 = acc[mi][ni][rr] + bv;
                if (act == 1) v2 = 0.5f * v2 * (1.0f + erff(v2 * 0.70710678118654752f));
                const size_t idx = (size_t)(rowb + rr) * N + col;
                if (Cfp) Cfp[idx] = v2;
                if (Cb) Cb[idx] = __float2bfloat16(v2);
            }
        }
    }
}

// ---------------- flash attention (round-11 compute, CU-load-balanced remap) ----------------
__global__ __launch_bounds__(256) void k_attn(const __hip_bfloat16* __restrict__ qkv,
                                              const __hip_bfloat16* __restrict__ vT,
                                              const int* __restrict__ seq,
                                              const float* __restrict__ biasT,
                                              __hip_bfloat16* __restrict__ out) {
    const int f = blockIdx.x;
    const int half = f >> 8;
    const int qb = half ? (7 - (f & 7)) : (f & 7);
    const int hb = ((f & 255) >> 3) + (half << 5);
    const int h = hb & 15, b = hb >> 4;
    const int q0 = qb * 64;
    const int tid = threadIdx.x, lane = tid & 63, w = tid >> 6;
    const int l16 = lane & 15, lq = lane >> 4;

    __shared__ __align__(16) char Ks[2 * 8192];
    __shared__ __align__(16) char Vs[2 * 8192];
    __shared__ __align__(16) char Ps[4 * 2048];
    __shared__ float bias_l[513];
    __shared__ float pad_l[512];

    for (int i = tid; i < 513; i += 256) bias_l[i] = biasT[h * 513 + i];
    for (int i = tid; i < 512; i += 256) pad_l[i] = (seq[b * 512 + i] == 0) ? -1e9f : 0.0f;

    const int qrowA = q0 + w * 16 + l16;
    const __hip_bfloat16* qptr = qkv + (size_t)(b * 512 + qrowA) * 3072 + h * 64;
    Frag8 qf[2];
    qf[0].v = *(const s16x8*)(qptr + lq * 8);
    qf[1].v = *(const s16x8*)(qptr + 32 + lq * 8);

    const int kr0 = tid >> 3, sl = tid & 7;
    const int kr1 = kr0 + 32;
    char* kdst0 = Ks + kr0 * 128 + ((sl ^ (kr0 & 7)) * 16);
    char* kdst1 = Ks + kr1 * 128 + ((sl ^ (kr1 & 7)) * 16);
    char* vdst0 = Vs + kr0 * 128 + ((sl ^ (kr0 & 7)) * 16);
    char* vdst1 = Vs + kr1 * 128 + ((sl ^ (kr1 & 7)) * 16);
    const __hip_bfloat16* vbase = vT + (size_t)(b * 16 + h) * 64 * 512;

    s16x8 kreg0, kreg1, vreg0, vreg1;
    auto load_regs = [&](int kt) {
        const size_t kb_ = (size_t)(b * 512 + kt * 64) * 3072 + h * 64 + 1024;
        kreg0 = *(const s16x8*)(qkv + kb_ + (size_t)kr0 * 3072 + sl * 8);
        kreg1 = *(const s16x8*)(qkv + kb_ + (size_t)kr1 * 3072 + sl * 8);
        vreg0 = *(const s16x8*)(vbase + (size_t)kr0 * 512 + kt * 64 + sl * 8);
        vreg1 = *(const s16x8*)(vbase + (size_t)kr1 * 512 + kt * 64 + sl * 8);
    };

    f32x4 oacc[4] = {};
    float mrow[4] = {-1e30f, -1e30f, -1e30f, -1e30f};
    float lrow[4] = {0.f, 0.f, 0.f, 0.f};
    char* PsW = Ps + w * 2048;

    load_regs(0);
    for (int kt = 0; kt <= qb; ++kt) {
        const int bo = (kt & 1) * 8192;
        *(s16x8*)(kdst0 + bo) = kreg0;
        *(s16x8*)(kdst1 + bo) = kreg1;
        *(s16x8*)(vdst0 + bo) = vreg0;
        *(s16x8*)(vdst1 + bo) = vreg1;
        __syncthreads();
        if (kt < qb) load_regs(kt + 1);

        const char* Kb = Ks + bo;
        const char* Vb = Vs + bo;

        f32x4 sacc[4] = {};
#pragma unroll
        for (int ks = 0; ks < 2; ++ks) {
#pragma unroll
            for (int nf = 0; nf < 4; ++nf) {
                const int key = nf * 16 + l16;
                Frag8 kf;
                kf.v = *(const s16x8*)(Kb + key * 128 + (((ks * 4 + lq) ^ (key & 7)) * 16));
                sacc[nf] = mfma16(qf[ks], kf, sacc[nf]);
            }
        }

        float pvv[4][4];
#pragma unroll
        for (int nf = 0; nf < 4; ++nf) {
            const int keyg = kt * 64 + nf * 16 + l16;
            const float padv = pad_l[keyg];
#pragma unroll
            for (int rr = 0; rr < 4; ++rr) {
                const int qg = q0 + w * 16 + lq * 4 + rr;
                pvv[nf][rr] = (keyg > qg) ? -1e9f
                            : sacc[nf][rr] * 0.125f + bias_l[qg - keyg] + padv;
            }
        }

#pragma unroll
        for (int rr = 0; rr < 4; ++rr) {
            float tm = fmaxf(fmaxf(pvv[0][rr], pvv[1][rr]), fmaxf(pvv[2][rr], pvv[3][rr]));
#pragma unroll
            for (int off = 1; off < 16; off <<= 1) tm = fmaxf(tm, __shfl_xor(tm, off, 64));
            const float mnew = fmaxf(mrow[rr], tm);
            const float sf = __expf(mrow[rr] - mnew);
            mrow[rr] = mnew;
            float ts = 0.f;
#pragma unroll
            for (int nf = 0; nf < 4; ++nf) {
                const float pe = __expf(pvv[nf][rr] - mnew);
                pvv[nf][rr] = pe;
                ts += pe;
            }
#pragma unroll
            for (int off = 1; off < 16; off <<= 1) ts += __shfl_xor(ts, off, 64);
            lrow[rr] = lrow[rr] * sf + ts;
            oacc[0][rr] *= sf; oacc[1][rr] *= sf; oacc[2][rr] *= sf; oacc[3][rr] *= sf;
        }

#pragma unroll
        for (int nf = 0; nf < 4; ++nf) {
            const int cc = nf * 16 + l16;
            const int slot = cc >> 3, rem = cc & 7;
#pragma unroll
            for (int rr = 0; rr < 4; ++rr) {
                const int row = lq * 4 + rr;
                *(short*)(PsW + row * 128 + ((slot ^ (row & 7)) * 16) + rem * 2) =
                    (short)bf16bits(pvv[nf][rr]);
            }
        }

#pragma unroll
        for (int ks = 0; ks < 2; ++ks) {
            Frag8 pf;
            pf.v = *(const s16x8*)(PsW + l16 * 128 + (((ks * 4 + lq) ^ (l16 & 7)) * 16));
#pragma unroll
            for (int nf = 0; nf < 4; ++nf) {
                const int d = nf * 16 + l16;
                Frag8 vf;
                vf.v = *(const s16x8*)(Vb + d * 128 + (((ks * 4 + lq) ^ (d & 7)) * 16));
                oacc[nf] = mfma16(pf, vf, oacc[nf]);
            }
        }
    }

#pragma unroll
    for (int nf = 0; nf < 4; ++nf) {
        const int d = nf * 16 + l16;
#pragma unroll
        for (int rr = 0; rr < 4; ++rr) {
            const int qg = q0 + w * 16 + lq * 4 + rr;
            out[(size_t)(b * 512 + qg) * 1024 + h * 64 + d] = __float2bfloat16(oacc[nf][rr] / lrow[rr]);
        }
    }
}

// ---------------- fused residual add (up to 4 partials) + LayerNorm ----------------
__global__ __launch_bounds__(256) void k_add_ln(const float* __restrict__ x,
                                                const float* __restrict__ res0,
                                                const float* __restrict__ res1,
                                                const float* __restrict__ res2,
                                                const float* __restrict__ res3,
                                                const float* __restrict__ gamma,
                                                const float* __restrict__ beta,
                                                float* __restrict__ xout,
                                                __hip_bfloat16* __restrict__ bout) {
    const int t = blockIdx.x;
    const int tid = threadIdx.x;
    float4 y = *(const float4*)(x + (size_t)t * 1024 + tid * 4);
    const float* rs[4] = {res0, res1, res2, res3};
#pragma unroll
    for (int k = 0; k < 4; ++k) {
        if (rs[k]) {
            const float4 rv = *(const float4*)(rs[k] + (size_t)t * 1024 + tid * 4);
            y.x += rv.x; y.y += rv.y; y.z += rv.z; y.w += rv.w;
        }
    }
    float s = y.x + y.y + y.z + y.w;
    float s2 = y.x * y.x + y.y * y.y + y.z * y.z + y.w * y.w;
#pragma unroll
    for (int off = 32; off >= 1; off >>= 1) {
        s += __shfl_xor(s, off, 64);
        s2 += __shfl_xor(s2, off, 64);
    }
    __shared__ float red[8];
    const int w = tid >> 6, lane = tid & 63;
    if (lane == 0) { red[w] = s; red[4 + w] = s2; }
    __syncthreads();
    const float tot = red[0] + red[1] + red[2] + red[3];
    const float tot2 = red[4] + red[5] + red[6] + red[7];
    const float mean = tot * (1.0f / 1024.0f);
    const float var = tot2 * (1.0f / 1024.0f) - mean * mean;
    const float inv = rsqrtf(var + 1e-5f);
    const float4 g = *(const float4*)(gamma + tid * 4);
    const float4 bb = *(const float4*)(beta + tid * 4);
    float4 o;
    o.x = (y.x - mean) * inv * g.x + bb.x;
    o.y = (y.y - mean) * inv * g.y + bb.y;
    o.z = (y.z - mean) * inv * g.z + bb.z;
    o.w = (y.w - mean) * inv * g.w + bb.w;
    *(float4*)(xout + (size_t)t * 1024 + tid * 4) = o;
    ushort4 u;
    u.x = bf16bits(o.x); u.y = bf16bits(o.y); u.z = bf16bits(o.z); u.w = bf16bits(o.w);
    *(ushort4*)((unsigned short*)bout + (size_t)t * 1024 + tid * 4) = u;
}

// ---------------- host ----------------
extern "C" void kernel_launch(void* const* d_in, const int* in_sizes, int n_in,
                              void* d_out, int out_size, void* d_ws, size_t ws_size,
                              hipStream_t stream) {
    const int* seq = (const int*)d_in[0];
    const float* tok = (const float*)d_in[1];
    const float* dist = (const float*)d_in[2];
    const float* Wqkv = (const float*)d_in[3];
    const float* bqkv = (const float*)d_in[4];
    const float* Wo = (const float*)d_in[5];
    const float* bo = (const float*)d_in[6];
    const float* W1 = (const float*)d_in[7];
    const float* b1 = (const float*)d_in[8];
    const float* W2 = (const float*)d_in[9];
    const float* b2 = (const float*)d_in[10];
    const float* ln1s = (const float*)d_in[11];
    const float* ln1b = (const float*)d_in[12];
    const float* ln2s = (const float*)d_in[13];
    const float* ln2b = (const float*)d_in[14];
    const float* lnfs = (const float*)d_in[15];
    const float* lnfb = (const float*)d_in[16];
    const float* Wg = (const float*)d_in[17];
    const float* bg = (const float*)d_in[18];
    float* out = (float*)d_out;

    const size_t base_need = (size_t)300 * 1024 * 1024;
    const int ffn2_splits = (ws_size >= base_need) ? 4 : 2;

    char* p = (char*)d_ws;
    auto take = [&](size_t bytes) {
        char* r = p;
        p += (bytes + 255) & ~(size_t)255;
        return r;
    };
    __hip_bfloat16* wqkv_b = (__hip_bfloat16*)take((size_t)6 * 3072 * 1024 * 2);
    __hip_bfloat16* wo_b = (__hip_bfloat16*)take((size_t)6 * 1024 * 1024 * 2);
    __hip_bfloat16* w1_b = (__hip_bfloat16*)take((size_t)6 * 4096 * 1024 * 2);
    __hip_bfloat16* w2_b = (__hip_bfloat16*)take((size_t)6 * 1024 * 4096 * 2);
    __hip_bfloat16* wg_b = (__hip_bfloat16*)take((size_t)32000 * 1024 * 2);
    float* xf = (float*)take((size_t)2048 * 1024 * 4);
    __hip_bfloat16* xb = (__hip_bfloat16*)take((size_t)2048 * 1024 * 2);
    __hip_bfloat16* qkvb = (__hip_bfloat16*)take((size_t)2048 * 3072 * 2);
    __hip_bfloat16* hb = (__hip_bfloat16*)take((size_t)2048 * 4096 * 2);
    __hip_bfloat16* ab = (__hip_bfloat16*)take((size_t)2048 * 1024 * 2);
    __hip_bfloat16* vTb = (__hip_bfloat16*)take((size_t)64 * 64 * 512 * 2);
    float* biasT = (float*)take((size_t)16 * 513 * 4);
    float* tmpf = (float*)take((size_t)ffn2_splits * 2048 * 1024 * 4);
    float* tmpf1 = tmpf + (size_t)2048 * 1024;
    float* tmpf2 = (ffn2_splits == 4) ? tmpf + (size_t)2 * 2048 * 1024 : nullptr;
    float* tmpf3 = (ffn2_splits == 4) ? tmpf + (size_t)3 * 2048 * 1024 : nullptr;

    k_conv5<<<dim3(52864), dim3(256), 0, stream>>>(
        Wqkv, Wo, W1, W2, Wg, wqkv_b, wo_b, w1_b, w2_b, wg_b,
        9216, 9216 + 3072, 9216 + 3072 + 12288, 9216 + 3072 + 12288 + 12288);
    k_bias_prep<<<dim3(16), dim3(256), 0, stream>>>(dist, biasT);
    k_embed<<<dim3(2048), dim3(256), 0, stream>>>(seq, tok, xf, xb);

    for (int l = 0; l < 6; ++l) {
        // QKV: 2048 x 3072 x 1024 (128^2 tiles: 384 wgs), bf16 out
        k_gemm<0><<<dim3(16 * 24), dim3(256), 0, stream>>>(
            xb, wqkv_b + (size_t)l * 3072 * 1024, bqkv + l * 3072, nullptr, qkvb,
            2048, 3072, 1024, 1024, 16, 0);
        k_vtrans<<<dim3(8, 64), dim3(256), 0, stream>>>(qkvb, vTb);
        k_attn<<<dim3(512), dim3(256), 0, stream>>>(qkvb, vTb, seq, biasT, ab);
        // Wo: 2048 x 1024 x 1024, 128^2 split-K=2 -> f32 partials
        k_gemm<1><<<dim3(16 * 8, 2), dim3(256), 0, stream>>>(
            ab, wo_b + (size_t)l * 1024 * 1024, bo + l * 1024, tmpf, nullptr,
            2048, 1024, 1024, 512, 16, 0);
        k_add_ln<<<dim3(2048), dim3(256), 0, stream>>>(xf, tmpf, tmpf1, nullptr, nullptr,
                                                       ln1s + l * 1024, ln1b + l * 1024, xf, xb);
        // FFN1: 2048 x 4096 x 1024 (256x128 tiles: 8 x 32 = 256 wgs, full coverage), GELU
        k_gemm256n<2><<<dim3(256), dim3(512), 0, stream>>>(
            xb, w1_b + (size_t)l * 4096 * 1024, b1 + l * 4096, nullptr, hb,
            2048, 4096, 1024, 1024, 8, 1);
        // FFN2: 2048 x 1024 x 4096
        if (ffn2_splits == 4) {
            // 256x128 tiles split-K=4: 64 x 4 = 256 wgs full coverage, NT=16
            k_gemm256n<3><<<dim3(64, 4), dim3(512), 0, stream>>>(
                hb, w2_b + (size_t)l * 1024 * 4096, b2 + l * 1024, tmpf, nullptr,
                2048, 1024, 4096, 1024, 8, 0);
        } else {
            k_gemm<3><<<dim3(16 * 8, 2), dim3(256), 0, stream>>>(
                hb, w2_b + (size_t)l * 1024 * 4096, b2 + l * 1024, tmpf, nullptr,
                2048, 1024, 4096, 2048, 16, 0);
        }
        k_add_ln<<<dim3(2048), dim3(256), 0, stream>>>(xf, tmpf, tmpf1, tmpf2, tmpf3,
                                                       ln2s + l * 1024, ln2b + l * 1024, xf, xb);
    }
    k_add_ln<<<dim3(2048), dim3(256), 0, stream>>>(xf, nullptr, nullptr, nullptr, nullptr,
                                                   lnfs, lnfb, xf, xb);
    // vocab: 2048 x 32000 x 1024 (256^2 tiles: 8 x 125 = 1000 wgs), f32 out
    k_gemm256<4><<<dim3(1000), dim3(512), 0, stream>>>(xb, wg_b, bg, out, nullptr,
                                                       2048, 32000, 1024, 8, 0);
}

// Round 17
// 1214.676 us; speedup vs baseline: 1.0325x; 1.0318x over previous
//
#include <hip/hip_runtime.h>
#include <hip/hip_bf16.h>
#include <cstdint>

// Problem dims
// L=6, E=1024, H=16, F=4096, V=32000, B=4, S=512, ML=512, DH=64, tokens=2048

typedef float f32x4 __attribute__((ext_vector_type(4)));
typedef short s16x8 __attribute__((ext_vector_type(8)));
typedef __bf16 b16x8 __attribute__((ext_vector_type(8)));

struct Frag8 {
    s16x8 v;
    __device__ operator s16x8() const { return v; }
    __device__ operator b16x8() const { return __builtin_bit_cast(b16x8, v); }
};

__device__ __forceinline__ f32x4 mfma16(Frag8 a, Frag8 b, f32x4 c) {
    return __builtin_amdgcn_mfma_f32_16x16x32_bf16(a, b, c, 0, 0, 0);
}

__device__ __forceinline__ void gload_lds16(const void* g, void* l) {
    __builtin_amdgcn_global_load_lds(
        (__attribute__((address_space(1))) void*)g,
        (__attribute__((address_space(3))) void*)l, 16, 0, 0);
}

__device__ __forceinline__ unsigned short bf16bits(float x) {
    return __builtin_bit_cast(unsigned short, __float2bfloat16(x));
}

__device__ __forceinline__ float b2f(unsigned short u) {
    unsigned int x = (unsigned int)u << 16;
    return __builtin_bit_cast(float, x);
}

// ---------------- fused fp32 -> bf16 conversion (5 segments, 8 elems/thread) ----------------
__global__ __launch_bounds__(256) void k_conv5(const float* __restrict__ s0, const float* __restrict__ s1,
                                               const float* __restrict__ s2, const float* __restrict__ s3,
                                               const float* __restrict__ s4,
                                               __hip_bfloat16* __restrict__ d0, __hip_bfloat16* __restrict__ d1,
                                               __hip_bfloat16* __restrict__ d2, __hip_bfloat16* __restrict__ d3,
                                               __hip_bfloat16* __restrict__ d4,
                                               int b0, int b1, int b2, int b3) {
    const int blk = blockIdx.x;
    const float* src;
    __hip_bfloat16* dst;
    long base;
    if (blk < b0)      { src = s0; dst = d0; base = (long)blk * 2048; }
    else if (blk < b1) { src = s1; dst = d1; base = (long)(blk - b0) * 2048; }
    else if (blk < b2) { src = s2; dst = d2; base = (long)(blk - b1) * 2048; }
    else if (blk < b3) { src = s3; dst = d3; base = (long)(blk - b2) * 2048; }
    else               { src = s4; dst = d4; base = (long)(blk - b3) * 2048; }
    const long i = base + (long)threadIdx.x * 8;
    const float4 v0 = *(const float4*)(src + i);
    const float4 v1 = *(const float4*)(src + i + 4);
    s16x8 u;
    u[0] = (short)bf16bits(v0.x); u[1] = (short)bf16bits(v0.y);
    u[2] = (short)bf16bits(v0.z); u[3] = (short)bf16bits(v0.w);
    u[4] = (short)bf16bits(v1.x); u[5] = (short)bf16bits(v1.y);
    u[6] = (short)bf16bits(v1.z); u[7] = (short)bf16bits(v1.w);
    *(s16x8*)((unsigned short*)dst + i) = u;
}

// ---------------- bias pre-extraction: dist_emb[(i,h)] -> biasT[h][i] ----------------
__global__ __launch_bounds__(256) void k_bias_prep(const float* __restrict__ dist_emb,
                                                   float* __restrict__ biasT) {
    const int h = blockIdx.x;
    for (int i = threadIdx.x; i < 513; i += 256) biasT[h * 513 + i] = dist_emb[i * 16 + h];
}

// ---------------- embedding gather ----------------
__global__ __launch_bounds__(256) void k_embed(const int* __restrict__ seq,
                                               const float* __restrict__ tok,
                                               float* __restrict__ x,
                                               __hip_bfloat16* __restrict__ xb) {
    const int t = blockIdx.x;
    const int tokid = seq[t];
    const float4 v = *(const float4*)(tok + (size_t)tokid * 1024 + threadIdx.x * 4);
    float4 o;
    o.x = v.x * 32.0f; o.y = v.y * 32.0f; o.z = v.z * 32.0f; o.w = v.w * 32.0f;
    *(float4*)(x + (size_t)t * 1024 + threadIdx.x * 4) = o;
    ushort4 u;
    u.x = bf16bits(o.x); u.y = bf16bits(o.y); u.z = bf16bits(o.z); u.w = bf16bits(o.w);
    *(ushort4*)((unsigned short*)xb + (size_t)t * 1024 + threadIdx.x * 4) = u;
}

// ---------------- V transpose: qkv V-part -> vT[b,h,d,s] (LDS-tiled, coalesced) ----------------
__global__ __launch_bounds__(256) void k_vtrans(const __hip_bfloat16* __restrict__ qkv,
                                                __hip_bfloat16* __restrict__ vT) {
    const int st = blockIdx.x;
    const int bh = blockIdx.y;
    const int b = bh >> 4, h = bh & 15;
    __shared__ __align__(16) short T[64][72];
    const int tid = threadIdx.x;
#pragma unroll
    for (int i = 0; i < 2; ++i) {
        const int c = i * 256 + tid;
        const int s = c >> 3, d0 = (c & 7) * 8;
        const s16x8 v = *(const s16x8*)(qkv + (size_t)(b * 512 + st * 64 + s) * 3072 + 2048 + h * 64 + d0);
#pragma unroll
        for (int j = 0; j < 8; ++j) T[d0 + j][s] = v[j];
    }
    __syncthreads();
#pragma unroll
    for (int i = 0; i < 2; ++i) {
        const int c = i * 256 + tid;
        const int d = c >> 3, s0 = (c & 7) * 8;
        const s16x8 v = *(const s16x8*)&T[d][s0];
        *(s16x8*)(vT + ((size_t)bh * 64 + d) * 512 + st * 64 + s0) = v;
    }
}

// ============ 256x256-tile 8-wave phase-interleaved GEMM (vocab, f32 out) ============
template <int TAG>
__global__ __launch_bounds__(512, 2) void k_gemm256(const __hip_bfloat16* __restrict__ A,
                                                    const __hip_bfloat16* __restrict__ B,
                                                    const float* __restrict__ bias,
                                                    float* __restrict__ Cf,
                                                    __hip_bfloat16* __restrict__ Cb,
                                                    const int M, const int N, const int K,
                                                    const int mtiles, const int act) {
    __shared__ __align__(16) char lds[131072];  // [buf][A 32KB | B 32KB] x2

    const int nwg = gridDim.x, bid = blockIdx.x;
    const int qq = nwg >> 3, rr = nwg & 7;
    const int xcd = bid & 7, local = bid >> 3;
    const int wgid = (xcd < rr ? xcd * (qq + 1) : rr * (qq + 1) + (xcd - rr) * qq) + local;
    const int m0 = (wgid % mtiles) * 256;
    const int n0 = (wgid / mtiles) * 256;

    const int tid = threadIdx.x;
    const int lane = tid & 63;
    const int wid = tid >> 6;
    const int wr = wid >> 2, wc = wid & 3;
    const int l16 = lane & 15, lq = lane >> 4;
    const int sw = l16 & 7;

    const int srow = tid >> 3;
    const int scol = ((tid & 7) ^ (srow & 7)) << 3;
    const __hip_bfloat16* aS = A + (size_t)(m0 + srow) * K + scol;
    const __hip_bfloat16* bS = B + (size_t)(n0 + srow) * K + scol;
    const size_t rstep = (size_t)64 * K;

    const int NT = K >> 6;
    const int arow = wr * 128 + l16;
    const int brow = wc * 64 + l16;

    auto stage = [&](int d, int isB, int blk, int kk) {
        const __hip_bfloat16* src = (isB ? bS : aS) + (size_t)blk * rstep + kk;
        char* dst = lds + d * 65536 + isB * 32768 + blk * 8192 + tid * 16;
        gload_lds16(src, dst);
    };

    stage(0, 1, 0, 0); stage(0, 1, 1, 0);
    stage(0, 1, 2, 0); stage(0, 1, 3, 0);
    stage(0, 0, 0, 0); stage(0, 0, 2, 0);
    stage(0, 0, 1, 0); stage(0, 0, 3, 0);
    asm volatile("s_waitcnt vmcnt(2)" ::: "memory");
    __builtin_amdgcn_sched_barrier(0);
    __builtin_amdgcn_s_barrier();
    __builtin_amdgcn_sched_barrier(0);

    f32x4 acc[8][4] = {};
    Frag8 bfr[2][4];

    for (int t = 0; t < NT; ++t) {
        const int d = t & 1;
        const char* Ab = lds + d * 65536;
        const char* Bb = Ab + 32768;
        const bool st = (t + 1 < NT);
        const int k1 = (t + 1) << 6;

#pragma unroll
        for (int q = 0; q < 4; ++q) {
            if (q == 0) {
#pragma unroll
                for (int ks = 0; ks < 2; ++ks)
#pragma unroll
                    for (int ni = 0; ni < 4; ++ni)
                        bfr[ks][ni].v = *(const s16x8*)(
                            Bb + (brow + ni * 16) * 128 + (((ks * 4 + lq) ^ sw) << 4));
            }
            Frag8 af[2][2];
#pragma unroll
            for (int m2 = 0; m2 < 2; ++m2)
#pragma unroll
                for (int ks = 0; ks < 2; ++ks)
                    af[m2][ks].v = *(const s16x8*)(
                        Ab + (arow + (q * 2 + m2) * 16) * 128 + (((ks * 4 + lq) ^ sw) << 4));

            if (st) {
                if (q == 0)      { stage(d ^ 1, 1, 0, k1); stage(d ^ 1, 1, 1, k1); }
                else if (q == 1) { stage(d ^ 1, 1, 2, k1); stage(d ^ 1, 1, 3, k1); }
                else if (q == 2) { stage(d ^ 1, 0, 0, k1); stage(d ^ 1, 0, 2, k1); }
                else             { stage(d ^ 1, 0, 1, k1); stage(d ^ 1, 0, 3, k1); }
            }

            // no pre-MFMA barrier: compiler inserts lgkmcnt for the ds_read deps
            __builtin_amdgcn_sched_barrier(0);
            __builtin_amdgcn_s_setprio(1);
#pragma unroll
            for (int ks = 0; ks < 2; ++ks)
#pragma unroll
                for (int m2 = 0; m2 < 2; ++m2)
#pragma unroll
                    for (int ni = 0; ni < 4; ++ni)
                        acc[q * 2 + m2][ni] = mfma16(af[m2][ks], bfr[ks][ni], acc[q * 2 + m2][ni]);
            __builtin_amdgcn_s_setprio(0);
            __builtin_amdgcn_sched_barrier(0);
            if (q == 1) {
                if (st) asm volatile("s_waitcnt vmcnt(4)" ::: "memory");
                else    asm volatile("s_waitcnt vmcnt(0)" ::: "memory");
            } else if (q == 3) {
                if (st) asm volatile("s_waitcnt vmcnt(2)" ::: "memory");
                else    asm volatile("s_waitcnt vmcnt(0)" ::: "memory");
            }
            __builtin_amdgcn_s_barrier();
            __builtin_amdgcn_sched_barrier(0);
        }
    }

#pragma unroll
    for (int mi = 0; mi < 8; ++mi) {
        const int rowb = m0 + wr * 128 + mi * 16 + lq * 4;
#pragma unroll
        for (int ni = 0; ni < 4; ++ni) {
            const int col = n0 + wc * 64 + ni * 16 + l16;
            const float bv = bias[col];
#pragma unroll
            for (int r = 0; r < 4; ++r) {
                float v2 = acc[mi][ni][r] + bv;
                if (act == 1) v2 = 0.5f * v2 * (1.0f + erff(v2 * 0.70710678118654752f));
                const size_t idx = (size_t)(rowb + r) * N + col;
                if (Cf) Cf[idx] = v2;
                if (Cb) Cb[idx] = __float2bfloat16(v2);
            }
        }
    }
}

// ============ 256x128-tile 8-wave barrier-free GEMM (FFN1 / FFN2 split-K) ============
// grid.y = split-K slice; partials written as bf16 to Cp (bias only in slice 0).
template <int TAG>
__global__ __launch_bounds__(512, 2) void k_gemm256n(const __hip_bfloat16* __restrict__ A,
                                                     const __hip_bfloat16* __restrict__ B,
                                                     const float* __restrict__ bias,
                                                     __hip_bfloat16* __restrict__ Cp,
                                                     __hip_bfloat16* __restrict__ Cb,
                                                     const int M, const int N, const int K,
                                                     const int Ksub, const int mtiles,
                                                     const int act) {
    __shared__ __align__(16) char lds[98304];  // 2 bufs x (A 32KB | B 16KB)

    const int nwg = gridDim.x, bid = blockIdx.x;
    const int qq = nwg >> 3, rr = nwg & 7;
    const int xcd = bid & 7, local = bid >> 3;
    const int wgid = (xcd < rr ? xcd * (qq + 1) : rr * (qq + 1) + (xcd - rr) * qq) + local;
    const int m0 = (wgid % mtiles) * 256;
    const int n0 = (wgid / mtiles) * 128;

    const int tid = threadIdx.x;
    const int lane = tid & 63;
    const int wid = tid >> 6;
    const int wr = wid >> 2, wc = wid & 3;
    const int l16 = lane & 15, lq = lane >> 4;
    const int sw = l16 & 7;

    const int kb = blockIdx.y * Ksub;
    const int srow = tid >> 3;
    const int scol = ((tid & 7) ^ (srow & 7)) << 3;
    const __hip_bfloat16* aS = A + (size_t)(m0 + srow) * K + scol + kb;
    const __hip_bfloat16* bS = B + (size_t)(n0 + srow) * K + scol + kb;
    const size_t rstep = (size_t)64 * K;

    const int NT = Ksub >> 6;
    const int arow = wr * 128 + l16;
    const int brow = wc * 32 + l16;

    auto stage = [&](int d, int isB, int blk, int kk) {
        const __hip_bfloat16* src = (isB ? bS : aS) + (size_t)blk * rstep + kk;
        char* dst = lds + d * 49152 + isB * 32768 + blk * 8192 + tid * 16;
        gload_lds16(src, dst);
    };

    // prologue: stage K-tile 0, order = [B0,B1, A0,A2, A1,A3]
    stage(0, 1, 0, 0); stage(0, 1, 1, 0);
    stage(0, 0, 0, 0); stage(0, 0, 2, 0);
    stage(0, 0, 1, 0); stage(0, 0, 3, 0);
    asm volatile("s_waitcnt vmcnt(2)" ::: "memory");
    __builtin_amdgcn_sched_barrier(0);
    __builtin_amdgcn_s_barrier();
    __builtin_amdgcn_sched_barrier(0);

    f32x4 acc[8][2] = {};
    Frag8 bfr[2][2];

    for (int t = 0; t < NT; ++t) {
        const int d = t & 1;
        const char* Ab = lds + d * 49152;
        const char* Bb = Ab + 32768;
        const bool st = (t + 1 < NT);
        const int k1 = (t + 1) << 6;

#pragma unroll
        for (int q = 0; q < 4; ++q) {
            if (q == 0) {
#pragma unroll
                for (int ks = 0; ks < 2; ++ks)
#pragma unroll
                    for (int ni = 0; ni < 2; ++ni)
                        bfr[ks][ni].v = *(const s16x8*)(
                            Bb + (brow + ni * 16) * 128 + (((ks * 4 + lq) ^ sw) << 4));
            }
            Frag8 af[2][2];
#pragma unroll
            for (int m2 = 0; m2 < 2; ++m2)
#pragma unroll
                for (int ks = 0; ks < 2; ++ks)
                    af[m2][ks].v = *(const s16x8*)(
                        Ab + (arow + (q * 2 + m2) * 16) * 128 + (((ks * 4 + lq) ^ sw) << 4));

            if (st) {
                if (q == 0)      { stage(d ^ 1, 1, 0, k1); stage(d ^ 1, 1, 1, k1); }
                else if (q == 1) { stage(d ^ 1, 0, 0, k1); stage(d ^ 1, 0, 2, k1); }
                else if (q == 2) { stage(d ^ 1, 0, 1, k1); stage(d ^ 1, 0, 3, k1); }
            }

            __builtin_amdgcn_sched_barrier(0);
            __builtin_amdgcn_s_setprio(1);
#pragma unroll
            for (int ks = 0; ks < 2; ++ks)
#pragma unroll
                for (int m2 = 0; m2 < 2; ++m2)
#pragma unroll
                    for (int ni = 0; ni < 2; ++ni)
                        acc[q * 2 + m2][ni] = mfma16(af[m2][ks], bfr[ks][ni], acc[q * 2 + m2][ni]);
            __builtin_amdgcn_s_setprio(0);
            __builtin_amdgcn_sched_barrier(0);
            if (q == 1) {
                if (st) asm volatile("s_waitcnt vmcnt(4)" ::: "memory");
                else    asm volatile("s_waitcnt vmcnt(0)" ::: "memory");
            } else if (q == 3) {
                if (st) asm volatile("s_waitcnt vmcnt(2)" ::: "memory");
                else    asm volatile("s_waitcnt vmcnt(0)" ::: "memory");
            }
            __builtin_amdgcn_s_barrier();
            __builtin_amdgcn_sched_barrier(0);
        }
    }

    __hip_bfloat16* Cpp = Cp ? Cp + (size_t)blockIdx.y * M * N : nullptr;
    const bool addb = (blockIdx.y == 0);

#pragma unroll
    for (int mi = 0; mi < 8; ++mi) {
        const int rowb = m0 + wr * 128 + mi * 16 + lq * 4;
#pragma unroll
        for (int ni = 0; ni < 2; ++ni) {
            const int col = n0 + wc * 32 + ni * 16 + l16;
            const float bv = addb ? bias[col] : 0.0f;
#pragma unroll
            for (int r = 0; r < 4; ++r) {
                float v2 = acc[mi][ni][r] + bv;
                if (act == 1) v2 = 0.5f * v2 * (1.0f + erff(v2 * 0.70710678118654752f));
                const size_t idx = (size_t)(rowb + r) * N + col;
                if (Cpp) Cpp[idx] = __float2bfloat16(v2);
                if (Cb) Cb[idx] = __float2bfloat16(v2);
            }
        }
    }
}

// ============ 128x128-tile pipelined GEMM (QKV, Wo, fallback) ============
__device__ __forceinline__ const s16x8* fragp(const char* base, int row, int lq) {
    const int line = row >> 1;
    const int u = ((row & 1) << 2) | lq;
    return (const s16x8*)(base + line * 128 + ((u ^ (line & 7)) << 4));
}

template <int TAG>
__global__ __launch_bounds__(256, 2) void k_gemm(const __hip_bfloat16* __restrict__ A,
                                                 const __hip_bfloat16* __restrict__ B,
                                                 const float* __restrict__ bias,
                                                 __hip_bfloat16* __restrict__ Cp,
                                                 __hip_bfloat16* __restrict__ Cb,
                                                 const int M, const int N, const int K,
                                                 const int Ksub, const int mtiles,
                                                 const int act) {
    __shared__ __align__(16) char lds[3 * 16384];

    const int nwg = gridDim.x;
    const int bid = blockIdx.x;
    const int q = nwg >> 3, r = nwg & 7;
    const int xcd = bid & 7, local = bid >> 3;
    const int wgid = (xcd < r ? xcd * (q + 1) : r * (q + 1) + (xcd - r) * q) + local;
    const int m0 = (wgid % mtiles) * 128;
    const int n0 = (wgid / mtiles) * 128;

    const int tid = threadIdx.x;
    const int lane = tid & 63, w = tid >> 6;
    const int wr = w >> 1, wc = w & 1;
    const int l16 = lane & 15, lq = lane >> 4;

    const int kb = blockIdx.y * Ksub;
    const int NT = Ksub >> 5;

    int arow0, acol0, arow1, acol1;
    {
        const int c0 = tid, line0 = c0 >> 3, u0 = (c0 & 7) ^ (line0 & 7);
        arow0 = (line0 << 1) | (u0 >> 2); acol0 = (u0 & 3) * 8;
        const int c1 = tid + 256, line1 = c1 >> 3, u1 = (c1 & 7) ^ (line1 & 7);
        arow1 = (line1 << 1) | (u1 >> 2); acol1 = (u1 & 3) * 8;
    }
    const size_t abase0 = (size_t)(m0 + arow0) * K + acol0 + kb;
    const size_t abase1 = (size_t)(m0 + arow1) * K + acol1 + kb;
    const size_t bbase0 = (size_t)(n0 + arow0) * K + acol0 + kb;
    const size_t bbase1 = (size_t)(n0 + arow1) * K + acol1 + kb;

    auto stageA = [&](int tt, int buf) {
        char* dst = lds + buf * 16384;
        gload_lds16(A + abase0 + tt * 32, dst + tid * 16);
        gload_lds16(A + abase1 + tt * 32, dst + (tid + 256) * 16);
    };
    auto stageB = [&](int tt, int buf) {
        char* dst = lds + buf * 16384 + 8192;
        gload_lds16(B + bbase0 + tt * 32, dst + tid * 16);
        gload_lds16(B + bbase1 + tt * 32, dst + (tid + 256) * 16);
    };

    f32x4 acc[4][4] = {};

    stageA(0, 0); stageB(0, 0);
    stageA(1, 1); stageB(1, 1);
    asm volatile("s_waitcnt vmcnt(4)" ::: "memory");
    __builtin_amdgcn_sched_barrier(0);
    __builtin_amdgcn_s_barrier();
    __builtin_amdgcn_sched_barrier(0);

    int cur = 0;
    for (int t = 0; t < NT; ++t) {
        const int stb = (cur == 0) ? 2 : cur - 1;
        const char* Ab = lds + cur * 16384;
        const char* Bb = Ab + 8192;
        const bool doStage = (t + 2 < NT);

        if (doStage) stageA(t + 2, stb);

        Frag8 a0, a1, b0, b1, b2, b3;
        a0.v = *fragp(Ab, wr * 64 + l16, lq);
        a1.v = *fragp(Ab, wr * 64 + 16 + l16, lq);
        b0.v = *fragp(Bb, wc * 64 + l16, lq);
        b1.v = *fragp(Bb, wc * 64 + 16 + l16, lq);
        b2.v = *fragp(Bb, wc * 64 + 32 + l16, lq);
        b3.v = *fragp(Bb, wc * 64 + 48 + l16, lq);

        __builtin_amdgcn_s_setprio(1);
        acc[0][0] = mfma16(a0, b0, acc[0][0]);
        acc[0][1] = mfma16(a0, b1, acc[0][1]);
        acc[0][2] = mfma16(a0, b2, acc[0][2]);
        acc[0][3] = mfma16(a0, b3, acc[0][3]);
        acc[1][0] = mfma16(a1, b0, acc[1][0]);
        acc[1][1] = mfma16(a1, b1, acc[1][1]);
        acc[1][2] = mfma16(a1, b2, acc[1][2]);
        acc[1][3] = mfma16(a1, b3, acc[1][3]);
        __builtin_amdgcn_s_setprio(0);

        if (doStage) stageB(t + 2, stb);

        Frag8 a2, a3;
        a2.v = *fragp(Ab, wr * 64 + 32 + l16, lq);
        a3.v = *fragp(Ab, wr * 64 + 48 + l16, lq);

        __builtin_amdgcn_s_setprio(1);
        acc[2][0] = mfma16(a2, b0, acc[2][0]);
        acc[2][1] = mfma16(a2, b1, acc[2][1]);
        acc[2][2] = mfma16(a2, b2, acc[2][2]);
        acc[2][3] = mfma16(a2, b3, acc[2][3]);
        acc[3][0] = mfma16(a3, b0, acc[3][0]);
        acc[3][1] = mfma16(a3, b1, acc[3][1]);
        acc[3][2] = mfma16(a3, b2, acc[3][2]);
        acc[3][3] = mfma16(a3, b3, acc[3][3]);
        __builtin_amdgcn_s_setprio(0);

        if (t + 3 < NT) {
            asm volatile("s_waitcnt vmcnt(4)" ::: "memory");
        } else {
            asm volatile("s_waitcnt vmcnt(0)" ::: "memory");
        }
        __builtin_amdgcn_sched_barrier(0);
        __builtin_amdgcn_s_barrier();
        __builtin_amdgcn_sched_barrier(0);

        cur = (cur == 2) ? 0 : cur + 1;
    }

    __hip_bfloat16* Cpp = Cp ? Cp + (size_t)blockIdx.y * M * N : nullptr;
    const bool addb = (blockIdx.y == 0);

#pragma unroll
    for (int mi = 0; mi < 4; ++mi) {
        const int rowb = m0 + wr * 64 + mi * 16 + lq * 4;
#pragma unroll
        for (int ni = 0; ni < 4; ++ni) {
            const int col = n0 + wc * 64 + ni * 16 + l16;
            const float bv = addb ? bias[col] : 0.0f;
#pragma unroll
            for (int rr = 0; rr < 4; ++rr) {
                float v2 = acc[mi][ni][rr] + bv;
                if (act == 1) v2 = 0.5f * v2 * (1.0f + erff(v2 * 0.70710678118654752f));
                const size_t idx = (size_t)(rowb + rr) * N + col;
                if (Cpp) Cpp[idx] = __float2bfloat16(v2);
                if (Cb) Cb[idx] = __float2bfloat16(v2);
            }
        }
    }
}

// ---------------- flash attention (round-11 compute, CU-load-balanced remap) ----------------
__global__ __launch_bounds__(256) void k_attn(const __hip_bfloat16* __restrict__ qkv,
                                              const __hip_bfloat16* __restrict__ vT,
                                              const int* __restrict__ seq,
                                              const float* __restrict__ biasT,
                                              __hip_bfloat16* __restrict__ out) {
    const int f = blockIdx.x;
    const int half = f >> 8;
    const int qb = half ? (7 - (f & 7)) : (f & 7);
    const int hb = ((f & 255) >> 3) + (half << 5);
    const int h = hb & 15, b = hb >> 4;
    const int q0 = qb * 64;
    const int tid = threadIdx.x, lane = tid & 63, w = tid >> 6;
    const int l16 = lane & 15, lq = lane >> 4;

    __shared__ __align__(16) char Ks[2 * 8192];
    __shared__ __align__(16) char Vs[2 * 8192];
    __shared__ __align__(16) char Ps[4 * 2048];
    __shared__ float bias_l[513];
    __shared__ float pad_l[512];

    for (int i = tid; i < 513; i += 256) bias_l[i] = biasT[h * 513 + i];
    for (int i = tid; i < 512; i += 256) pad_l[i] = (seq[b * 512 + i] == 0) ? -1e9f : 0.0f;

    const int qrowA = q0 + w * 16 + l16;
    const __hip_bfloat16* qptr = qkv + (size_t)(b * 512 + qrowA) * 3072 + h * 64;
    Frag8 qf[2];
    qf[0].v = *(const s16x8*)(qptr + lq * 8);
    qf[1].v = *(const s16x8*)(qptr + 32 + lq * 8);

    const int kr0 = tid >> 3, sl = tid & 7;
    const int kr1 = kr0 + 32;
    char* kdst0 = Ks + kr0 * 128 + ((sl ^ (kr0 & 7)) * 16);
    char* kdst1 = Ks + kr1 * 128 + ((sl ^ (kr1 & 7)) * 16);
    char* vdst0 = Vs + kr0 * 128 + ((sl ^ (kr0 & 7)) * 16);
    char* vdst1 = Vs + kr1 * 128 + ((sl ^ (kr1 & 7)) * 16);
    const __hip_bfloat16* vbase = vT + (size_t)(b * 16 + h) * 64 * 512;

    s16x8 kreg0, kreg1, vreg0, vreg1;
    auto load_regs = [&](int kt) {
        const size_t kb_ = (size_t)(b * 512 + kt * 64) * 3072 + h * 64 + 1024;
        kreg0 = *(const s16x8*)(qkv + kb_ + (size_t)kr0 * 3072 + sl * 8);
        kreg1 = *(const s16x8*)(qkv + kb_ + (size_t)kr1 * 3072 + sl * 8);
        vreg0 = *(const s16x8*)(vbase + (size_t)kr0 * 512 + kt * 64 + sl * 8);
        vreg1 = *(const s16x8*)(vbase + (size_t)kr1 * 512 + kt * 64 + sl * 8);
    };

    f32x4 oacc[4] = {};
    float mrow[4] = {-1e30f, -1e30f, -1e30f, -1e30f};
    float lrow[4] = {0.f, 0.f, 0.f, 0.f};
    char* PsW = Ps + w * 2048;

    load_regs(0);
    for (int kt = 0; kt <= qb; ++kt) {
        const int bo = (kt & 1) * 8192;
        *(s16x8*)(kdst0 + bo) = kreg0;
        *(s16x8*)(kdst1 + bo) = kreg1;
        *(s16x8*)(vdst0 + bo) = vreg0;
        *(s16x8*)(vdst1 + bo) = vreg1;
        __syncthreads();
        if (kt < qb) load_regs(kt + 1);

        const char* Kb = Ks + bo;
        const char* Vb = Vs + bo;

        f32x4 sacc[4] = {};
#pragma unroll
        for (int ks = 0; ks < 2; ++ks) {
#pragma unroll
            for (int nf = 0; nf < 4; ++nf) {
                const int key = nf * 16 + l16;
                Frag8 kf;
                kf.v = *(const s16x8*)(Kb + key * 128 + (((ks * 4 + lq) ^ (key & 7)) * 16));
                sacc[nf] = mfma16(qf[ks], kf, sacc[nf]);
            }
        }

        float pvv[4][4];
#pragma unroll
        for (int nf = 0; nf < 4; ++nf) {
            const int keyg = kt * 64 + nf * 16 + l16;
            const float padv = pad_l[keyg];
#pragma unroll
            for (int rr = 0; rr < 4; ++rr) {
                const int qg = q0 + w * 16 + lq * 4 + rr;
                pvv[nf][rr] = (keyg > qg) ? -1e9f
                            : sacc[nf][rr] * 0.125f + bias_l[qg - keyg] + padv;
            }
        }

#pragma unroll
        for (int rr = 0; rr < 4; ++rr) {
            float tm = fmaxf(fmaxf(pvv[0][rr], pvv[1][rr]), fmaxf(pvv[2][rr], pvv[3][rr]));
#pragma unroll
            for (int off = 1; off < 16; off <<= 1) tm = fmaxf(tm, __shfl_xor(tm, off, 64));
            const float mnew = fmaxf(mrow[rr], tm);
            const float sf = __expf(mrow[rr] - mnew);
            mrow[rr] = mnew;
            float ts = 0.f;
#pragma unroll
            for (int nf = 0; nf < 4; ++nf) {
                const float pe = __expf(pvv[nf][rr] - mnew);
                pvv[nf][rr] = pe;
                ts += pe;
            }
#pragma unroll
            for (int off = 1; off < 16; off <<= 1) ts += __shfl_xor(ts, off, 64);
            lrow[rr] = lrow[rr] * sf + ts;
            oacc[0][rr] *= sf; oacc[1][rr] *= sf; oacc[2][rr] *= sf; oacc[3][rr] *= sf;
        }

#pragma unroll
        for (int nf = 0; nf < 4; ++nf) {
            const int cc = nf * 16 + l16;
            const int slot = cc >> 3, rem = cc & 7;
#pragma unroll
            for (int rr = 0; rr < 4; ++rr) {
                const int row = lq * 4 + rr;
                *(short*)(PsW + row * 128 + ((slot ^ (row & 7)) * 16) + rem * 2) =
                    (short)bf16bits(pvv[nf][rr]);
            }
        }

#pragma unroll
        for (int ks = 0; ks < 2; ++ks) {
            Frag8 pf;
            pf.v = *(const s16x8*)(PsW + l16 * 128 + (((ks * 4 + lq) ^ (l16 & 7)) * 16));
#pragma unroll
            for (int nf = 0; nf < 4; ++nf) {
                const int d = nf * 16 + l16;
                Frag8 vf;
                vf.v = *(const s16x8*)(Vb + d * 128 + (((ks * 4 + lq) ^ (d & 7)) * 16));
                oacc[nf] = mfma16(pf, vf, oacc[nf]);
            }
        }
    }

#pragma unroll
    for (int nf = 0; nf < 4; ++nf) {
        const int d = nf * 16 + l16;
#pragma unroll
        for (int rr = 0; rr < 4; ++rr) {
            const int qg = q0 + w * 16 + lq * 4 + rr;
            out[(size_t)(b * 512 + qg) * 1024 + h * 64 + d] = __float2bfloat16(oacc[nf][rr] / lrow[rr]);
        }
    }
}

// ---------------- fused residual add (up to 4 bf16 partials) + LayerNorm ----------------
__global__ __launch_bounds__(256) void k_add_ln(const float* __restrict__ x,
                                                const __hip_bfloat16* __restrict__ res0,
                                                const __hip_bfloat16* __restrict__ res1,
                                                const __hip_bfloat16* __restrict__ res2,
                                                const __hip_bfloat16* __restrict__ res3,
                                                const float* __restrict__ gamma,
                                                const float* __restrict__ beta,
                                                float* __restrict__ xout,
                                                __hip_bfloat16* __restrict__ bout) {
    const int t = blockIdx.x;
    const int tid = threadIdx.x;
    float4 y = *(const float4*)(x + (size_t)t * 1024 + tid * 4);
    const __hip_bfloat16* rs[4] = {res0, res1, res2, res3};
#pragma unroll
    for (int k = 0; k < 4; ++k) {
        if (rs[k]) {
            const ushort4 rv = *(const ushort4*)((const unsigned short*)rs[k] + (size_t)t * 1024 + tid * 4);
            y.x += b2f(rv.x); y.y += b2f(rv.y); y.z += b2f(rv.z); y.w += b2f(rv.w);
        }
    }
    float s = y.x + y.y + y.z + y.w;
    float s2 = y.x * y.x + y.y * y.y + y.z * y.z + y.w * y.w;
#pragma unroll
    for (int off = 32; off >= 1; off >>= 1) {
        s += __shfl_xor(s, off, 64);
        s2 += __shfl_xor(s2, off, 64);
    }
    __shared__ float red[8];
    const int w = tid >> 6, lane = tid & 63;
    if (lane == 0) { red[w] = s; red[4 + w] = s2; }
    __syncthreads();
    const float tot = red[0] + red[1] + red[2] + red[3];
    const float tot2 = red[4] + red[5] + red[6] + red[7];
    const float mean = tot * (1.0f / 1024.0f);
    const float var = tot2 * (1.0f / 1024.0f) - mean * mean;
    const float inv = rsqrtf(var + 1e-5f);
    const float4 g = *(const float4*)(gamma + tid * 4);
    const float4 bb = *(const float4*)(beta + tid * 4);
    float4 o;
    o.x = (y.x - mean) * inv * g.x + bb.x;
    o.y = (y.y - mean) * inv * g.y + bb.y;
    o.z = (y.z - mean) * inv * g.z + bb.z;
    o.w = (y.w - mean) * inv * g.w + bb.w;
    *(float4*)(xout + (size_t)t * 1024 + tid * 4) = o;
    ushort4 u;
    u.x = bf16bits(o.x); u.y = bf16bits(o.y); u.z = bf16bits(o.z); u.w = bf16bits(o.w);
    *(ushort4*)((unsigned short*)bout + (size_t)t * 1024 + tid * 4) = u;
}

// ---------------- host ----------------
extern "C" void kernel_launch(void* const* d_in, const int* in_sizes, int n_in,
                              void* d_out, int out_size, void* d_ws, size_t ws_size,
                              hipStream_t stream) {
    const int* seq = (const int*)d_in[0];
    const float* tok = (const float*)d_in[1];
    const float* dist = (const float*)d_in[2];
    const float* Wqkv = (const float*)d_in[3];
    const float* bqkv = (const float*)d_in[4];
    const float* Wo = (const float*)d_in[5];
    const float* bo = (const float*)d_in[6];
    const float* W1 = (const float*)d_in[7];
    const float* b1 = (const float*)d_in[8];
    const float* W2 = (const float*)d_in[9];
    const float* b2 = (const float*)d_in[10];
    const float* ln1s = (const float*)d_in[11];
    const float* ln1b = (const float*)d_in[12];
    const float* ln2s = (const float*)d_in[13];
    const float* ln2b = (const float*)d_in[14];
    const float* lnfs = (const float*)d_in[15];
    const float* lnfb = (const float*)d_in[16];
    const float* Wg = (const float*)d_in[17];
    const float* bg = (const float*)d_in[18];
    float* out = (float*)d_out;

    const size_t base_need = (size_t)300 * 1024 * 1024;
    const int ffn2_splits = (ws_size >= base_need) ? 4 : 2;

    char* p = (char*)d_ws;
    auto take = [&](size_t bytes) {
        char* r = p;
        p += (bytes + 255) & ~(size_t)255;
        return r;
    };
    __hip_bfloat16* wqkv_b = (__hip_bfloat16*)take((size_t)6 * 3072 * 1024 * 2);
    __hip_bfloat16* wo_b = (__hip_bfloat16*)take((size_t)6 * 1024 * 1024 * 2);
    __hip_bfloat16* w1_b = (__hip_bfloat16*)take((size_t)6 * 4096 * 1024 * 2);
    __hip_bfloat16* w2_b = (__hip_bfloat16*)take((size_t)6 * 1024 * 4096 * 2);
    __hip_bfloat16* wg_b = (__hip_bfloat16*)take((size_t)32000 * 1024 * 2);
    float* xf = (float*)take((size_t)2048 * 1024 * 4);
    __hip_bfloat16* xb = (__hip_bfloat16*)take((size_t)2048 * 1024 * 2);
    __hip_bfloat16* qkvb = (__hip_bfloat16*)take((size_t)2048 * 3072 * 2);
    __hip_bfloat16* hb = (__hip_bfloat16*)take((size_t)2048 * 4096 * 2);
    __hip_bfloat16* ab = (__hip_bfloat16*)take((size_t)2048 * 1024 * 2);
    __hip_bfloat16* vTb = (__hip_bfloat16*)take((size_t)64 * 64 * 512 * 2);
    float* biasT = (float*)take((size_t)16 * 513 * 4);
    __hip_bfloat16* tmpb = (__hip_bfloat16*)take((size_t)ffn2_splits * 2048 * 1024 * 2);
    __hip_bfloat16* tmpb1 = tmpb + (size_t)2048 * 1024;
    __hip_bfloat16* tmpb2 = (ffn2_splits == 4) ? tmpb + (size_t)2 * 2048 * 1024 : nullptr;
    __hip_bfloat16* tmpb3 = (ffn2_splits == 4) ? tmpb + (size_t)3 * 2048 * 1024 : nullptr;

    k_conv5<<<dim3(52864), dim3(256), 0, stream>>>(
        Wqkv, Wo, W1, W2, Wg, wqkv_b, wo_b, w1_b, w2_b, wg_b,
        9216, 9216 + 3072, 9216 + 3072 + 12288, 9216 + 3072 + 12288 + 12288);
    k_bias_prep<<<dim3(16), dim3(256), 0, stream>>>(dist, biasT);
    k_embed<<<dim3(2048), dim3(256), 0, stream>>>(seq, tok, xf, xb);

    for (int l = 0; l < 6; ++l) {
        // QKV: 2048 x 3072 x 1024 (128^2 tiles: 384 wgs), bf16 out
        k_gemm<0><<<dim3(16 * 24), dim3(256), 0, stream>>>(
            xb, wqkv_b + (size_t)l * 3072 * 1024, bqkv + l * 3072, nullptr, qkvb,
            2048, 3072, 1024, 1024, 16, 0);
        k_vtrans<<<dim3(8, 64), dim3(256), 0, stream>>>(qkvb, vTb);
        k_attn<<<dim3(512), dim3(256), 0, stream>>>(qkvb, vTb, seq, biasT, ab);
        // Wo: 2048 x 1024 x 1024, 128^2 split-K=2 -> bf16 partials
        k_gemm<1><<<dim3(16 * 8, 2), dim3(256), 0, stream>>>(
            ab, wo_b + (size_t)l * 1024 * 1024, bo + l * 1024, tmpb, nullptr,
            2048, 1024, 1024, 512, 16, 0);
        k_add_ln<<<dim3(2048), dim3(256), 0, stream>>>(xf, tmpb, tmpb1, nullptr, nullptr,
                                                       ln1s + l * 1024, ln1b + l * 1024, xf, xb);
        // FFN1: 2048 x 4096 x 1024 (256x128 tiles: 256 wgs full coverage), GELU
        k_gemm256n<2><<<dim3(256), dim3(512), 0, stream>>>(
            xb, w1_b + (size_t)l * 4096 * 1024, b1 + l * 4096, nullptr, hb,
            2048, 4096, 1024, 1024, 8, 1);
        // FFN2: 2048 x 1024 x 4096 -> bf16 partials
        if (ffn2_splits == 4) {
            k_gemm256n<3><<<dim3(64, 4), dim3(512), 0, stream>>>(
                hb, w2_b + (size_t)l * 1024 * 4096, b2 + l * 1024, tmpb, nullptr,
                2048, 1024, 4096, 1024, 8, 0);
        } else {
            k_gemm<3><<<dim3(16 * 8, 2), dim3(256), 0, stream>>>(
                hb, w2_b + (size_t)l * 1024 * 4096, b2 + l * 1024, tmpb, nullptr,
                2048, 1024, 4096, 2048, 16, 0);
        }
        k_add_ln<<<dim3(2048), dim3(256), 0, stream>>>(xf, tmpb, tmpb1, tmpb2, tmpb3,
                                                       ln2s + l * 1024, ln2b + l * 1024, xf, xb);
    }
    k_add_ln<<<dim3(2048), dim3(256), 0, stream>>>(xf, nullptr, nullptr, nullptr, nullptr,
                                                   lnfs, lnfb, xf, xb);
    // vocab: 2048 x 32000 x 1024 (256^2 tiles: 8 x 125 = 1000 wgs), f32 out
    k_gemm256<4><<<dim3(1000), dim3(512), 0, stream>>>(xb, wg_b, bg, out, nullptr,
                                                       2048, 32000, 1024, 8, 0);
}

// Round 18
// 1209.827 us; speedup vs baseline: 1.0366x; 1.0040x over previous
//
#include <hip/hip_runtime.h>
#include <hip/hip_bf16.h>
#include <cstdint>

// Problem dims
// L=6, E=1024, H=16, F=4096, V=32000, B=4, S=512, ML=512, DH=64, tokens=2048

typedef float f32x4 __attribute__((ext_vector_type(4)));
typedef short s16x8 __attribute__((ext_vector_type(8)));
typedef __bf16 b16x8 __attribute__((ext_vector_type(8)));

struct Frag8 {
    s16x8 v;
    __device__ operator s16x8() const { return v; }
    __device__ operator b16x8() const { return __builtin_bit_cast(b16x8, v); }
};

__device__ __forceinline__ f32x4 mfma16(Frag8 a, Frag8 b, f32x4 c) {
    return __builtin_amdgcn_mfma_f32_16x16x32_bf16(a, b, c, 0, 0, 0);
}

__device__ __forceinline__ void gload_lds16(const void* g, void* l) {
    __builtin_amdgcn_global_load_lds(
        (__attribute__((address_space(1))) void*)g,
        (__attribute__((address_space(3))) void*)l, 16, 0, 0);
}

__device__ __forceinline__ unsigned short bf16bits(float x) {
    return __builtin_bit_cast(unsigned short, __float2bfloat16(x));
}

__device__ __forceinline__ float b2f(unsigned short u) {
    unsigned int x = (unsigned int)u << 16;
    return __builtin_bit_cast(float, x);
}

// ---------------- fused fp32 -> bf16 conversion (5 segments, 8 elems/thread) ----------------
__global__ __launch_bounds__(256) void k_conv5(const float* __restrict__ s0, const float* __restrict__ s1,
                                               const float* __restrict__ s2, const float* __restrict__ s3,
                                               const float* __restrict__ s4,
                                               __hip_bfloat16* __restrict__ d0, __hip_bfloat16* __restrict__ d1,
                                               __hip_bfloat16* __restrict__ d2, __hip_bfloat16* __restrict__ d3,
                                               __hip_bfloat16* __restrict__ d4,
                                               int b0, int b1, int b2, int b3) {
    const int blk = blockIdx.x;
    const float* src;
    __hip_bfloat16* dst;
    long base;
    if (blk < b0)      { src = s0; dst = d0; base = (long)blk * 2048; }
    else if (blk < b1) { src = s1; dst = d1; base = (long)(blk - b0) * 2048; }
    else if (blk < b2) { src = s2; dst = d2; base = (long)(blk - b1) * 2048; }
    else if (blk < b3) { src = s3; dst = d3; base = (long)(blk - b2) * 2048; }
    else               { src = s4; dst = d4; base = (long)(blk - b3) * 2048; }
    const long i = base + (long)threadIdx.x * 8;
    const float4 v0 = *(const float4*)(src + i);
    const float4 v1 = *(const float4*)(src + i + 4);
    s16x8 u;
    u[0] = (short)bf16bits(v0.x); u[1] = (short)bf16bits(v0.y);
    u[2] = (short)bf16bits(v0.z); u[3] = (short)bf16bits(v0.w);
    u[4] = (short)bf16bits(v1.x); u[5] = (short)bf16bits(v1.y);
    u[6] = (short)bf16bits(v1.z); u[7] = (short)bf16bits(v1.w);
    *(s16x8*)((unsigned short*)dst + i) = u;
}

// ---------------- bias pre-extraction: dist_emb[(i,h)] -> biasT[h][i] ----------------
__global__ __launch_bounds__(256) void k_bias_prep(const float* __restrict__ dist_emb,
                                                   float* __restrict__ biasT) {
    const int h = blockIdx.x;
    for (int i = threadIdx.x; i < 513; i += 256) biasT[h * 513 + i] = dist_emb[i * 16 + h];
}

// ---------------- embedding gather ----------------
__global__ __launch_bounds__(256) void k_embed(const int* __restrict__ seq,
                                               const float* __restrict__ tok,
                                               float* __restrict__ x,
                                               __hip_bfloat16* __restrict__ xb) {
    const int t = blockIdx.x;
    const int tokid = seq[t];
    const float4 v = *(const float4*)(tok + (size_t)tokid * 1024 + threadIdx.x * 4);
    float4 o;
    o.x = v.x * 32.0f; o.y = v.y * 32.0f; o.z = v.z * 32.0f; o.w = v.w * 32.0f;
    *(float4*)(x + (size_t)t * 1024 + threadIdx.x * 4) = o;
    ushort4 u;
    u.x = bf16bits(o.x); u.y = bf16bits(o.y); u.z = bf16bits(o.z); u.w = bf16bits(o.w);
    *(ushort4*)((unsigned short*)xb + (size_t)t * 1024 + threadIdx.x * 4) = u;
}

// ---------------- V transpose: qkv V-part -> vT[b,h,d,s] (LDS-tiled, coalesced) ----------------
__global__ __launch_bounds__(256) void k_vtrans(const __hip_bfloat16* __restrict__ qkv,
                                                __hip_bfloat16* __restrict__ vT) {
    const int st = blockIdx.x;
    const int bh = blockIdx.y;
    const int b = bh >> 4, h = bh & 15;
    __shared__ __align__(16) short T[64][72];
    const int tid = threadIdx.x;
#pragma unroll
    for (int i = 0; i < 2; ++i) {
        const int c = i * 256 + tid;
        const int s = c >> 3, d0 = (c & 7) * 8;
        const s16x8 v = *(const s16x8*)(qkv + (size_t)(b * 512 + st * 64 + s) * 3072 + 2048 + h * 64 + d0);
#pragma unroll
        for (int j = 0; j < 8; ++j) T[d0 + j][s] = v[j];
    }
    __syncthreads();
#pragma unroll
    for (int i = 0; i < 2; ++i) {
        const int c = i * 256 + tid;
        const int d = c >> 3, s0 = (c & 7) * 8;
        const s16x8 v = *(const s16x8*)&T[d][s0];
        *(s16x8*)(vT + ((size_t)bh * 64 + d) * 512 + st * 64 + s0) = v;
    }
}

// ============ 256x256-tile 8-wave phase-interleaved GEMM (vocab, f32 out) ============
template <int TAG>
__global__ __launch_bounds__(512, 2) void k_gemm256(const __hip_bfloat16* __restrict__ A,
                                                    const __hip_bfloat16* __restrict__ B,
                                                    const float* __restrict__ bias,
                                                    float* __restrict__ Cf,
                                                    __hip_bfloat16* __restrict__ Cb,
                                                    const int M, const int N, const int K,
                                                    const int mtiles, const int act) {
    __shared__ __align__(16) char lds[131072];  // [buf][A 32KB | B 32KB] x2

    const int nwg = gridDim.x, bid = blockIdx.x;
    const int qq = nwg >> 3, rr = nwg & 7;
    const int xcd = bid & 7, local = bid >> 3;
    const int wgid = (xcd < rr ? xcd * (qq + 1) : rr * (qq + 1) + (xcd - rr) * qq) + local;
    const int m0 = (wgid % mtiles) * 256;
    const int n0 = (wgid / mtiles) * 256;

    const int tid = threadIdx.x;
    const int lane = tid & 63;
    const int wid = tid >> 6;
    const int wr = wid >> 2, wc = wid & 3;
    const int l16 = lane & 15, lq = lane >> 4;
    const int sw = l16 & 7;

    const int srow = tid >> 3;
    const int scol = ((tid & 7) ^ (srow & 7)) << 3;
    const __hip_bfloat16* aS = A + (size_t)(m0 + srow) * K + scol;
    const __hip_bfloat16* bS = B + (size_t)(n0 + srow) * K + scol;
    const size_t rstep = (size_t)64 * K;

    const int NT = K >> 6;
    const int arow = wr * 128 + l16;
    const int brow = wc * 64 + l16;

    auto stage = [&](int d, int isB, int blk, int kk) {
        const __hip_bfloat16* src = (isB ? bS : aS) + (size_t)blk * rstep + kk;
        char* dst = lds + d * 65536 + isB * 32768 + blk * 8192 + tid * 16;
        gload_lds16(src, dst);
    };

    stage(0, 1, 0, 0); stage(0, 1, 1, 0);
    stage(0, 1, 2, 0); stage(0, 1, 3, 0);
    stage(0, 0, 0, 0); stage(0, 0, 2, 0);
    stage(0, 0, 1, 0); stage(0, 0, 3, 0);
    asm volatile("s_waitcnt vmcnt(2)" ::: "memory");
    __builtin_amdgcn_sched_barrier(0);
    __builtin_amdgcn_s_barrier();
    __builtin_amdgcn_sched_barrier(0);

    f32x4 acc[8][4] = {};
    Frag8 bfr[2][4];

    for (int t = 0; t < NT; ++t) {
        const int d = t & 1;
        const char* Ab = lds + d * 65536;
        const char* Bb = Ab + 32768;
        const bool st = (t + 1 < NT);
        const int k1 = (t + 1) << 6;

#pragma unroll
        for (int q = 0; q < 4; ++q) {
            if (q == 0) {
#pragma unroll
                for (int ks = 0; ks < 2; ++ks)
#pragma unroll
                    for (int ni = 0; ni < 4; ++ni)
                        bfr[ks][ni].v = *(const s16x8*)(
                            Bb + (brow + ni * 16) * 128 + (((ks * 4 + lq) ^ sw) << 4));
            }
            Frag8 af[2][2];
#pragma unroll
            for (int m2 = 0; m2 < 2; ++m2)
#pragma unroll
                for (int ks = 0; ks < 2; ++ks)
                    af[m2][ks].v = *(const s16x8*)(
                        Ab + (arow + (q * 2 + m2) * 16) * 128 + (((ks * 4 + lq) ^ sw) << 4));

            if (st) {
                if (q == 0)      { stage(d ^ 1, 1, 0, k1); stage(d ^ 1, 1, 1, k1); }
                else if (q == 1) { stage(d ^ 1, 1, 2, k1); stage(d ^ 1, 1, 3, k1); }
                else if (q == 2) { stage(d ^ 1, 0, 0, k1); stage(d ^ 1, 0, 2, k1); }
                else             { stage(d ^ 1, 0, 1, k1); stage(d ^ 1, 0, 3, k1); }
            }

            // no pre-MFMA barrier: compiler inserts lgkmcnt for the ds_read deps
            __builtin_amdgcn_sched_barrier(0);
            __builtin_amdgcn_s_setprio(1);
#pragma unroll
            for (int ks = 0; ks < 2; ++ks)
#pragma unroll
                for (int m2 = 0; m2 < 2; ++m2)
#pragma unroll
                    for (int ni = 0; ni < 4; ++ni)
                        acc[q * 2 + m2][ni] = mfma16(af[m2][ks], bfr[ks][ni], acc[q * 2 + m2][ni]);
            __builtin_amdgcn_s_setprio(0);
            __builtin_amdgcn_sched_barrier(0);
            if (q == 1) {
                if (st) asm volatile("s_waitcnt vmcnt(4)" ::: "memory");
                else    asm volatile("s_waitcnt vmcnt(0)" ::: "memory");
            } else if (q == 3) {
                if (st) asm volatile("s_waitcnt vmcnt(2)" ::: "memory");
                else    asm volatile("s_waitcnt vmcnt(0)" ::: "memory");
            }
            __builtin_amdgcn_s_barrier();
            __builtin_amdgcn_sched_barrier(0);
        }
    }

#pragma unroll
    for (int mi = 0; mi < 8; ++mi) {
        const int rowb = m0 + wr * 128 + mi * 16 + lq * 4;
#pragma unroll
        for (int ni = 0; ni < 4; ++ni) {
            const int col = n0 + wc * 64 + ni * 16 + l16;
            const float bv = bias[col];
#pragma unroll
            for (int r = 0; r < 4; ++r) {
                float v2 = acc[mi][ni][r] + bv;
                if (act == 1) v2 = 0.5f * v2 * (1.0f + erff(v2 * 0.70710678118654752f));
                const size_t idx = (size_t)(rowb + r) * N + col;
                if (Cf) Cf[idx] = v2;
                if (Cb) Cb[idx] = __float2bfloat16(v2);
            }
        }
    }
}

// ============ 256x128-tile 8-wave barrier-free GEMM (FFN1 / FFN2 split-K) ============
// grid.y = split-K slice; partials written as bf16 to Cp (bias only in slice 0).
template <int TAG>
__global__ __launch_bounds__(512, 2) void k_gemm256n(const __hip_bfloat16* __restrict__ A,
                                                     const __hip_bfloat16* __restrict__ B,
                                                     const float* __restrict__ bias,
                                                     __hip_bfloat16* __restrict__ Cp,
                                                     __hip_bfloat16* __restrict__ Cb,
                                                     const int M, const int N, const int K,
                                                     const int Ksub, const int mtiles,
                                                     const int act) {
    __shared__ __align__(16) char lds[98304];  // 2 bufs x (A 32KB | B 16KB)

    const int nwg = gridDim.x, bid = blockIdx.x;
    const int qq = nwg >> 3, rr = nwg & 7;
    const int xcd = bid & 7, local = bid >> 3;
    const int wgid = (xcd < rr ? xcd * (qq + 1) : rr * (qq + 1) + (xcd - rr) * qq) + local;
    const int m0 = (wgid % mtiles) * 256;
    const int n0 = (wgid / mtiles) * 128;

    const int tid = threadIdx.x;
    const int lane = tid & 63;
    const int wid = tid >> 6;
    const int wr = wid >> 2, wc = wid & 3;
    const int l16 = lane & 15, lq = lane >> 4;
    const int sw = l16 & 7;

    const int kb = blockIdx.y * Ksub;
    const int srow = tid >> 3;
    const int scol = ((tid & 7) ^ (srow & 7)) << 3;
    const __hip_bfloat16* aS = A + (size_t)(m0 + srow) * K + scol + kb;
    const __hip_bfloat16* bS = B + (size_t)(n0 + srow) * K + scol + kb;
    const size_t rstep = (size_t)64 * K;

    const int NT = Ksub >> 6;
    const int arow = wr * 128 + l16;
    const int brow = wc * 32 + l16;

    auto stage = [&](int d, int isB, int blk, int kk) {
        const __hip_bfloat16* src = (isB ? bS : aS) + (size_t)blk * rstep + kk;
        char* dst = lds + d * 49152 + isB * 32768 + blk * 8192 + tid * 16;
        gload_lds16(src, dst);
    };

    // prologue: stage K-tile 0, order = [B0,B1, A0,A2, A1,A3]
    stage(0, 1, 0, 0); stage(0, 1, 1, 0);
    stage(0, 0, 0, 0); stage(0, 0, 2, 0);
    stage(0, 0, 1, 0); stage(0, 0, 3, 0);
    asm volatile("s_waitcnt vmcnt(2)" ::: "memory");
    __builtin_amdgcn_sched_barrier(0);
    __builtin_amdgcn_s_barrier();
    __builtin_amdgcn_sched_barrier(0);

    f32x4 acc[8][2] = {};
    Frag8 bfr[2][2];

    for (int t = 0; t < NT; ++t) {
        const int d = t & 1;
        const char* Ab = lds + d * 49152;
        const char* Bb = Ab + 32768;
        const bool st = (t + 1 < NT);
        const int k1 = (t + 1) << 6;

#pragma unroll
        for (int q = 0; q < 4; ++q) {
            if (q == 0) {
#pragma unroll
                for (int ks = 0; ks < 2; ++ks)
#pragma unroll
                    for (int ni = 0; ni < 2; ++ni)
                        bfr[ks][ni].v = *(const s16x8*)(
                            Bb + (brow + ni * 16) * 128 + (((ks * 4 + lq) ^ sw) << 4));
            }
            Frag8 af[2][2];
#pragma unroll
            for (int m2 = 0; m2 < 2; ++m2)
#pragma unroll
                for (int ks = 0; ks < 2; ++ks)
                    af[m2][ks].v = *(const s16x8*)(
                        Ab + (arow + (q * 2 + m2) * 16) * 128 + (((ks * 4 + lq) ^ sw) << 4));

            if (st) {
                if (q == 0)      { stage(d ^ 1, 1, 0, k1); stage(d ^ 1, 1, 1, k1); }
                else if (q == 1) { stage(d ^ 1, 0, 0, k1); stage(d ^ 1, 0, 2, k1); }
                else if (q == 2) { stage(d ^ 1, 0, 1, k1); stage(d ^ 1, 0, 3, k1); }
            }

            __builtin_amdgcn_sched_barrier(0);
            __builtin_amdgcn_s_setprio(1);
#pragma unroll
            for (int ks = 0; ks < 2; ++ks)
#pragma unroll
                for (int m2 = 0; m2 < 2; ++m2)
#pragma unroll
                    for (int ni = 0; ni < 2; ++ni)
                        acc[q * 2 + m2][ni] = mfma16(af[m2][ks], bfr[ks][ni], acc[q * 2 + m2][ni]);
            __builtin_amdgcn_s_setprio(0);
            __builtin_amdgcn_sched_barrier(0);
            if (q == 1) {
                if (st) asm volatile("s_waitcnt vmcnt(4)" ::: "memory");
                else    asm volatile("s_waitcnt vmcnt(0)" ::: "memory");
            } else if (q == 3) {
                if (st) asm volatile("s_waitcnt vmcnt(2)" ::: "memory");
                else    asm volatile("s_waitcnt vmcnt(0)" ::: "memory");
            }
            __builtin_amdgcn_s_barrier();
            __builtin_amdgcn_sched_barrier(0);
        }
    }

    __hip_bfloat16* Cpp = Cp ? Cp + (size_t)blockIdx.y * M * N : nullptr;
    const bool addb = (blockIdx.y == 0);

#pragma unroll
    for (int mi = 0; mi < 8; ++mi) {
        const int rowb = m0 + wr * 128 + mi * 16 + lq * 4;
#pragma unroll
        for (int ni = 0; ni < 2; ++ni) {
            const int col = n0 + wc * 32 + ni * 16 + l16;
            const float bv = addb ? bias[col] : 0.0f;
#pragma unroll
            for (int r = 0; r < 4; ++r) {
                float v2 = acc[mi][ni][r] + bv;
                if (act == 1) v2 = 0.5f * v2 * (1.0f + erff(v2 * 0.70710678118654752f));
                const size_t idx = (size_t)(rowb + r) * N + col;
                if (Cpp) Cpp[idx] = __float2bfloat16(v2);
                if (Cb) Cb[idx] = __float2bfloat16(v2);
            }
        }
    }
}

// ============ 128x128-tile pipelined GEMM (QKV, Wo, fallback) ============
__device__ __forceinline__ const s16x8* fragp(const char* base, int row, int lq) {
    const int line = row >> 1;
    const int u = ((row & 1) << 2) | lq;
    return (const s16x8*)(base + line * 128 + ((u ^ (line & 7)) << 4));
}

template <int TAG>
__global__ __launch_bounds__(256, 2) void k_gemm(const __hip_bfloat16* __restrict__ A,
                                                 const __hip_bfloat16* __restrict__ B,
                                                 const float* __restrict__ bias,
                                                 __hip_bfloat16* __restrict__ Cp,
                                                 __hip_bfloat16* __restrict__ Cb,
                                                 const int M, const int N, const int K,
                                                 const int Ksub, const int mtiles,
                                                 const int act) {
    __shared__ __align__(16) char lds[3 * 16384];

    const int nwg = gridDim.x;
    const int bid = blockIdx.x;
    const int q = nwg >> 3, r = nwg & 7;
    const int xcd = bid & 7, local = bid >> 3;
    const int wgid = (xcd < r ? xcd * (q + 1) : r * (q + 1) + (xcd - r) * q) + local;
    const int m0 = (wgid % mtiles) * 128;
    const int n0 = (wgid / mtiles) * 128;

    const int tid = threadIdx.x;
    const int lane = tid & 63, w = tid >> 6;
    const int wr = w >> 1, wc = w & 1;
    const int l16 = lane & 15, lq = lane >> 4;

    const int kb = blockIdx.y * Ksub;
    const int NT = Ksub >> 5;

    int arow0, acol0, arow1, acol1;
    {
        const int c0 = tid, line0 = c0 >> 3, u0 = (c0 & 7) ^ (line0 & 7);
        arow0 = (line0 << 1) | (u0 >> 2); acol0 = (u0 & 3) * 8;
        const int c1 = tid + 256, line1 = c1 >> 3, u1 = (c1 & 7) ^ (line1 & 7);
        arow1 = (line1 << 1) | (u1 >> 2); acol1 = (u1 & 3) * 8;
    }
    const size_t abase0 = (size_t)(m0 + arow0) * K + acol0 + kb;
    const size_t abase1 = (size_t)(m0 + arow1) * K + acol1 + kb;
    const size_t bbase0 = (size_t)(n0 + arow0) * K + acol0 + kb;
    const size_t bbase1 = (size_t)(n0 + arow1) * K + acol1 + kb;

    auto stageA = [&](int tt, int buf) {
        char* dst = lds + buf * 16384;
        gload_lds16(A + abase0 + tt * 32, dst + tid * 16);
        gload_lds16(A + abase1 + tt * 32, dst + (tid + 256) * 16);
    };
    auto stageB = [&](int tt, int buf) {
        char* dst = lds + buf * 16384 + 8192;
        gload_lds16(B + bbase0 + tt * 32, dst + tid * 16);
        gload_lds16(B + bbase1 + tt * 32, dst + (tid + 256) * 16);
    };

    f32x4 acc[4][4] = {};

    stageA(0, 0); stageB(0, 0);
    stageA(1, 1); stageB(1, 1);
    asm volatile("s_waitcnt vmcnt(4)" ::: "memory");
    __builtin_amdgcn_sched_barrier(0);
    __builtin_amdgcn_s_barrier();
    __builtin_amdgcn_sched_barrier(0);

    int cur = 0;
    for (int t = 0; t < NT; ++t) {
        const int stb = (cur == 0) ? 2 : cur - 1;
        const char* Ab = lds + cur * 16384;
        const char* Bb = Ab + 8192;
        const bool doStage = (t + 2 < NT);

        if (doStage) stageA(t + 2, stb);

        Frag8 a0, a1, b0, b1, b2, b3;
        a0.v = *fragp(Ab, wr * 64 + l16, lq);
        a1.v = *fragp(Ab, wr * 64 + 16 + l16, lq);
        b0.v = *fragp(Bb, wc * 64 + l16, lq);
        b1.v = *fragp(Bb, wc * 64 + 16 + l16, lq);
        b2.v = *fragp(Bb, wc * 64 + 32 + l16, lq);
        b3.v = *fragp(Bb, wc * 64 + 48 + l16, lq);

        __builtin_amdgcn_s_setprio(1);
        acc[0][0] = mfma16(a0, b0, acc[0][0]);
        acc[0][1] = mfma16(a0, b1, acc[0][1]);
        acc[0][2] = mfma16(a0, b2, acc[0][2]);
        acc[0][3] = mfma16(a0, b3, acc[0][3]);
        acc[1][0] = mfma16(a1, b0, acc[1][0]);
        acc[1][1] = mfma16(a1, b1, acc[1][1]);
        acc[1][2] = mfma16(a1, b2, acc[1][2]);
        acc[1][3] = mfma16(a1, b3, acc[1][3]);
        __builtin_amdgcn_s_setprio(0);

        if (doStage) stageB(t + 2, stb);

        Frag8 a2, a3;
        a2.v = *fragp(Ab, wr * 64 + 32 + l16, lq);
        a3.v = *fragp(Ab, wr * 64 + 48 + l16, lq);

        __builtin_amdgcn_s_setprio(1);
        acc[2][0] = mfma16(a2, b0, acc[2][0]);
        acc[2][1] = mfma16(a2, b1, acc[2][1]);
        acc[2][2] = mfma16(a2, b2, acc[2][2]);
        acc[2][3] = mfma16(a2, b3, acc[2][3]);
        acc[3][0] = mfma16(a3, b0, acc[3][0]);
        acc[3][1] = mfma16(a3, b1, acc[3][1]);
        acc[3][2] = mfma16(a3, b2, acc[3][2]);
        acc[3][3] = mfma16(a3, b3, acc[3][3]);
        __builtin_amdgcn_s_setprio(0);

        if (t + 3 < NT) {
            asm volatile("s_waitcnt vmcnt(4)" ::: "memory");
        } else {
            asm volatile("s_waitcnt vmcnt(0)" ::: "memory");
        }
        __builtin_amdgcn_sched_barrier(0);
        __builtin_amdgcn_s_barrier();
        __builtin_amdgcn_sched_barrier(0);

        cur = (cur == 2) ? 0 : cur + 1;
    }

    __hip_bfloat16* Cpp = Cp ? Cp + (size_t)blockIdx.y * M * N : nullptr;
    const bool addb = (blockIdx.y == 0);

#pragma unroll
    for (int mi = 0; mi < 4; ++mi) {
        const int rowb = m0 + wr * 64 + mi * 16 + lq * 4;
#pragma unroll
        for (int ni = 0; ni < 4; ++ni) {
            const int col = n0 + wc * 64 + ni * 16 + l16;
            const float bv = addb ? bias[col] : 0.0f;
#pragma unroll
            for (int rr = 0; rr < 4; ++rr) {
                float v2 = acc[mi][ni][rr] + bv;
                if (act == 1) v2 = 0.5f * v2 * (1.0f + erff(v2 * 0.70710678118654752f));
                const size_t idx = (size_t)(rowb + rr) * N + col;
                if (Cpp) Cpp[idx] = __float2bfloat16(v2);
                if (Cb) Cb[idx] = __float2bfloat16(v2);
            }
        }
    }
}

// ---------------- flash attention (round-11 compute, CU-load-balanced remap) ----------------
__global__ __launch_bounds__(256) void k_attn(const __hip_bfloat16* __restrict__ qkv,
                                              const __hip_bfloat16* __restrict__ vT,
                                              const int* __restrict__ seq,
                                              const float* __restrict__ biasT,
                                              __hip_bfloat16* __restrict__ out) {
    const int f = blockIdx.x;
    const int half = f >> 8;
    const int qb = half ? (7 - (f & 7)) : (f & 7);
    const int hb = ((f & 255) >> 3) + (half << 5);
    const int h = hb & 15, b = hb >> 4;
    const int q0 = qb * 64;
    const int tid = threadIdx.x, lane = tid & 63, w = tid >> 6;
    const int l16 = lane & 15, lq = lane >> 4;

    __shared__ __align__(16) char Ks[2 * 8192];
    __shared__ __align__(16) char Vs[2 * 8192];
    __shared__ __align__(16) char Ps[4 * 2048];
    __shared__ float bias_l[513];
    __shared__ float pad_l[512];

    for (int i = tid; i < 513; i += 256) bias_l[i] = biasT[h * 513 + i];
    for (int i = tid; i < 512; i += 256) pad_l[i] = (seq[b * 512 + i] == 0) ? -1e9f : 0.0f;

    const int qrowA = q0 + w * 16 + l16;
    const __hip_bfloat16* qptr = qkv + (size_t)(b * 512 + qrowA) * 3072 + h * 64;
    Frag8 qf[2];
    qf[0].v = *(const s16x8*)(qptr + lq * 8);
    qf[1].v = *(const s16x8*)(qptr + 32 + lq * 8);

    const int kr0 = tid >> 3, sl = tid & 7;
    const int kr1 = kr0 + 32;
    char* kdst0 = Ks + kr0 * 128 + ((sl ^ (kr0 & 7)) * 16);
    char* kdst1 = Ks + kr1 * 128 + ((sl ^ (kr1 & 7)) * 16);
    char* vdst0 = Vs + kr0 * 128 + ((sl ^ (kr0 & 7)) * 16);
    char* vdst1 = Vs + kr1 * 128 + ((sl ^ (kr1 & 7)) * 16);
    const __hip_bfloat16* vbase = vT + (size_t)(b * 16 + h) * 64 * 512;

    s16x8 kreg0, kreg1, vreg0, vreg1;
    auto load_regs = [&](int kt) {
        const size_t kb_ = (size_t)(b * 512 + kt * 64) * 3072 + h * 64 + 1024;
        kreg0 = *(const s16x8*)(qkv + kb_ + (size_t)kr0 * 3072 + sl * 8);
        kreg1 = *(const s16x8*)(qkv + kb_ + (size_t)kr1 * 3072 + sl * 8);
        vreg0 = *(const s16x8*)(vbase + (size_t)kr0 * 512 + kt * 64 + sl * 8);
        vreg1 = *(const s16x8*)(vbase + (size_t)kr1 * 512 + kt * 64 + sl * 8);
    };

    f32x4 oacc[4] = {};
    float mrow[4] = {-1e30f, -1e30f, -1e30f, -1e30f};
    float lrow[4] = {0.f, 0.f, 0.f, 0.f};
    char* PsW = Ps + w * 2048;

    load_regs(0);
    for (int kt = 0; kt <= qb; ++kt) {
        const int bo = (kt & 1) * 8192;
        *(s16x8*)(kdst0 + bo) = kreg0;
        *(s16x8*)(kdst1 + bo) = kreg1;
        *(s16x8*)(vdst0 + bo) = vreg0;
        *(s16x8*)(vdst1 + bo) = vreg1;
        __syncthreads();
        if (kt < qb) load_regs(kt + 1);

        const char* Kb = Ks + bo;
        const char* Vb = Vs + bo;

        f32x4 sacc[4] = {};
#pragma unroll
        for (int ks = 0; ks < 2; ++ks) {
#pragma unroll
            for (int nf = 0; nf < 4; ++nf) {
                const int key = nf * 16 + l16;
                Frag8 kf;
                kf.v = *(const s16x8*)(Kb + key * 128 + (((ks * 4 + lq) ^ (key & 7)) * 16));
                sacc[nf] = mfma16(qf[ks], kf, sacc[nf]);
            }
        }

        float pvv[4][4];
#pragma unroll
        for (int nf = 0; nf < 4; ++nf) {
            const int keyg = kt * 64 + nf * 16 + l16;
            const float padv = pad_l[keyg];
#pragma unroll
            for (int rr = 0; rr < 4; ++rr) {
                const int qg = q0 + w * 16 + lq * 4 + rr;
                pvv[nf][rr] = (keyg > qg) ? -1e9f
                            : sacc[nf][rr] * 0.125f + bias_l[qg - keyg] + padv;
            }
        }

#pragma unroll
        for (int rr = 0; rr < 4; ++rr) {
            float tm = fmaxf(fmaxf(pvv[0][rr], pvv[1][rr]), fmaxf(pvv[2][rr], pvv[3][rr]));
#pragma unroll
            for (int off = 1; off < 16; off <<= 1) tm = fmaxf(tm, __shfl_xor(tm, off, 64));
            const float mnew = fmaxf(mrow[rr], tm);
            const float sf = __expf(mrow[rr] - mnew);
            mrow[rr] = mnew;
            float ts = 0.f;
#pragma unroll
            for (int nf = 0; nf < 4; ++nf) {
                const float pe = __expf(pvv[nf][rr] - mnew);
                pvv[nf][rr] = pe;
                ts += pe;
            }
#pragma unroll
            for (int off = 1; off < 16; off <<= 1) ts += __shfl_xor(ts, off, 64);
            lrow[rr] = lrow[rr] * sf + ts;
            oacc[0][rr] *= sf; oacc[1][rr] *= sf; oacc[2][rr] *= sf; oacc[3][rr] *= sf;
        }

#pragma unroll
        for (int nf = 0; nf < 4; ++nf) {
            const int cc = nf * 16 + l16;
            const int slot = cc >> 3, rem = cc & 7;
#pragma unroll
            for (int rr = 0; rr < 4; ++rr) {
                const int row = lq * 4 + rr;
                *(short*)(PsW + row * 128 + ((slot ^ (row & 7)) * 16) + rem * 2) =
                    (short)bf16bits(pvv[nf][rr]);
            }
        }

#pragma unroll
        for (int ks = 0; ks < 2; ++ks) {
            Frag8 pf;
            pf.v = *(const s16x8*)(PsW + l16 * 128 + (((ks * 4 + lq) ^ (l16 & 7)) * 16));
#pragma unroll
            for (int nf = 0; nf < 4; ++nf) {
                const int d = nf * 16 + l16;
                Frag8 vf;
                vf.v = *(const s16x8*)(Vb + d * 128 + (((ks * 4 + lq) ^ (d & 7)) * 16));
                oacc[nf] = mfma16(pf, vf, oacc[nf]);
            }
        }
    }

#pragma unroll
    for (int nf = 0; nf < 4; ++nf) {
        const int d = nf * 16 + l16;
#pragma unroll
        for (int rr = 0; rr < 4; ++rr) {
            const int qg = q0 + w * 16 + lq * 4 + rr;
            out[(size_t)(b * 512 + qg) * 1024 + h * 64 + d] = __float2bfloat16(oacc[nf][rr] / lrow[rr]);
        }
    }
}

// ---------------- fused residual add (up to 4 bf16 partials) + LayerNorm ----------------
__global__ __launch_bounds__(256) void k_add_ln(const float* __restrict__ x,
                                                const __hip_bfloat16* __restrict__ res0,
                                                const __hip_bfloat16* __restrict__ res1,
                                                const __hip_bfloat16* __restrict__ res2,
                                                const __hip_bfloat16* __restrict__ res3,
                                                const float* __restrict__ gamma,
                                                const float* __restrict__ beta,
                                                float* __restrict__ xout,
                                                __hip_bfloat16* __restrict__ bout) {
    const int t = blockIdx.x;
    const int tid = threadIdx.x;
    float4 y = *(const float4*)(x + (size_t)t * 1024 + tid * 4);
    const __hip_bfloat16* rs[4] = {res0, res1, res2, res3};
#pragma unroll
    for (int k = 0; k < 4; ++k) {
        if (rs[k]) {
            const ushort4 rv = *(const ushort4*)((const unsigned short*)rs[k] + (size_t)t * 1024 + tid * 4);
            y.x += b2f(rv.x); y.y += b2f(rv.y); y.z += b2f(rv.z); y.w += b2f(rv.w);
        }
    }
    float s = y.x + y.y + y.z + y.w;
    float s2 = y.x * y.x + y.y * y.y + y.z * y.z + y.w * y.w;
#pragma unroll
    for (int off = 32; off >= 1; off >>= 1) {
        s += __shfl_xor(s, off, 64);
        s2 += __shfl_xor(s2, off, 64);
    }
    __shared__ float red[8];
    const int w = tid >> 6, lane = tid & 63;
    if (lane == 0) { red[w] = s; red[4 + w] = s2; }
    __syncthreads();
    const float tot = red[0] + red[1] + red[2] + red[3];
    const float tot2 = red[4] + red[5] + red[6] + red[7];
    const float mean = tot * (1.0f / 1024.0f);
    const float var = tot2 * (1.0f / 1024.0f) - mean * mean;
    const float inv = rsqrtf(var + 1e-5f);
    const float4 g = *(const float4*)(gamma + tid * 4);
    const float4 bb = *(const float4*)(beta + tid * 4);
    float4 o;
    o.x = (y.x - mean) * inv * g.x + bb.x;
    o.y = (y.y - mean) * inv * g.y + bb.y;
    o.z = (y.z - mean) * inv * g.z + bb.z;
    o.w = (y.w - mean) * inv * g.w + bb.w;
    *(float4*)(xout + (size_t)t * 1024 + tid * 4) = o;
    ushort4 u;
    u.x = bf16bits(o.x); u.y = bf16bits(o.y); u.z = bf16bits(o.z); u.w = bf16bits(o.w);
    *(ushort4*)((unsigned short*)bout + (size_t)t * 1024 + tid * 4) = u;
}

// ---------------- host ----------------
extern "C" void kernel_launch(void* const* d_in, const int* in_sizes, int n_in,
                              void* d_out, int out_size, void* d_ws, size_t ws_size,
                              hipStream_t stream) {
    const int* seq = (const int*)d_in[0];
    const float* tok = (const float*)d_in[1];
    const float* dist = (const float*)d_in[2];
    const float* Wqkv = (const float*)d_in[3];
    const float* bqkv = (const float*)d_in[4];
    const float* Wo = (const float*)d_in[5];
    const float* bo = (const float*)d_in[6];
    const float* W1 = (const float*)d_in[7];
    const float* b1 = (const float*)d_in[8];
    const float* W2 = (const float*)d_in[9];
    const float* b2 = (const float*)d_in[10];
    const float* ln1s = (const float*)d_in[11];
    const float* ln1b = (const float*)d_in[12];
    const float* ln2s = (const float*)d_in[13];
    const float* ln2b = (const float*)d_in[14];
    const float* lnfs = (const float*)d_in[15];
    const float* lnfb = (const float*)d_in[16];
    const float* Wg = (const float*)d_in[17];
    const float* bg = (const float*)d_in[18];
    float* out = (float*)d_out;

    const size_t base_need = (size_t)300 * 1024 * 1024;
    const int ffn2_splits = (ws_size >= base_need) ? 4 : 2;
    const int wo_splits = (ffn2_splits == 4) ? 4 : 2;  // needs 4 partial slots

    char* p = (char*)d_ws;
    auto take = [&](size_t bytes) {
        char* r = p;
        p += (bytes + 255) & ~(size_t)255;
        return r;
    };
    __hip_bfloat16* wqkv_b = (__hip_bfloat16*)take((size_t)6 * 3072 * 1024 * 2);
    __hip_bfloat16* wo_b = (__hip_bfloat16*)take((size_t)6 * 1024 * 1024 * 2);
    __hip_bfloat16* w1_b = (__hip_bfloat16*)take((size_t)6 * 4096 * 1024 * 2);
    __hip_bfloat16* w2_b = (__hip_bfloat16*)take((size_t)6 * 1024 * 4096 * 2);
    __hip_bfloat16* wg_b = (__hip_bfloat16*)take((size_t)32000 * 1024 * 2);
    float* xf = (float*)take((size_t)2048 * 1024 * 4);
    __hip_bfloat16* xb = (__hip_bfloat16*)take((size_t)2048 * 1024 * 2);
    __hip_bfloat16* qkvb = (__hip_bfloat16*)take((size_t)2048 * 3072 * 2);
    __hip_bfloat16* hb = (__hip_bfloat16*)take((size_t)2048 * 4096 * 2);
    __hip_bfloat16* ab = (__hip_bfloat16*)take((size_t)2048 * 1024 * 2);
    __hip_bfloat16* vTb = (__hip_bfloat16*)take((size_t)64 * 64 * 512 * 2);
    float* biasT = (float*)take((size_t)16 * 513 * 4);
    __hip_bfloat16* tmpb = (__hip_bfloat16*)take((size_t)ffn2_splits * 2048 * 1024 * 2);
    __hip_bfloat16* tmpb1 = tmpb + (size_t)2048 * 1024;
    __hip_bfloat16* tmpb2 = (ffn2_splits == 4) ? tmpb + (size_t)2 * 2048 * 1024 : nullptr;
    __hip_bfloat16* tmpb3 = (ffn2_splits == 4) ? tmpb + (size_t)3 * 2048 * 1024 : nullptr;

    k_conv5<<<dim3(52864), dim3(256), 0, stream>>>(
        Wqkv, Wo, W1, W2, Wg, wqkv_b, wo_b, w1_b, w2_b, wg_b,
        9216, 9216 + 3072, 9216 + 3072 + 12288, 9216 + 3072 + 12288 + 12288);
    k_bias_prep<<<dim3(16), dim3(256), 0, stream>>>(dist, biasT);
    k_embed<<<dim3(2048), dim3(256), 0, stream>>>(seq, tok, xf, xb);

    for (int l = 0; l < 6; ++l) {
        // QKV: 2048 x 3072 x 1024 (128^2 tiles: 384 wgs), bf16 out
        k_gemm<0><<<dim3(16 * 24), dim3(256), 0, stream>>>(
            xb, wqkv_b + (size_t)l * 3072 * 1024, bqkv + l * 3072, nullptr, qkvb,
            2048, 3072, 1024, 1024, 16, 0);
        k_vtrans<<<dim3(8, 64), dim3(256), 0, stream>>>(qkvb, vTb);
        k_attn<<<dim3(512), dim3(256), 0, stream>>>(qkvb, vTb, seq, biasT, ab);
        // Wo: 2048 x 1024 x 1024, 128^2 split-K=4 (512 wgs = 2/CU) -> bf16 partials
        k_gemm<1><<<dim3(16 * 8, wo_splits), dim3(256), 0, stream>>>(
            ab, wo_b + (size_t)l * 1024 * 1024, bo + l * 1024, tmpb, nullptr,
            2048, 1024, 1024, 1024 / wo_splits, 16, 0);
        k_add_ln<<<dim3(2048), dim3(256), 0, stream>>>(
            xf, tmpb, tmpb1, (wo_splits == 4) ? tmpb2 : nullptr,
            (wo_splits == 4) ? tmpb3 : nullptr,
            ln1s + l * 1024, ln1b + l * 1024, xf, xb);
        // FFN1: 2048 x 4096 x 1024 (256x128 tiles: 256 wgs full coverage), GELU
        k_gemm256n<2><<<dim3(256), dim3(512), 0, stream>>>(
            xb, w1_b + (size_t)l * 4096 * 1024, b1 + l * 4096, nullptr, hb,
            2048, 4096, 1024, 1024, 8, 1);
        // FFN2: 2048 x 1024 x 4096 -> bf16 partials
        if (ffn2_splits == 4) {
            k_gemm256n<3><<<dim3(64, 4), dim3(512), 0, stream>>>(
                hb, w2_b + (size_t)l * 1024 * 4096, b2 + l * 1024, tmpb, nullptr,
                2048, 1024, 4096, 1024, 8, 0);
        } else {
            k_gemm<3><<<dim3(16 * 8, 2), dim3(256), 0, stream>>>(
                hb, w2_b + (size_t)l * 1024 * 4096, b2 + l * 1024, tmpb, nullptr,
                2048, 1024, 4096, 2048, 16, 0);
        }
        k_add_ln<<<dim3(2048), dim3(256), 0, stream>>>(xf, tmpb, tmpb1, tmpb2, tmpb3,
                                                       ln2s + l * 1024, ln2b + l * 1024, xf, xb);
    }
    k_add_ln<<<dim3(2048), dim3(256), 0, stream>>>(xf, nullptr, nullptr, nullptr, nullptr,
                                                   lnfs, lnfb, xf, xb);
    // vocab: 2048 x 32000 x 1024 (256^2 tiles: 8 x 125 = 1000 wgs), f32 out
    k_gemm256<4><<<dim3(1000), dim3(512), 0, stream>>>(xb, wg_b, bg, out, nullptr,
                                                       2048, 32000, 1024, 8, 0);
}

// Round 19
// 1189.415 us; speedup vs baseline: 1.0544x; 1.0172x over previous
//
#include <hip/hip_runtime.h>
#include <hip/hip_bf16.h>
#include <cstdint>

// Problem dims
// L=6, E=1024, H=16, F=4096, V=32000, B=4, S=512, ML=512, DH=64, tokens=2048

typedef float f32x4 __attribute__((ext_vector_type(4)));
typedef short s16x8 __attribute__((ext_vector_type(8)));
typedef __bf16 b16x8 __attribute__((ext_vector_type(8)));

struct Frag8 {
    s16x8 v;
    __device__ operator s16x8() const { return v; }
    __device__ operator b16x8() const { return __builtin_bit_cast(b16x8, v); }
};

__device__ __forceinline__ f32x4 mfma16(Frag8 a, Frag8 b, f32x4 c) {
    return __builtin_amdgcn_mfma_f32_16x16x32_bf16(a, b, c, 0, 0, 0);
}

__device__ __forceinline__ void gload_lds16(const void* g, void* l) {
    __builtin_amdgcn_global_load_lds(
        (__attribute__((address_space(1))) void*)g,
        (__attribute__((address_space(3))) void*)l, 16, 0, 0);
}

__device__ __forceinline__ unsigned short bf16bits(float x) {
    return __builtin_bit_cast(unsigned short, __float2bfloat16(x));
}

__device__ __forceinline__ float b2f(unsigned short u) {
    unsigned int x = (unsigned int)u << 16;
    return __builtin_bit_cast(float, x);
}

// ---------------- fused fp32 -> bf16 conversion (5 segments, 8 elems/thread) ----------------
__global__ __launch_bounds__(256) void k_conv5(const float* __restrict__ s0, const float* __restrict__ s1,
                                               const float* __restrict__ s2, const float* __restrict__ s3,
                                               const float* __restrict__ s4,
                                               __hip_bfloat16* __restrict__ d0, __hip_bfloat16* __restrict__ d1,
                                               __hip_bfloat16* __restrict__ d2, __hip_bfloat16* __restrict__ d3,
                                               __hip_bfloat16* __restrict__ d4,
                                               int b0, int b1, int b2, int b3) {
    const int blk = blockIdx.x;
    const float* src;
    __hip_bfloat16* dst;
    long base;
    if (blk < b0)      { src = s0; dst = d0; base = (long)blk * 2048; }
    else if (blk < b1) { src = s1; dst = d1; base = (long)(blk - b0) * 2048; }
    else if (blk < b2) { src = s2; dst = d2; base = (long)(blk - b1) * 2048; }
    else if (blk < b3) { src = s3; dst = d3; base = (long)(blk - b2) * 2048; }
    else               { src = s4; dst = d4; base = (long)(blk - b3) * 2048; }
    const long i = base + (long)threadIdx.x * 8;
    const float4 v0 = *(const float4*)(src + i);
    const float4 v1 = *(const float4*)(src + i + 4);
    s16x8 u;
    u[0] = (short)bf16bits(v0.x); u[1] = (short)bf16bits(v0.y);
    u[2] = (short)bf16bits(v0.z); u[3] = (short)bf16bits(v0.w);
    u[4] = (short)bf16bits(v1.x); u[5] = (short)bf16bits(v1.y);
    u[6] = (short)bf16bits(v1.z); u[7] = (short)bf16bits(v1.w);
    *(s16x8*)((unsigned short*)dst + i) = u;
}

// ---------------- bias pre-extraction: dist_emb[(i,h)] -> biasT[h][i] ----------------
__global__ __launch_bounds__(256) void k_bias_prep(const float* __restrict__ dist_emb,
                                                   float* __restrict__ biasT) {
    const int h = blockIdx.x;
    for (int i = threadIdx.x; i < 513; i += 256) biasT[h * 513 + i] = dist_emb[i * 16 + h];
}

// ---------------- embedding gather (bf16 residual stream only) ----------------
__global__ __launch_bounds__(256) void k_embed(const int* __restrict__ seq,
                                               const float* __restrict__ tok,
                                               __hip_bfloat16* __restrict__ xb) {
    const int t = blockIdx.x;
    const int tokid = seq[t];
    const float4 v = *(const float4*)(tok + (size_t)tokid * 1024 + threadIdx.x * 4);
    ushort4 u;
    u.x = bf16bits(v.x * 32.0f); u.y = bf16bits(v.y * 32.0f);
    u.z = bf16bits(v.z * 32.0f); u.w = bf16bits(v.w * 32.0f);
    *(ushort4*)((unsigned short*)xb + (size_t)t * 1024 + threadIdx.x * 4) = u;
}

// ---------------- V transpose: qkv V-part -> vT[b,h,d,s] (LDS-tiled, coalesced) ----------------
__global__ __launch_bounds__(256) void k_vtrans(const __hip_bfloat16* __restrict__ qkv,
                                                __hip_bfloat16* __restrict__ vT) {
    const int st = blockIdx.x;
    const int bh = blockIdx.y;
    const int b = bh >> 4, h = bh & 15;
    __shared__ __align__(16) short T[64][72];
    const int tid = threadIdx.x;
#pragma unroll
    for (int i = 0; i < 2; ++i) {
        const int c = i * 256 + tid;
        const int s = c >> 3, d0 = (c & 7) * 8;
        const s16x8 v = *(const s16x8*)(qkv + (size_t)(b * 512 + st * 64 + s) * 3072 + 2048 + h * 64 + d0);
#pragma unroll
        for (int j = 0; j < 8; ++j) T[d0 + j][s] = v[j];
    }
    __syncthreads();
#pragma unroll
    for (int i = 0; i < 2; ++i) {
        const int c = i * 256 + tid;
        const int d = c >> 3, s0 = (c & 7) * 8;
        const s16x8 v = *(const s16x8*)&T[d][s0];
        *(s16x8*)(vT + ((size_t)bh * 64 + d) * 512 + st * 64 + s0) = v;
    }
}

// ============ 256x256-tile 8-wave phase-interleaved GEMM (vocab, f32 out) ============
template <int TAG>
__global__ __launch_bounds__(512, 2) void k_gemm256(const __hip_bfloat16* __restrict__ A,
                                                    const __hip_bfloat16* __restrict__ B,
                                                    const float* __restrict__ bias,
                                                    float* __restrict__ Cf,
                                                    __hip_bfloat16* __restrict__ Cb,
                                                    const int M, const int N, const int K,
                                                    const int mtiles, const int act) {
    __shared__ __align__(16) char lds[131072];  // [buf][A 32KB | B 32KB] x2

    const int nwg = gridDim.x, bid = blockIdx.x;
    const int qq = nwg >> 3, rr = nwg & 7;
    const int xcd = bid & 7, local = bid >> 3;
    const int wgid = (xcd < rr ? xcd * (qq + 1) : rr * (qq + 1) + (xcd - rr) * qq) + local;
    const int m0 = (wgid % mtiles) * 256;
    const int n0 = (wgid / mtiles) * 256;

    const int tid = threadIdx.x;
    const int lane = tid & 63;
    const int wid = tid >> 6;
    const int wr = wid >> 2, wc = wid & 3;
    const int l16 = lane & 15, lq = lane >> 4;
    const int sw = l16 & 7;

    const int srow = tid >> 3;
    const int scol = ((tid & 7) ^ (srow & 7)) << 3;
    const __hip_bfloat16* aS = A + (size_t)(m0 + srow) * K + scol;
    const __hip_bfloat16* bS = B + (size_t)(n0 + srow) * K + scol;
    const size_t rstep = (size_t)64 * K;

    const int NT = K >> 6;
    const int arow = wr * 128 + l16;
    const int brow = wc * 64 + l16;

    auto stage = [&](int d, int isB, int blk, int kk) {
        const __hip_bfloat16* src = (isB ? bS : aS) + (size_t)blk * rstep + kk;
        char* dst = lds + d * 65536 + isB * 32768 + blk * 8192 + tid * 16;
        gload_lds16(src, dst);
    };

    stage(0, 1, 0, 0); stage(0, 1, 1, 0);
    stage(0, 1, 2, 0); stage(0, 1, 3, 0);
    stage(0, 0, 0, 0); stage(0, 0, 2, 0);
    stage(0, 0, 1, 0); stage(0, 0, 3, 0);
    asm volatile("s_waitcnt vmcnt(2)" ::: "memory");
    __builtin_amdgcn_sched_barrier(0);
    __builtin_amdgcn_s_barrier();
    __builtin_amdgcn_sched_barrier(0);

    f32x4 acc[8][4] = {};
    Frag8 bfr[2][4];

    for (int t = 0; t < NT; ++t) {
        const int d = t & 1;
        const char* Ab = lds + d * 65536;
        const char* Bb = Ab + 32768;
        const bool st = (t + 1 < NT);
        const int k1 = (t + 1) << 6;

#pragma unroll
        for (int q = 0; q < 4; ++q) {
            if (q == 0) {
#pragma unroll
                for (int ks = 0; ks < 2; ++ks)
#pragma unroll
                    for (int ni = 0; ni < 4; ++ni)
                        bfr[ks][ni].v = *(const s16x8*)(
                            Bb + (brow + ni * 16) * 128 + (((ks * 4 + lq) ^ sw) << 4));
            }
            Frag8 af[2][2];
#pragma unroll
            for (int m2 = 0; m2 < 2; ++m2)
#pragma unroll
                for (int ks = 0; ks < 2; ++ks)
                    af[m2][ks].v = *(const s16x8*)(
                        Ab + (arow + (q * 2 + m2) * 16) * 128 + (((ks * 4 + lq) ^ sw) << 4));

            if (st) {
                if (q == 0)      { stage(d ^ 1, 1, 0, k1); stage(d ^ 1, 1, 1, k1); }
                else if (q == 1) { stage(d ^ 1, 1, 2, k1); stage(d ^ 1, 1, 3, k1); }
                else if (q == 2) { stage(d ^ 1, 0, 0, k1); stage(d ^ 1, 0, 2, k1); }
                else             { stage(d ^ 1, 0, 1, k1); stage(d ^ 1, 0, 3, k1); }
            }

            // no pre-MFMA barrier: compiler inserts lgkmcnt for the ds_read deps
            __builtin_amdgcn_sched_barrier(0);
            __builtin_amdgcn_s_setprio(1);
#pragma unroll
            for (int ks = 0; ks < 2; ++ks)
#pragma unroll
                for (int m2 = 0; m2 < 2; ++m2)
#pragma unroll
                    for (int ni = 0; ni < 4; ++ni)
                        acc[q * 2 + m2][ni] = mfma16(af[m2][ks], bfr[ks][ni], acc[q * 2 + m2][ni]);
            __builtin_amdgcn_s_setprio(0);
            __builtin_amdgcn_sched_barrier(0);
            if (q == 1) {
                if (st) asm volatile("s_waitcnt vmcnt(4)" ::: "memory");
                else    asm volatile("s_waitcnt vmcnt(0)" ::: "memory");
            } else if (q == 3) {
                if (st) asm volatile("s_waitcnt vmcnt(2)" ::: "memory");
                else    asm volatile("s_waitcnt vmcnt(0)" ::: "memory");
            }
            __builtin_amdgcn_s_barrier();
            __builtin_amdgcn_sched_barrier(0);
        }
    }

#pragma unroll
    for (int mi = 0; mi < 8; ++mi) {
        const int rowb = m0 + wr * 128 + mi * 16 + lq * 4;
#pragma unroll
        for (int ni = 0; ni < 4; ++ni) {
            const int col = n0 + wc * 64 + ni * 16 + l16;
            const float bv = bias[col];
#pragma unroll
            for (int r = 0; r < 4; ++r) {
                float v2 = acc[mi][ni][r] + bv;
                if (act == 1) v2 = 0.5f * v2 * (1.0f + erff(v2 * 0.70710678118654752f));
                const size_t idx = (size_t)(rowb + r) * N + col;
                if (Cf) Cf[idx] = v2;
                if (Cb) Cb[idx] = __float2bfloat16(v2);
            }
        }
    }
}

// ============ 256x128-tile 8-wave barrier-free GEMM (FFN1 / FFN2 split-K) ============
// grid.y = split-K slice; partials written as bf16 to Cp (bias only in slice 0).
template <int TAG>
__global__ __launch_bounds__(512, 2) void k_gemm256n(const __hip_bfloat16* __restrict__ A,
                                                     const __hip_bfloat16* __restrict__ B,
                                                     const float* __restrict__ bias,
                                                     __hip_bfloat16* __restrict__ Cp,
                                                     __hip_bfloat16* __restrict__ Cb,
                                                     const int M, const int N, const int K,
                                                     const int Ksub, const int mtiles,
                                                     const int act) {
    __shared__ __align__(16) char lds[98304];  // 2 bufs x (A 32KB | B 16KB)

    const int nwg = gridDim.x, bid = blockIdx.x;
    const int qq = nwg >> 3, rr = nwg & 7;
    const int xcd = bid & 7, local = bid >> 3;
    const int wgid = (xcd < rr ? xcd * (qq + 1) : rr * (qq + 1) + (xcd - rr) * qq) + local;
    const int m0 = (wgid % mtiles) * 256;
    const int n0 = (wgid / mtiles) * 128;

    const int tid = threadIdx.x;
    const int lane = tid & 63;
    const int wid = tid >> 6;
    const int wr = wid >> 2, wc = wid & 3;
    const int l16 = lane & 15, lq = lane >> 4;
    const int sw = l16 & 7;

    const int kb = blockIdx.y * Ksub;
    const int srow = tid >> 3;
    const int scol = ((tid & 7) ^ (srow & 7)) << 3;
    const __hip_bfloat16* aS = A + (size_t)(m0 + srow) * K + scol + kb;
    const __hip_bfloat16* bS = B + (size_t)(n0 + srow) * K + scol + kb;
    const size_t rstep = (size_t)64 * K;

    const int NT = Ksub >> 6;
    const int arow = wr * 128 + l16;
    const int brow = wc * 32 + l16;

    auto stage = [&](int d, int isB, int blk, int kk) {
        const __hip_bfloat16* src = (isB ? bS : aS) + (size_t)blk * rstep + kk;
        char* dst = lds + d * 49152 + isB * 32768 + blk * 8192 + tid * 16;
        gload_lds16(src, dst);
    };

    // prologue: stage K-tile 0, order = [B0,B1, A0,A2, A1,A3]
    stage(0, 1, 0, 0); stage(0, 1, 1, 0);
    stage(0, 0, 0, 0); stage(0, 0, 2, 0);
    stage(0, 0, 1, 0); stage(0, 0, 3, 0);
    asm volatile("s_waitcnt vmcnt(2)" ::: "memory");
    __builtin_amdgcn_sched_barrier(0);
    __builtin_amdgcn_s_barrier();
    __builtin_amdgcn_sched_barrier(0);

    f32x4 acc[8][2] = {};
    Frag8 bfr[2][2];

    for (int t = 0; t < NT; ++t) {
        const int d = t & 1;
        const char* Ab = lds + d * 49152;
        const char* Bb = Ab + 32768;
        const bool st = (t + 1 < NT);
        const int k1 = (t + 1) << 6;

#pragma unroll
        for (int q = 0; q < 4; ++q) {
            if (q == 0) {
#pragma unroll
                for (int ks = 0; ks < 2; ++ks)
#pragma unroll
                    for (int ni = 0; ni < 2; ++ni)
                        bfr[ks][ni].v = *(const s16x8*)(
                            Bb + (brow + ni * 16) * 128 + (((ks * 4 + lq) ^ sw) << 4));
            }
            Frag8 af[2][2];
#pragma unroll
            for (int m2 = 0; m2 < 2; ++m2)
#pragma unroll
                for (int ks = 0; ks < 2; ++ks)
                    af[m2][ks].v = *(const s16x8*)(
                        Ab + (arow + (q * 2 + m2) * 16) * 128 + (((ks * 4 + lq) ^ sw) << 4));

            if (st) {
                if (q == 0)      { stage(d ^ 1, 1, 0, k1); stage(d ^ 1, 1, 1, k1); }
                else if (q == 1) { stage(d ^ 1, 0, 0, k1); stage(d ^ 1, 0, 2, k1); }
                else if (q == 2) { stage(d ^ 1, 0, 1, k1); stage(d ^ 1, 0, 3, k1); }
            }

            __builtin_amdgcn_sched_barrier(0);
            __builtin_amdgcn_s_setprio(1);
#pragma unroll
            for (int ks = 0; ks < 2; ++ks)
#pragma unroll
                for (int m2 = 0; m2 < 2; ++m2)
#pragma unroll
                    for (int ni = 0; ni < 2; ++ni)
                        acc[q * 2 + m2][ni] = mfma16(af[m2][ks], bfr[ks][ni], acc[q * 2 + m2][ni]);
            __builtin_amdgcn_s_setprio(0);
            __builtin_amdgcn_sched_barrier(0);
            if (q == 1) {
                if (st) asm volatile("s_waitcnt vmcnt(4)" ::: "memory");
                else    asm volatile("s_waitcnt vmcnt(0)" ::: "memory");
            } else if (q == 3) {
                if (st) asm volatile("s_waitcnt vmcnt(2)" ::: "memory");
                else    asm volatile("s_waitcnt vmcnt(0)" ::: "memory");
            }
            __builtin_amdgcn_s_barrier();
            __builtin_amdgcn_sched_barrier(0);
        }
    }

    __hip_bfloat16* Cpp = Cp ? Cp + (size_t)blockIdx.y * M * N : nullptr;
    const bool addb = (blockIdx.y == 0);

#pragma unroll
    for (int mi = 0; mi < 8; ++mi) {
        const int rowb = m0 + wr * 128 + mi * 16 + lq * 4;
#pragma unroll
        for (int ni = 0; ni < 2; ++ni) {
            const int col = n0 + wc * 32 + ni * 16 + l16;
            const float bv = addb ? bias[col] : 0.0f;
#pragma unroll
            for (int r = 0; r < 4; ++r) {
                float v2 = acc[mi][ni][r] + bv;
                if (act == 1) v2 = 0.5f * v2 * (1.0f + erff(v2 * 0.70710678118654752f));
                const size_t idx = (size_t)(rowb + r) * N + col;
                if (Cpp) Cpp[idx] = __float2bfloat16(v2);
                if (Cb) Cb[idx] = __float2bfloat16(v2);
            }
        }
    }
}

// ============ 128x128-tile pipelined GEMM (QKV, Wo, fallback) ============
__device__ __forceinline__ const s16x8* fragp(const char* base, int row, int lq) {
    const int line = row >> 1;
    const int u = ((row & 1) << 2) | lq;
    return (const s16x8*)(base + line * 128 + ((u ^ (line & 7)) << 4));
}

template <int TAG>
__global__ __launch_bounds__(256, 2) void k_gemm(const __hip_bfloat16* __restrict__ A,
                                                 const __hip_bfloat16* __restrict__ B,
                                                 const float* __restrict__ bias,
                                                 __hip_bfloat16* __restrict__ Cp,
                                                 __hip_bfloat16* __restrict__ Cb,
                                                 const int M, const int N, const int K,
                                                 const int Ksub, const int mtiles,
                                                 const int act) {
    __shared__ __align__(16) char lds[3 * 16384];

    const int nwg = gridDim.x;
    const int bid = blockIdx.x;
    const int q = nwg >> 3, r = nwg & 7;
    const int xcd = bid & 7, local = bid >> 3;
    const int wgid = (xcd < r ? xcd * (q + 1) : r * (q + 1) + (xcd - r) * q) + local;
    const int m0 = (wgid % mtiles) * 128;
    const int n0 = (wgid / mtiles) * 128;

    const int tid = threadIdx.x;
    const int lane = tid & 63, w = tid >> 6;
    const int wr = w >> 1, wc = w & 1;
    const int l16 = lane & 15, lq = lane >> 4;

    const int kb = blockIdx.y * Ksub;
    const int NT = Ksub >> 5;

    int arow0, acol0, arow1, acol1;
    {
        const int c0 = tid, line0 = c0 >> 3, u0 = (c0 & 7) ^ (line0 & 7);
        arow0 = (line0 << 1) | (u0 >> 2); acol0 = (u0 & 3) * 8;
        const int c1 = tid + 256, line1 = c1 >> 3, u1 = (c1 & 7) ^ (line1 & 7);
        arow1 = (line1 << 1) | (u1 >> 2); acol1 = (u1 & 3) * 8;
    }
    const size_t abase0 = (size_t)(m0 + arow0) * K + acol0 + kb;
    const size_t abase1 = (size_t)(m0 + arow1) * K + acol1 + kb;
    const size_t bbase0 = (size_t)(n0 + arow0) * K + acol0 + kb;
    const size_t bbase1 = (size_t)(n0 + arow1) * K + acol1 + kb;

    auto stageA = [&](int tt, int buf) {
        char* dst = lds + buf * 16384;
        gload_lds16(A + abase0 + tt * 32, dst + tid * 16);
        gload_lds16(A + abase1 + tt * 32, dst + (tid + 256) * 16);
    };
    auto stageB = [&](int tt, int buf) {
        char* dst = lds + buf * 16384 + 8192;
        gload_lds16(B + bbase0 + tt * 32, dst + tid * 16);
        gload_lds16(B + bbase1 + tt * 32, dst + (tid + 256) * 16);
    };

    f32x4 acc[4][4] = {};

    stageA(0, 0); stageB(0, 0);
    stageA(1, 1); stageB(1, 1);
    asm volatile("s_waitcnt vmcnt(4)" ::: "memory");
    __builtin_amdgcn_sched_barrier(0);
    __builtin_amdgcn_s_barrier();
    __builtin_amdgcn_sched_barrier(0);

    int cur = 0;
    for (int t = 0; t < NT; ++t) {
        const int stb = (cur == 0) ? 2 : cur - 1;
        const char* Ab = lds + cur * 16384;
        const char* Bb = Ab + 8192;
        const bool doStage = (t + 2 < NT);

        if (doStage) stageA(t + 2, stb);

        Frag8 a0, a1, b0, b1, b2, b3;
        a0.v = *fragp(Ab, wr * 64 + l16, lq);
        a1.v = *fragp(Ab, wr * 64 + 16 + l16, lq);
        b0.v = *fragp(Bb, wc * 64 + l16, lq);
        b1.v = *fragp(Bb, wc * 64 + 16 + l16, lq);
        b2.v = *fragp(Bb, wc * 64 + 32 + l16, lq);
        b3.v = *fragp(Bb, wc * 64 + 48 + l16, lq);

        __builtin_amdgcn_s_setprio(1);
        acc[0][0] = mfma16(a0, b0, acc[0][0]);
        acc[0][1] = mfma16(a0, b1, acc[0][1]);
        acc[0][2] = mfma16(a0, b2, acc[0][2]);
        acc[0][3] = mfma16(a0, b3, acc[0][3]);
        acc[1][0] = mfma16(a1, b0, acc[1][0]);
        acc[1][1] = mfma16(a1, b1, acc[1][1]);
        acc[1][2] = mfma16(a1, b2, acc[1][2]);
        acc[1][3] = mfma16(a1, b3, acc[1][3]);
        __builtin_amdgcn_s_setprio(0);

        if (doStage) stageB(t + 2, stb);

        Frag8 a2, a3;
        a2.v = *fragp(Ab, wr * 64 + 32 + l16, lq);
        a3.v = *fragp(Ab, wr * 64 + 48 + l16, lq);

        __builtin_amdgcn_s_setprio(1);
        acc[2][0] = mfma16(a2, b0, acc[2][0]);
        acc[2][1] = mfma16(a2, b1, acc[2][1]);
        acc[2][2] = mfma16(a2, b2, acc[2][2]);
        acc[2][3] = mfma16(a2, b3, acc[2][3]);
        acc[3][0] = mfma16(a3, b0, acc[3][0]);
        acc[3][1] = mfma16(a3, b1, acc[3][1]);
        acc[3][2] = mfma16(a3, b2, acc[3][2]);
        acc[3][3] = mfma16(a3, b3, acc[3][3]);
        __builtin_amdgcn_s_setprio(0);

        if (t + 3 < NT) {
            asm volatile("s_waitcnt vmcnt(4)" ::: "memory");
        } else {
            asm volatile("s_waitcnt vmcnt(0)" ::: "memory");
        }
        __builtin_amdgcn_sched_barrier(0);
        __builtin_amdgcn_s_barrier();
        __builtin_amdgcn_sched_barrier(0);

        cur = (cur == 2) ? 0 : cur + 1;
    }

    __hip_bfloat16* Cpp = Cp ? Cp + (size_t)blockIdx.y * M * N : nullptr;
    const bool addb = (blockIdx.y == 0);

#pragma unroll
    for (int mi = 0; mi < 4; ++mi) {
        const int rowb = m0 + wr * 64 + mi * 16 + lq * 4;
#pragma unroll
        for (int ni = 0; ni < 4; ++ni) {
            const int col = n0 + wc * 64 + ni * 16 + l16;
            const float bv = addb ? bias[col] : 0.0f;
#pragma unroll
            for (int rr = 0; rr < 4; ++rr) {
                float v2 = acc[mi][ni][rr] + bv;
                if (act == 1) v2 = 0.5f * v2 * (1.0f + erff(v2 * 0.70710678118654752f));
                const size_t idx = (size_t)(rowb + rr) * N + col;
                if (Cpp) Cpp[idx] = __float2bfloat16(v2);
                if (Cb) Cb[idx] = __float2bfloat16(v2);
            }
        }
    }
}

// ---------------- flash attention (round-11 compute, CU-load-balanced remap) ----------------
__global__ __launch_bounds__(256) void k_attn(const __hip_bfloat16* __restrict__ qkv,
                                              const __hip_bfloat16* __restrict__ vT,
                                              const int* __restrict__ seq,
                                              const float* __restrict__ biasT,
                                              __hip_bfloat16* __restrict__ out) {
    const int f = blockIdx.x;
    const int half = f >> 8;
    const int qb = half ? (7 - (f & 7)) : (f & 7);
    const int hb = ((f & 255) >> 3) + (half << 5);
    const int h = hb & 15, b = hb >> 4;
    const int q0 = qb * 64;
    const int tid = threadIdx.x, lane = tid & 63, w = tid >> 6;
    const int l16 = lane & 15, lq = lane >> 4;

    __shared__ __align__(16) char Ks[2 * 8192];
    __shared__ __align__(16) char Vs[2 * 8192];
    __shared__ __align__(16) char Ps[4 * 2048];
    __shared__ float bias_l[513];
    __shared__ float pad_l[512];

    for (int i = tid; i < 513; i += 256) bias_l[i] = biasT[h * 513 + i];
    for (int i = tid; i < 512; i += 256) pad_l[i] = (seq[b * 512 + i] == 0) ? -1e9f : 0.0f;

    const int qrowA = q0 + w * 16 + l16;
    const __hip_bfloat16* qptr = qkv + (size_t)(b * 512 + qrowA) * 3072 + h * 64;
    Frag8 qf[2];
    qf[0].v = *(const s16x8*)(qptr + lq * 8);
    qf[1].v = *(const s16x8*)(qptr + 32 + lq * 8);

    const int kr0 = tid >> 3, sl = tid & 7;
    const int kr1 = kr0 + 32;
    char* kdst0 = Ks + kr0 * 128 + ((sl ^ (kr0 & 7)) * 16);
    char* kdst1 = Ks + kr1 * 128 + ((sl ^ (kr1 & 7)) * 16);
    char* vdst0 = Vs + kr0 * 128 + ((sl ^ (kr0 & 7)) * 16);
    char* vdst1 = Vs + kr1 * 128 + ((sl ^ (kr1 & 7)) * 16);
    const __hip_bfloat16* vbase = vT + (size_t)(b * 16 + h) * 64 * 512;

    s16x8 kreg0, kreg1, vreg0, vreg1;
    auto load_regs = [&](int kt) {
        const size_t kb_ = (size_t)(b * 512 + kt * 64) * 3072 + h * 64 + 1024;
        kreg0 = *(const s16x8*)(qkv + kb_ + (size_t)kr0 * 3072 + sl * 8);
        kreg1 = *(const s16x8*)(qkv + kb_ + (size_t)kr1 * 3072 + sl * 8);
        vreg0 = *(const s16x8*)(vbase + (size_t)kr0 * 512 + kt * 64 + sl * 8);
        vreg1 = *(const s16x8*)(vbase + (size_t)kr1 * 512 + kt * 64 + sl * 8);
    };

    f32x4 oacc[4] = {};
    float mrow[4] = {-1e30f, -1e30f, -1e30f, -1e30f};
    float lrow[4] = {0.f, 0.f, 0.f, 0.f};
    char* PsW = Ps + w * 2048;

    load_regs(0);
    for (int kt = 0; kt <= qb; ++kt) {
        const int bo = (kt & 1) * 8192;
        *(s16x8*)(kdst0 + bo) = kreg0;
        *(s16x8*)(kdst1 + bo) = kreg1;
        *(s16x8*)(vdst0 + bo) = vreg0;
        *(s16x8*)(vdst1 + bo) = vreg1;
        __syncthreads();
        if (kt < qb) load_regs(kt + 1);

        const char* Kb = Ks + bo;
        const char* Vb = Vs + bo;

        f32x4 sacc[4] = {};
#pragma unroll
        for (int ks = 0; ks < 2; ++ks) {
#pragma unroll
            for (int nf = 0; nf < 4; ++nf) {
                const int key = nf * 16 + l16;
                Frag8 kf;
                kf.v = *(const s16x8*)(Kb + key * 128 + (((ks * 4 + lq) ^ (key & 7)) * 16));
                sacc[nf] = mfma16(qf[ks], kf, sacc[nf]);
            }
        }

        float pvv[4][4];
#pragma unroll
        for (int nf = 0; nf < 4; ++nf) {
            const int keyg = kt * 64 + nf * 16 + l16;
            const float padv = pad_l[keyg];
#pragma unroll
            for (int rr = 0; rr < 4; ++rr) {
                const int qg = q0 + w * 16 + lq * 4 + rr;
                pvv[nf][rr] = (keyg > qg) ? -1e9f
                            : sacc[nf][rr] * 0.125f + bias_l[qg - keyg] + padv;
            }
        }

#pragma unroll
        for (int rr = 0; rr < 4; ++rr) {
            float tm = fmaxf(fmaxf(pvv[0][rr], pvv[1][rr]), fmaxf(pvv[2][rr], pvv[3][rr]));
#pragma unroll
            for (int off = 1; off < 16; off <<= 1) tm = fmaxf(tm, __shfl_xor(tm, off, 64));
            const float mnew = fmaxf(mrow[rr], tm);
            const float sf = __expf(mrow[rr] - mnew);
            mrow[rr] = mnew;
            float ts = 0.f;
#pragma unroll
            for (int nf = 0; nf < 4; ++nf) {
                const float pe = __expf(pvv[nf][rr] - mnew);
                pvv[nf][rr] = pe;
                ts += pe;
            }
#pragma unroll
            for (int off = 1; off < 16; off <<= 1) ts += __shfl_xor(ts, off, 64);
            lrow[rr] = lrow[rr] * sf + ts;
            oacc[0][rr] *= sf; oacc[1][rr] *= sf; oacc[2][rr] *= sf; oacc[3][rr] *= sf;
        }

#pragma unroll
        for (int nf = 0; nf < 4; ++nf) {
            const int cc = nf * 16 + l16;
            const int slot = cc >> 3, rem = cc & 7;
#pragma unroll
            for (int rr = 0; rr < 4; ++rr) {
                const int row = lq * 4 + rr;
                *(short*)(PsW + row * 128 + ((slot ^ (row & 7)) * 16) + rem * 2) =
                    (short)bf16bits(pvv[nf][rr]);
            }
        }

#pragma unroll
        for (int ks = 0; ks < 2; ++ks) {
            Frag8 pf;
            pf.v = *(const s16x8*)(PsW + l16 * 128 + (((ks * 4 + lq) ^ (l16 & 7)) * 16));
#pragma unroll
            for (int nf = 0; nf < 4; ++nf) {
                const int d = nf * 16 + l16;
                Frag8 vf;
                vf.v = *(const s16x8*)(Vb + d * 128 + (((ks * 4 + lq) ^ (d & 7)) * 16));
                oacc[nf] = mfma16(pf, vf, oacc[nf]);
            }
        }
    }

#pragma unroll
    for (int nf = 0; nf < 4; ++nf) {
        const int d = nf * 16 + l16;
#pragma unroll
        for (int rr = 0; rr < 4; ++rr) {
            const int qg = q0 + w * 16 + lq * 4 + rr;
            out[(size_t)(b * 512 + qg) * 1024 + h * 64 + d] = __float2bfloat16(oacc[nf][rr] / lrow[rr]);
        }
    }
}

// ---------------- fused residual add (bf16 residual + up to 4 bf16 partials) + LayerNorm ----
// Residual stream lives only in bf16 (xb). In-place safe: each block reads/writes its own row.
__global__ __launch_bounds__(256) void k_add_ln(const __hip_bfloat16* __restrict__ xin,
                                                const __hip_bfloat16* __restrict__ res0,
                                                const __hip_bfloat16* __restrict__ res1,
                                                const __hip_bfloat16* __restrict__ res2,
                                                const __hip_bfloat16* __restrict__ res3,
                                                const float* __restrict__ gamma,
                                                const float* __restrict__ beta,
                                                __hip_bfloat16* __restrict__ bout) {
    const int t = blockIdx.x;
    const int tid = threadIdx.x;
    const ushort4 xv = *(const ushort4*)((const unsigned short*)xin + (size_t)t * 1024 + tid * 4);
    float4 y;
    y.x = b2f(xv.x); y.y = b2f(xv.y); y.z = b2f(xv.z); y.w = b2f(xv.w);
    const __hip_bfloat16* rs[4] = {res0, res1, res2, res3};
#pragma unroll
    for (int k = 0; k < 4; ++k) {
        if (rs[k]) {
            const ushort4 rv = *(const ushort4*)((const unsigned short*)rs[k] + (size_t)t * 1024 + tid * 4);
            y.x += b2f(rv.x); y.y += b2f(rv.y); y.z += b2f(rv.z); y.w += b2f(rv.w);
        }
    }
    float s = y.x + y.y + y.z + y.w;
    float s2 = y.x * y.x + y.y * y.y + y.z * y.z + y.w * y.w;
#pragma unroll
    for (int off = 32; off >= 1; off >>= 1) {
        s += __shfl_xor(s, off, 64);
        s2 += __shfl_xor(s2, off, 64);
    }
    __shared__ float red[8];
    const int w = tid >> 6, lane = tid & 63;
    if (lane == 0) { red[w] = s; red[4 + w] = s2; }
    __syncthreads();
    const float tot = red[0] + red[1] + red[2] + red[3];
    const float tot2 = red[4] + red[5] + red[6] + red[7];
    const float mean = tot * (1.0f / 1024.0f);
    const float var = tot2 * (1.0f / 1024.0f) - mean * mean;
    const float inv = rsqrtf(var + 1e-5f);
    const float4 g = *(const float4*)(gamma + tid * 4);
    const float4 bb = *(const float4*)(beta + tid * 4);
    ushort4 u;
    u.x = bf16bits((y.x - mean) * inv * g.x + bb.x);
    u.y = bf16bits((y.y - mean) * inv * g.y + bb.y);
    u.z = bf16bits((y.z - mean) * inv * g.z + bb.z);
    u.w = bf16bits((y.w - mean) * inv * g.w + bb.w);
    *(ushort4*)((unsigned short*)bout + (size_t)t * 1024 + tid * 4) = u;
}

// ---------------- host ----------------
extern "C" void kernel_launch(void* const* d_in, const int* in_sizes, int n_in,
                              void* d_out, int out_size, void* d_ws, size_t ws_size,
                              hipStream_t stream) {
    const int* seq = (const int*)d_in[0];
    const float* tok = (const float*)d_in[1];
    const float* dist = (const float*)d_in[2];
    const float* Wqkv = (const float*)d_in[3];
    const float* bqkv = (const float*)d_in[4];
    const float* Wo = (const float*)d_in[5];
    const float* bo = (const float*)d_in[6];
    const float* W1 = (const float*)d_in[7];
    const float* b1 = (const float*)d_in[8];
    const float* W2 = (const float*)d_in[9];
    const float* b2 = (const float*)d_in[10];
    const float* ln1s = (const float*)d_in[11];
    const float* ln1b = (const float*)d_in[12];
    const float* ln2s = (const float*)d_in[13];
    const float* ln2b = (const float*)d_in[14];
    const float* lnfs = (const float*)d_in[15];
    const float* lnfb = (const float*)d_in[16];
    const float* Wg = (const float*)d_in[17];
    const float* bg = (const float*)d_in[18];
    float* out = (float*)d_out;

    const size_t base_need = (size_t)300 * 1024 * 1024;
    const int ffn2_splits = (ws_size >= base_need) ? 4 : 2;
    const int wo_splits = (ffn2_splits == 4) ? 4 : 2;

    char* p = (char*)d_ws;
    auto take = [&](size_t bytes) {
        char* r = p;
        p += (bytes + 255) & ~(size_t)255;
        return r;
    };
    __hip_bfloat16* wqkv_b = (__hip_bfloat16*)take((size_t)6 * 3072 * 1024 * 2);
    __hip_bfloat16* wo_b = (__hip_bfloat16*)take((size_t)6 * 1024 * 1024 * 2);
    __hip_bfloat16* w1_b = (__hip_bfloat16*)take((size_t)6 * 4096 * 1024 * 2);
    __hip_bfloat16* w2_b = (__hip_bfloat16*)take((size_t)6 * 1024 * 4096 * 2);
    __hip_bfloat16* wg_b = (__hip_bfloat16*)take((size_t)32000 * 1024 * 2);
    __hip_bfloat16* xb = (__hip_bfloat16*)take((size_t)2048 * 1024 * 2);
    __hip_bfloat16* qkvb = (__hip_bfloat16*)take((size_t)2048 * 3072 * 2);
    __hip_bfloat16* hb = (__hip_bfloat16*)take((size_t)2048 * 4096 * 2);
    __hip_bfloat16* ab = (__hip_bfloat16*)take((size_t)2048 * 1024 * 2);
    __hip_bfloat16* vTb = (__hip_bfloat16*)take((size_t)64 * 64 * 512 * 2);
    float* biasT = (float*)take((size_t)16 * 513 * 4);
    __hip_bfloat16* tmpb = (__hip_bfloat16*)take((size_t)ffn2_splits * 2048 * 1024 * 2);
    __hip_bfloat16* tmpb1 = tmpb + (size_t)2048 * 1024;
    __hip_bfloat16* tmpb2 = (ffn2_splits == 4) ? tmpb + (size_t)2 * 2048 * 1024 : nullptr;
    __hip_bfloat16* tmpb3 = (ffn2_splits == 4) ? tmpb + (size_t)3 * 2048 * 1024 : nullptr;

    k_conv5<<<dim3(52864), dim3(256), 0, stream>>>(
        Wqkv, Wo, W1, W2, Wg, wqkv_b, wo_b, w1_b, w2_b, wg_b,
        9216, 9216 + 3072, 9216 + 3072 + 12288, 9216 + 3072 + 12288 + 12288);
    k_bias_prep<<<dim3(16), dim3(256), 0, stream>>>(dist, biasT);
    k_embed<<<dim3(2048), dim3(256), 0, stream>>>(seq, tok, xb);

    for (int l = 0; l < 6; ++l) {
        // QKV: 2048 x 3072 x 1024 (128^2 tiles: 384 wgs), bf16 out
        k_gemm<0><<<dim3(16 * 24), dim3(256), 0, stream>>>(
            xb, wqkv_b + (size_t)l * 3072 * 1024, bqkv + l * 3072, nullptr, qkvb,
            2048, 3072, 1024, 1024, 16, 0);
        k_vtrans<<<dim3(8, 64), dim3(256), 0, stream>>>(qkvb, vTb);
        k_attn<<<dim3(512), dim3(256), 0, stream>>>(qkvb, vTb, seq, biasT, ab);
        // Wo: 2048 x 1024 x 1024, 128^2 split-K -> bf16 partials
        k_gemm<1><<<dim3(16 * 8, wo_splits), dim3(256), 0, stream>>>(
            ab, wo_b + (size_t)l * 1024 * 1024, bo + l * 1024, tmpb, nullptr,
            2048, 1024, 1024, 1024 / wo_splits, 16, 0);
        k_add_ln<<<dim3(2048), dim3(256), 0, stream>>>(
            xb, tmpb, tmpb1, (wo_splits == 4) ? tmpb2 : nullptr,
            (wo_splits == 4) ? tmpb3 : nullptr,
            ln1s + l * 1024, ln1b + l * 1024, xb);
        // FFN1: 2048 x 4096 x 1024 (256x128 tiles: 256 wgs full coverage), GELU
        k_gemm256n<2><<<dim3(256), dim3(512), 0, stream>>>(
            xb, w1_b + (size_t)l * 4096 * 1024, b1 + l * 4096, nullptr, hb,
            2048, 4096, 1024, 1024, 8, 1);
        // FFN2: 2048 x 1024 x 4096 -> bf16 partials
        if (ffn2_splits == 4) {
            k_gemm256n<3><<<dim3(64, 4), dim3(512), 0, stream>>>(
                hb, w2_b + (size_t)l * 1024 * 4096, b2 + l * 1024, tmpb, nullptr,
                2048, 1024, 4096, 1024, 8, 0);
        } else {
            k_gemm<3><<<dim3(16 * 8, 2), dim3(256), 0, stream>>>(
                hb, w2_b + (size_t)l * 1024 * 4096, b2 + l * 1024, tmpb, nullptr,
                2048, 1024, 4096, 2048, 16, 0);
        }
        k_add_ln<<<dim3(2048), dim3(256), 0, stream>>>(xb, tmpb, tmpb1, tmpb2, tmpb3,
                                                       ln2s + l * 1024, ln2b + l * 1024, xb);
    }
    k_add_ln<<<dim3(2048), dim3(256), 0, stream>>>(xb, nullptr, nullptr, nullptr, nullptr,
                                                   lnfs, lnfb, xb);
    // vocab: 2048 x 32000 x 1024 (256^2 tiles: 8 x 125 = 1000 wgs), f32 out
    k_gemm256<4><<<dim3(1000), dim3(512), 0, stream>>>(xb, wg_b, bg, out, nullptr,
                                                       2048, 32000, 1024, 8, 0);
}